// Round 1
// baseline (2205.952 us; speedup 1.0000x reference)
//
#include <hip/hip_runtime.h>
#include <math.h>

typedef unsigned long long ull;

#define NB   8
#define NTOK 256
#define CIN  256
#define NP   16384
#define NCO  512
#define HW64 4096
#define OHW  1024
#define NS   64
#define EPS  1e-6f
#define KC   2304   // 9*256 conv K

// ---------------- workspace layout (float offsets) ----------------
constexpr size_t OFF_SUMS = 0;                                   // 8*4096*256 (zero) -> becomes x_map (B,HW,C)
constexpr size_t OFF_CNT  = OFF_SUMS + (size_t)NB*HW64*CIN;      // 8*4096 (zero)
constexpr size_t OFF_AMAT = OFF_CNT  + (size_t)NB*HW64;          // 8*256*1024 (zero) tok x cell32 weights
constexpr size_t OFF_ALLW = OFF_AMAT + (size_t)NB*NTOK*OHW;      // 8*64 (zero)
constexpr size_t OFF_DMAX = OFF_ALLW + (size_t)NB*NS;            // 8 (zero, uint bits)
constexpr size_t OFF_MAXW = OFF_DMAX + NB;                       // 8 (zero, uint bits)
constexpr size_t ZERO_END = OFF_MAXW + NB;
constexpr size_t OFF_WT   = ZERO_END;                            // 2304*512
constexpr size_t OFF_SKWT = OFF_WT   + (size_t)KC*NCO;           // 256*512
constexpr size_t OFF_Y    = OFF_SKWT + (size_t)CIN*NCO;          // 8*1024*512 conv out (B,cell32,Cout)
constexpr size_t OFF_C2   = OFF_Y    + (size_t)NB*OHW*NCO;       // 8*256*512 ssum
constexpr size_t OFF_WSUM = OFF_C2   + (size_t)NB*NTOK*NCO;      // 2048
constexpr size_t OFF_XSKIP= OFF_WSUM + (size_t)NB*NTOK;          // 8*256*512
constexpr size_t OFF_XTOK = OFF_XSKIP+ (size_t)NB*NTOK*NCO;      // 8*256*512
constexpr size_t OFF_XTOKT= OFF_XTOK + (size_t)NB*NTOK*NCO;      // 8*512*256
constexpr size_t OFF_WEXP = OFF_XTOKT+ (size_t)NB*NTOK*NCO;      // 2048
constexpr size_t OFF_SQ   = OFF_WEXP + (size_t)NB*NTOK;          // 2048
constexpr size_t OFF_DIST = OFF_SQ   + (size_t)NB*NTOK;          // 8*256*256
constexpr size_t OFF_DENS = OFF_DIST + (size_t)NB*NTOK*NTOK;     // 2048
constexpr size_t OFF_SCORE= OFF_DENS + (size_t)NB*NTOK;          // 2048
constexpr size_t OFF_IND  = OFF_SCORE+ (size_t)NB*NTOK;          // 512 (int)
constexpr size_t OFF_IDXCL= OFF_IND  + (size_t)NB*NS;            // 2048 (int)
constexpr size_t OFF_NORMW= OFF_IDXCL+ (size_t)NB*NTOK;          // 2048
constexpr size_t OFF_AWBUF= OFF_NORMW+ (size_t)NB*NTOK;          // 8*16384

// ---------------- kernels ----------------

// one block per point: scatter x row into sums[cell64], count, and agg_weight into Amat[tok][cell32]
__global__ void scatter_map(const float* __restrict__ x, const float* __restrict__ loc,
                            const int* __restrict__ idxagg, const float* __restrict__ aggw,
                            float* __restrict__ sums, float* __restrict__ cnt,
                            float* __restrict__ amat) {
    int bp = blockIdx.x;              // b*16384+p
    int b  = bp >> 14;
    float lx = loc[2*bp+0], ly = loc[2*bp+1];
    lx = fminf(fmaxf(lx, -1.f), 1.f);
    ly = fminf(fmaxf(ly, -1.f), 1.f);
    // cell at 64x64: round-half-even like jnp.round
    int px = (int)rintf((lx + 1.f)*32.f - 0.5f); px = min(max(px,0),63);
    int py = (int)rintf((ly + 1.f)*32.f - 0.5f); py = min(max(py,0),63);
    int cell = py*64 + px;
    int tok = idxagg[bp];
    const float* xr = x    + ((size_t)(b*NTOK + tok))*CIN;
    float*       sr = sums + ((size_t)(b*HW64 + cell))*CIN;
    int t = threadIdx.x;
    atomicAdd(sr + t, xr[t]);
    if (t == 0) {
        atomicAdd(cnt + b*HW64 + cell, 1.0f);
        int qx = (int)rintf((lx + 1.f)*16.f - 0.5f); qx = min(max(qx,0),31);
        int qy = (int)rintf((ly + 1.f)*16.f - 0.5f); qy = min(max(qy,0),31);
        atomicAdd(amat + ((size_t)(b*NTOK + tok))*OHW + qy*32 + qx, aggw[bp]);
    }
}

__global__ void finalize_map(float4* __restrict__ sums, const float* __restrict__ cnt) {
    size_t i = (size_t)blockIdx.x*256 + threadIdx.x;      // float4 index, total 2097152
    float c = cnt[i >> 6] + EPS;                          // 64 float4 per 256-ch row
    float4 v = sums[i];
    v.x /= c; v.y /= c; v.z /= c; v.w /= c;
    sums[i] = v;
}

// W_t[k][cout], k=(ky*3+kx)*256+cin
__global__ void wtrans(const float* __restrict__ convw, float* __restrict__ wt) {
    int id = blockIdx.x*256 + threadIdx.x;   // 1179648
    int o = id & 511, k = id >> 9;
    int cin = k & 255, grp = k >> 8;
    wt[id] = convw[(size_t)o*KC + cin*9 + grp];
}

__global__ void skiptrans(const float* __restrict__ skipw, float* __restrict__ skwt) {
    int id = blockIdx.x*256 + threadIdx.x;   // 131072
    int o = id & 511, k = id >> 9;
    skwt[id] = skipw[(size_t)o*CIN + k];
}

// implicit-GEMM conv: y[pos][cout] = sum_k Wt[k][cout]*patch[k](pos) + b[cout]
__launch_bounds__(256)
__global__ void conv_gemm(const float* __restrict__ xmap, const float* __restrict__ wt,
                          const float* __restrict__ convb, float* __restrict__ y) {
    __shared__ __align__(16) float As[16][68];
    __shared__ __align__(16) float Bs[16][68];
    int n0 = blockIdx.x*64;   // pos tile (8192/64 = 128)
    int m0 = blockIdx.y*64;   // cout tile (512/64 = 8)
    int t = threadIdx.x, tx = t & 15, ty = t >> 4;
    float acc[4][4] = {};
    int mL = t & 63, kbL = t >> 6;       // A-load mapping
    int kkL = t & 15, jbL = t >> 4;      // B-load mapping
    for (int ko = 0; ko < KC; ko += 16) {
        #pragma unroll
        for (int r = 0; r < 4; ++r) {
            int kk = kbL + 4*r;
            As[kk][mL] = wt[(size_t)(ko + kk)*NCO + m0 + mL];
        }
        int g = (ko + kkL) >> 8;         // same for all lanes in chunk
        int ky = g/3, kx = g - ky*3;
        int cin = (ko + kkL) & 255;
        #pragma unroll
        for (int r = 0; r < 4; ++r) {
            int j = jbL + 16*r;
            int pos = n0 + j;
            int bb = pos >> 10, rem = pos & 1023;
            int oy = rem >> 5, ox = rem & 31;
            int iy = 2*oy - 1 + ky, ix = 2*ox - 1 + kx;
            float v = 0.f;
            if ((unsigned)iy < 64u && (unsigned)ix < 64u)
                v = xmap[(((size_t)bb*64 + iy)*64 + ix)*256 + cin];
            Bs[kkL][j] = v;
        }
        __syncthreads();
        #pragma unroll
        for (int kk = 0; kk < 16; ++kk) {
            float4 a  = *(const float4*)&As[kk][ty*4];
            float4 bv = *(const float4*)&Bs[kk][tx*4];
            acc[0][0]+=a.x*bv.x; acc[0][1]+=a.x*bv.y; acc[0][2]+=a.x*bv.z; acc[0][3]+=a.x*bv.w;
            acc[1][0]+=a.y*bv.x; acc[1][1]+=a.y*bv.y; acc[1][2]+=a.y*bv.z; acc[1][3]+=a.y*bv.w;
            acc[2][0]+=a.z*bv.x; acc[2][1]+=a.z*bv.y; acc[2][2]+=a.z*bv.z; acc[2][3]+=a.z*bv.w;
            acc[3][0]+=a.w*bv.x; acc[3][1]+=a.w*bv.y; acc[3][2]+=a.w*bv.z; acc[3][3]+=a.w*bv.w;
        }
        __syncthreads();
    }
    #pragma unroll
    for (int jj = 0; jj < 4; ++jj) {
        int pos = n0 + tx*4 + jj;
        float4 o;
        o.x = acc[0][jj] + convb[m0+ty*4+0];
        o.y = acc[1][jj] + convb[m0+ty*4+1];
        o.z = acc[2][jj] + convb[m0+ty*4+2];
        o.w = acc[3][jj] + convb[m0+ty*4+3];
        *(float4*)&y[(size_t)pos*NCO + m0 + ty*4] = o;
    }
}

// generic 64x64-tile GEMM: C[m][n] = sum_k A[m][k]*B[k][n]; row strides = K / Ncols / Ncols
__launch_bounds__(256)
__global__ void gemm64(const float* __restrict__ A, const float* __restrict__ Bm,
                       float* __restrict__ Cc, int K, int Ncols,
                       long sA, long sB, long sC) {
    __shared__ __align__(16) float As[16][68];
    __shared__ __align__(16) float Bs[16][68];
    const float* Ab = A  + (size_t)blockIdx.z * sA;
    const float* Bb = Bm + (size_t)blockIdx.z * sB;
    float*       Cb = Cc + (size_t)blockIdx.z * sC;
    int n0 = blockIdx.x*64, m0 = blockIdx.y*64;
    int t = threadIdx.x, tx = t & 15, ty = t >> 4;
    float acc[4][4] = {};
    int kkA = t & 15, mbA = t >> 4;
    int nB  = t & 63, kbB = t >> 6;
    for (int ko = 0; ko < K; ko += 16) {
        #pragma unroll
        for (int r = 0; r < 4; ++r) {
            int m = mbA + 16*r;
            As[kkA][m] = Ab[(size_t)(m0 + m)*K + ko + kkA];
        }
        #pragma unroll
        for (int r = 0; r < 4; ++r) {
            int kk = kbB + 4*r;
            Bs[kk][nB] = Bb[(size_t)(ko + kk)*Ncols + n0 + nB];
        }
        __syncthreads();
        #pragma unroll
        for (int kk = 0; kk < 16; ++kk) {
            float4 a  = *(const float4*)&As[kk][ty*4];
            float4 bv = *(const float4*)&Bs[kk][tx*4];
            acc[0][0]+=a.x*bv.x; acc[0][1]+=a.x*bv.y; acc[0][2]+=a.x*bv.z; acc[0][3]+=a.x*bv.w;
            acc[1][0]+=a.y*bv.x; acc[1][1]+=a.y*bv.y; acc[1][2]+=a.y*bv.z; acc[1][3]+=a.y*bv.w;
            acc[2][0]+=a.z*bv.x; acc[2][1]+=a.z*bv.y; acc[2][2]+=a.z*bv.z; acc[2][3]+=a.z*bv.w;
            acc[3][0]+=a.w*bv.x; acc[3][1]+=a.w*bv.y; acc[3][2]+=a.w*bv.z; acc[3][3]+=a.w*bv.w;
        }
        __syncthreads();
    }
    #pragma unroll
    for (int ii = 0; ii < 4; ++ii) {
        float4 o = make_float4(acc[ii][0], acc[ii][1], acc[ii][2], acc[ii][3]);
        *(float4*)&Cb[(size_t)(m0 + ty*4 + ii)*Ncols + n0 + tx*4] = o;
    }
}

// row sums of Amat -> wsum  (one wave per row)
__global__ void wsum_rows(const float* __restrict__ amat, float* __restrict__ wsum) {
    int row = blockIdx.x*4 + (threadIdx.x >> 6);
    int lane = threadIdx.x & 63;
    const float* ar = amat + (size_t)row*OHW;
    float s = 0.f;
    #pragma unroll
    for (int r = 0; r < 16; ++r) s += ar[lane + 64*r];
    #pragma unroll
    for (int off = 32; off; off >>= 1) s += __shfl_xor(s, off, 64);
    if (lane == 0) wsum[row] = s;
}

__device__ __forceinline__ float block_sum256(float v, float* red) {
    #pragma unroll
    for (int off = 32; off; off >>= 1) v += __shfl_xor(v, off, 64);
    __syncthreads();
    if ((threadIdx.x & 63) == 0) red[threadIdx.x >> 6] = v;
    __syncthreads();
    return red[0] + red[1] + red[2] + red[3];
}

// x_tok = LN(C2/(wsum+eps) + xskip)*g + b ; conf -> wexp ; sq = sum(x_tok^2)
__global__ void ln_conf(const float* __restrict__ C2, const float* __restrict__ wsum,
                        const float* __restrict__ xskip, const float* __restrict__ g,
                        const float* __restrict__ be, const float* __restrict__ confw,
                        const float* __restrict__ confb, float* __restrict__ xtok,
                        float* __restrict__ wexp, float* __restrict__ sqv) {
    __shared__ float red[4];
    int row = blockIdx.x, t = threadIdx.x;
    float ws = wsum[row] + EPS;
    size_t base = (size_t)row*NCO;
    float v0 = C2[base + t]       / ws + xskip[base + t];
    float v1 = C2[base + t + 256] / ws + xskip[base + t + 256];
    float mu  = block_sum256(v0 + v1, red) / 512.0f;
    float d0 = v0 - mu, d1 = v1 - mu;
    float var = block_sum256(d0*d0 + d1*d1, red) / 512.0f;
    float sv = sqrtf(var + 1e-5f);
    float x0 = d0/sv * g[t]       + be[t];
    float x1 = d1/sv * g[t + 256] + be[t + 256];
    xtok[base + t] = x0;
    xtok[base + t + 256] = x1;
    float cs = block_sum256(x0*confw[t] + x1*confw[t + 256], red);
    float qs = block_sum256(x0*x0 + x1*x1, red);
    if (t == 0) {
        wexp[row] = expf(cs + confb[0]);
        sqv[row]  = qs;
    }
}

__global__ void xtok_trans(const float* __restrict__ xtok, float* __restrict__ xtokt) {
    size_t id = (size_t)blockIdx.x*256 + threadIdx.x;   // over 8*512*256
    int n = (int)(id & 255);
    int c = (int)((id >> 8) & 511);
    int b = (int)(id >> 17);
    xtokt[id] = xtok[((size_t)(b*NTOK + n))*NCO + c];
}

// dist[i][j] = sqrt(max(sq_i+sq_j-2*G,0))/sqrt(512); track per-batch max
__launch_bounds__(256)
__global__ void dist_gemm(const float* __restrict__ xtok, const float* __restrict__ xtokt,
                          const float* __restrict__ sq, float* __restrict__ dist,
                          unsigned* __restrict__ dmaxU) {
    __shared__ __align__(16) float As[16][68];
    __shared__ __align__(16) float Bs[16][68];
    int z = blockIdx.z;
    const float* Ab = xtok  + (size_t)z*NTOK*NCO;
    const float* Bb = xtokt + (size_t)z*NCO*NTOK;
    int n0 = blockIdx.x*64, m0 = blockIdx.y*64;
    int t = threadIdx.x, tx = t & 15, ty = t >> 4;
    float acc[4][4] = {};
    int kkA = t & 15, mbA = t >> 4;
    int nB  = t & 63, kbB = t >> 6;
    for (int ko = 0; ko < NCO; ko += 16) {
        #pragma unroll
        for (int r = 0; r < 4; ++r) {
            int m = mbA + 16*r;
            As[kkA][m] = Ab[(size_t)(m0 + m)*NCO + ko + kkA];
        }
        #pragma unroll
        for (int r = 0; r < 4; ++r) {
            int kk = kbB + 4*r;
            Bs[kk][nB] = Bb[(size_t)(ko + kk)*NTOK + n0 + nB];
        }
        __syncthreads();
        #pragma unroll
        for (int kk = 0; kk < 16; ++kk) {
            float4 a  = *(const float4*)&As[kk][ty*4];
            float4 bv = *(const float4*)&Bs[kk][tx*4];
            acc[0][0]+=a.x*bv.x; acc[0][1]+=a.x*bv.y; acc[0][2]+=a.x*bv.z; acc[0][3]+=a.x*bv.w;
            acc[1][0]+=a.y*bv.x; acc[1][1]+=a.y*bv.y; acc[1][2]+=a.y*bv.z; acc[1][3]+=a.y*bv.w;
            acc[2][0]+=a.z*bv.x; acc[2][1]+=a.z*bv.y; acc[2][2]+=a.z*bv.z; acc[2][3]+=a.z*bv.w;
            acc[3][0]+=a.w*bv.x; acc[3][1]+=a.w*bv.y; acc[3][2]+=a.w*bv.z; acc[3][3]+=a.w*bv.w;
        }
        __syncthreads();
    }
    const float s512 = sqrtf(512.0f);
    const float* sqb = sq + z*NTOK;
    float tmax = 0.f;
    #pragma unroll
    for (int ii = 0; ii < 4; ++ii) {
        int m = m0 + ty*4 + ii;
        float sm = sqb[m];
        #pragma unroll
        for (int jj = 0; jj < 4; ++jj) {
            int n = n0 + tx*4 + jj;
            float d2 = sm + sqb[n] - 2.0f*acc[ii][jj];
            float d = sqrtf(fmaxf(d2, 0.0f)) / s512;
            dist[((size_t)(z*NTOK + m))*NTOK + n] = d;
            tmax = fmaxf(tmax, d);
        }
    }
    atomicMax(&dmaxU[z], __float_as_uint(tmax));
}

// density = exp(-mean of 5 smallest dist^2) ; one wave per row
__global__ void knn_dens(const float* __restrict__ dist, float* __restrict__ dens) {
    int row = blockIdx.x*4 + (threadIdx.x >> 6);
    int lane = threadIdx.x & 63;
    const float* dr = dist + (size_t)row*NTOK;
    float v0 = dr[lane], v1 = dr[lane+64], v2 = dr[lane+128], v3 = dr[lane+192];
    float acc = 0.f;
    #pragma unroll
    for (int it = 0; it < 5; ++it) {
        float lm = fminf(fminf(v0, v1), fminf(v2, v3));
        float gm = lm;
        #pragma unroll
        for (int off = 32; off; off >>= 1) gm = fminf(gm, __shfl_xor(gm, off, 64));
        acc += gm*gm;
        ull ball = __ballot(lm == gm);
        int first = __ffsll(ball) - 1;
        if (lane == first) {
            if      (v0 == gm) v0 = 1e30f;
            else if (v1 == gm) v1 = 1e30f;
            else if (v2 == gm) v2 = 1e30f;
            else               v3 = 1e30f;
        }
    }
    if (lane == 0) dens[row] = expf(-(acc/5.0f));
}

// parent_dist = min_j (dens_j > dens_i ? dist_ij : dmax); score = pd * dens_i
__global__ void parent_score(const float* __restrict__ dist, const float* __restrict__ dens,
                             const unsigned* __restrict__ dmaxU, float* __restrict__ score) {
    int row = blockIdx.x*4 + (threadIdx.x >> 6);
    int lane = threadIdx.x & 63;
    int b = row >> 8;
    float di = dens[row];
    float dm = __uint_as_float(dmaxU[b]);
    const float* dr = dist + (size_t)row*NTOK;
    const float* db = dens + (size_t)b*NTOK;
    float pd = dm;
    #pragma unroll
    for (int r = 0; r < 4; ++r) {
        int j = lane + 64*r;
        pd = fminf(pd, (db[j] > di) ? dr[j] : dm);
    }
    #pragma unroll
    for (int off = 32; off; off >>= 1) pd = fminf(pd, __shfl_xor(pd, off, 64));
    if (lane == 0) score[row] = pd * di;
}

// top-64 scores per batch, descending, lower index first on ties. one wave per batch.
__global__ void topk64(const float* __restrict__ score, int* __restrict__ ind) {
    int b = blockIdx.x, lane = threadIdx.x;
    const float* sb = score + b*NTOK;
    ull k0, k1, k2, k3;
    {
        unsigned i0 = lane, i1 = lane+64, i2 = lane+128, i3 = lane+192;
        k0 = ((ull)(__float_as_uint(sb[i0]) + 1u) << 32) | (unsigned)(4095 - i0);
        k1 = ((ull)(__float_as_uint(sb[i1]) + 1u) << 32) | (unsigned)(4095 - i1);
        k2 = ((ull)(__float_as_uint(sb[i2]) + 1u) << 32) | (unsigned)(4095 - i2);
        k3 = ((ull)(__float_as_uint(sb[i3]) + 1u) << 32) | (unsigned)(4095 - i3);
    }
    for (int it = 0; it < 64; ++it) {
        ull lm = k0;
        if (k1 > lm) lm = k1;
        if (k2 > lm) lm = k2;
        if (k3 > lm) lm = k3;
        ull gm = lm;
        #pragma unroll
        for (int off = 32; off; off >>= 1) {
            ull o = __shfl_xor(gm, off, 64);
            if (o > gm) gm = o;
        }
        if (lane == 0) ind[b*NS + it] = 4095 - (int)(gm & 0xffffffffull);
        if      (k0 == gm) k0 = 0;
        else if (k1 == gm) k1 = 0;
        else if (k2 == gm) k2 = 0;
        else if (k3 == gm) k3 = 0;
    }
}

// idx_cluster[i] = argmin_s dist[center_s][i] (first min). one wave per token.
__global__ void assign_k(const float* __restrict__ dist, const int* __restrict__ ind,
                         int* __restrict__ idxcl) {
    int row = blockIdx.x*4 + (threadIdx.x >> 6);   // b*256+i
    int lane = threadIdx.x & 63;
    int b = row >> 8, i = row & 255;
    int center = ind[b*NS + lane];
    float d = dist[((size_t)(b*NTOK + center))*NTOK + i];
    ull key = ((ull)__float_as_uint(d) << 32) | (unsigned)lane;
    #pragma unroll
    for (int off = 32; off; off >>= 1) {
        ull o = __shfl_xor(key, off, 64);
        if (o < key) key = o;
    }
    if (lane == 0) idxcl[row] = (int)(key & 0xffffffffull);
}

__global__ void center_set(const int* __restrict__ ind, int* __restrict__ idxcl) {
    int id = threadIdx.x;   // 512
    int b = id >> 6, s = id & 63;
    idxcl[b*NTOK + ind[id]] = s;
}

__global__ void allw_acc(const int* __restrict__ idxcl, const float* __restrict__ wexp,
                         float* __restrict__ allw) {
    int b = blockIdx.x, i = threadIdx.x;
    atomicAdd(&allw[b*NS + idxcl[b*NTOK + i]], wexp[b*NTOK + i]);
}

__global__ void normw_k(const int* __restrict__ idxcl, const float* __restrict__ wexp,
                        const float* __restrict__ allw, float* __restrict__ normw) {
    int b = blockIdx.x, i = threadIdx.x;
    normw[b*NTOK + i] = wexp[b*NTOK + i] / (allw[b*NS + idxcl[b*NTOK + i]] + EPS);
}

// x_down accumulated directly into d_out (pre-zeroed)
__global__ void merge_k(const float* __restrict__ xtok, const int* __restrict__ idxcl,
                        const float* __restrict__ normw, float* __restrict__ xout) {
    int row = blockIdx.x, t = threadIdx.x;
    int b = row >> 8;
    int cl = idxcl[row];
    float nw = normw[row];
    float* o = xout + ((size_t)(b*NS + cl))*NCO;
    const float* xr = xtok + (size_t)row*NCO;
    atomicAdd(&o[t],       xr[t]       * nw);
    atomicAdd(&o[t + 256], xr[t + 256] * nw);
}

__global__ void out_idx_aw(const int* __restrict__ idxagg, const float* __restrict__ aggw,
                           const int* __restrict__ idxcl, const float* __restrict__ normw,
                           float* __restrict__ dout, float* __restrict__ awbuf,
                           unsigned* __restrict__ maxw) {
    int bp = blockIdx.x*256 + threadIdx.x;
    int b = bp >> 14;
    int tok = idxagg[bp];
    int cl = idxcl[b*NTOK + tok];
    dout[(size_t)NB*NS*NCO + bp] = (float)cl;
    float aw = aggw[bp] * normw[b*NTOK + tok];
    awbuf[bp] = aw;
    atomicMax(&maxw[b], __float_as_uint(aw));   // aw > 0: uint-bits compare == float compare
}

__global__ void aw_final(const float* __restrict__ awbuf, const float* __restrict__ maxw,
                         float* __restrict__ dout) {
    int bp = blockIdx.x*256 + threadIdx.x;
    int b = bp >> 14;
    dout[(size_t)NB*NS*NCO + (size_t)NB*NP + bp] = awbuf[bp] / maxw[b];
}

// ---------------- launch ----------------
extern "C" void kernel_launch(void* const* d_in, const int* in_sizes, int n_in,
                              void* d_out, int out_size, void* d_ws, size_t ws_size,
                              hipStream_t stream) {
    const float* x      = (const float*)d_in[0];
    const float* loc    = (const float*)d_in[1];
    const int*   idxagg = (const int*)  d_in[2];
    const float* aggw   = (const float*)d_in[3];
    // d_in[4] idx_k_loc, d_in[5] H, d_in[6] W: unused (H=W=64 fixed by problem)
    const float* convw  = (const float*)d_in[7];
    const float* convb  = (const float*)d_in[8];
    const float* skipw  = (const float*)d_in[9];
    const float* lng    = (const float*)d_in[10];
    const float* lnb    = (const float*)d_in[11];
    const float* confw  = (const float*)d_in[12];
    const float* confb  = (const float*)d_in[13];

    float* ws = (float*)d_ws;
    float* dout = (float*)d_out;

    (void)hipMemsetAsync(ws, 0, ZERO_END*sizeof(float), stream);
    (void)hipMemsetAsync(dout, 0, (size_t)NB*NS*NCO*sizeof(float), stream);

    scatter_map<<<dim3(NB*NP), 256, 0, stream>>>(x, loc, idxagg, aggw,
                                                 ws + OFF_SUMS, ws + OFF_CNT, ws + OFF_AMAT);
    wtrans<<<dim3(KC*NCO/256), 256, 0, stream>>>(convw, ws + OFF_WT);
    skiptrans<<<dim3(CIN*NCO/256), 256, 0, stream>>>(skipw, ws + OFF_SKWT);
    finalize_map<<<dim3((NB*HW64*CIN/4)/256), 256, 0, stream>>>((float4*)(ws + OFF_SUMS), ws + OFF_CNT);

    conv_gemm<<<dim3(128, 8), 256, 0, stream>>>(ws + OFF_SUMS, ws + OFF_WT, convb, ws + OFF_Y);

    wsum_rows<<<dim3(NB*NTOK/4), 256, 0, stream>>>(ws + OFF_AMAT, ws + OFF_WSUM);
    // ssum = Amat @ y : M=256,N=512,K=1024 per batch
    gemm64<<<dim3(8, 4, 8), 256, 0, stream>>>(ws + OFF_AMAT, ws + OFF_Y, ws + OFF_C2,
                                              OHW, NCO,
                                              (long)NTOK*OHW, (long)OHW*NCO, (long)NTOK*NCO);
    // xskip = x @ skip_wt : M=2048,N=512,K=256
    gemm64<<<dim3(8, 32, 1), 256, 0, stream>>>(x, ws + OFF_SKWT, ws + OFF_XSKIP,
                                               CIN, NCO, 0, 0, 0);

    ln_conf<<<dim3(NB*NTOK), 256, 0, stream>>>(ws + OFF_C2, ws + OFF_WSUM, ws + OFF_XSKIP,
                                               lng, lnb, confw, confb,
                                               ws + OFF_XTOK, ws + OFF_WEXP, ws + OFF_SQ);

    xtok_trans<<<dim3(NB*NCO*NTOK/256), 256, 0, stream>>>(ws + OFF_XTOK, ws + OFF_XTOKT);
    dist_gemm<<<dim3(4, 4, 8), 256, 0, stream>>>(ws + OFF_XTOK, ws + OFF_XTOKT, ws + OFF_SQ,
                                                 ws + OFF_DIST, (unsigned*)(ws + OFF_DMAX));

    knn_dens<<<dim3(NB*NTOK/4), 256, 0, stream>>>(ws + OFF_DIST, ws + OFF_DENS);
    parent_score<<<dim3(NB*NTOK/4), 256, 0, stream>>>(ws + OFF_DIST, ws + OFF_DENS,
                                                      (const unsigned*)(ws + OFF_DMAX), ws + OFF_SCORE);
    topk64<<<dim3(NB), 64, 0, stream>>>(ws + OFF_SCORE, (int*)(ws + OFF_IND));
    assign_k<<<dim3(NB*NTOK/4), 256, 0, stream>>>(ws + OFF_DIST, (const int*)(ws + OFF_IND),
                                                  (int*)(ws + OFF_IDXCL));
    center_set<<<dim3(1), 512, 0, stream>>>((const int*)(ws + OFF_IND), (int*)(ws + OFF_IDXCL));
    allw_acc<<<dim3(NB), 256, 0, stream>>>((const int*)(ws + OFF_IDXCL), ws + OFF_WEXP, ws + OFF_ALLW);
    normw_k<<<dim3(NB), 256, 0, stream>>>((const int*)(ws + OFF_IDXCL), ws + OFF_WEXP,
                                          ws + OFF_ALLW, ws + OFF_NORMW);
    merge_k<<<dim3(NB*NTOK), 256, 0, stream>>>(ws + OFF_XTOK, (const int*)(ws + OFF_IDXCL),
                                               ws + OFF_NORMW, dout);
    out_idx_aw<<<dim3(NB*NP/256), 256, 0, stream>>>(idxagg, aggw, (const int*)(ws + OFF_IDXCL),
                                                    ws + OFF_NORMW, dout, ws + OFF_AWBUF,
                                                    (unsigned*)(ws + OFF_MAXW));
    aw_final<<<dim3(NB*NP/256), 256, 0, stream>>>(ws + OFF_AWBUF, (const float*)(ws + OFF_MAXW), dout);
}

// Round 2
// 685.534 us; speedup vs baseline: 3.2179x; 3.2179x over previous
//
#include <hip/hip_runtime.h>
#include <math.h>

typedef unsigned long long ull;

#define NB   8
#define NTOK 256
#define CIN  256
#define NP   16384
#define NCO  512
#define HW64 4096
#define OHW  1024
#define NS   64
#define EPS  1e-6f
#define KC   2304   // 9*256 conv K

// ---------------- workspace layout (float offsets) ----------------
constexpr size_t OFF_SUMS = 0;                                   // 8*4096*256 (zero) -> becomes x_map (B,HW,C)
constexpr size_t OFF_CNT  = OFF_SUMS + (size_t)NB*HW64*CIN;      // 8*4096 (zero)
constexpr size_t OFF_AMAT = OFF_CNT  + (size_t)NB*HW64;          // 8*256*1024 (zero) tok x cell32 weights
constexpr size_t OFF_ALLW = OFF_AMAT + (size_t)NB*NTOK*OHW;      // 8*64 (zero)
constexpr size_t OFF_DMAX = OFF_ALLW + (size_t)NB*NS;            // 8 (zero, uint bits)
constexpr size_t OFF_MAXW = OFF_DMAX + NB;                       // 8 (zero, uint bits)
constexpr size_t ZERO_END = OFF_MAXW + NB;
constexpr size_t OFF_WT   = ZERO_END;                            // 2304*512
constexpr size_t OFF_SKWT = OFF_WT   + (size_t)KC*NCO;           // 256*512
constexpr size_t OFF_Y    = OFF_SKWT + (size_t)CIN*NCO;          // 8*1024*512 conv out (B,cell32,Cout)
constexpr size_t OFF_C2   = OFF_Y    + (size_t)NB*OHW*NCO;       // 8*256*512 ssum
constexpr size_t OFF_WSUM = OFF_C2   + (size_t)NB*NTOK*NCO;      // 2048
constexpr size_t OFF_XSKIP= OFF_WSUM + (size_t)NB*NTOK;          // 8*256*512
constexpr size_t OFF_XTOK = OFF_XSKIP+ (size_t)NB*NTOK*NCO;      // 8*256*512
constexpr size_t OFF_XTOKT= OFF_XTOK + (size_t)NB*NTOK*NCO;      // 8*512*256
constexpr size_t OFF_WEXP = OFF_XTOKT+ (size_t)NB*NTOK*NCO;      // 2048
constexpr size_t OFF_SQ   = OFF_WEXP + (size_t)NB*NTOK;          // 2048
constexpr size_t OFF_DIST = OFF_SQ   + (size_t)NB*NTOK;          // 8*256*256
constexpr size_t OFF_DENS = OFF_DIST + (size_t)NB*NTOK*NTOK;     // 2048
constexpr size_t OFF_SCORE= OFF_DENS + (size_t)NB*NTOK;          // 2048
constexpr size_t OFF_IND  = OFF_SCORE+ (size_t)NB*NTOK;          // 512 (int)
constexpr size_t OFF_IDXCL= OFF_IND  + (size_t)NB*NS;            // 2048 (int)
constexpr size_t OFF_NORMW= OFF_IDXCL+ (size_t)NB*NTOK;          // 2048
constexpr size_t OFF_AWBUF= OFF_NORMW+ (size_t)NB*NTOK;          // 8*16384

// ---------------- kernels ----------------

// one block per point: scatter x row into sums[cell64], count, and agg_weight into Amat[tok][cell32]
__global__ void scatter_map(const float* __restrict__ x, const float* __restrict__ loc,
                            const int* __restrict__ idxagg, const float* __restrict__ aggw,
                            float* __restrict__ sums, float* __restrict__ cnt,
                            float* __restrict__ amat) {
    int bp = blockIdx.x;              // b*16384+p
    int b  = bp >> 14;
    float lx = loc[2*bp+0], ly = loc[2*bp+1];
    lx = fminf(fmaxf(lx, -1.f), 1.f);
    ly = fminf(fmaxf(ly, -1.f), 1.f);
    // cell at 64x64: round-half-even like jnp.round
    int px = (int)rintf((lx + 1.f)*32.f - 0.5f); px = min(max(px,0),63);
    int py = (int)rintf((ly + 1.f)*32.f - 0.5f); py = min(max(py,0),63);
    int cell = py*64 + px;
    int tok = idxagg[bp];
    const float* xr = x    + ((size_t)(b*NTOK + tok))*CIN;
    float*       sr = sums + ((size_t)(b*HW64 + cell))*CIN;
    int t = threadIdx.x;
    atomicAdd(sr + t, xr[t]);
    if (t == 0) {
        atomicAdd(cnt + b*HW64 + cell, 1.0f);
        int qx = (int)rintf((lx + 1.f)*16.f - 0.5f); qx = min(max(qx,0),31);
        int qy = (int)rintf((ly + 1.f)*16.f - 0.5f); qy = min(max(qy,0),31);
        atomicAdd(amat + ((size_t)(b*NTOK + tok))*OHW + qy*32 + qx, aggw[bp]);
    }
}

__global__ void finalize_map(float4* __restrict__ sums, const float* __restrict__ cnt) {
    size_t i = (size_t)blockIdx.x*256 + threadIdx.x;      // float4 index, total 2097152
    float c = cnt[i >> 6] + EPS;                          // 64 float4 per 256-ch row
    float4 v = sums[i];
    v.x /= c; v.y /= c; v.z /= c; v.w /= c;
    sums[i] = v;
}

// W_t[k][cout], k=(ky*3+kx)*256+cin
__global__ void wtrans(const float* __restrict__ convw, float* __restrict__ wt) {
    int id = blockIdx.x*256 + threadIdx.x;   // 1179648
    int o = id & 511, k = id >> 9;
    int cin = k & 255, grp = k >> 8;
    wt[id] = convw[(size_t)o*KC + cin*9 + grp];
}

__global__ void skiptrans(const float* __restrict__ skipw, float* __restrict__ skwt) {
    int id = blockIdx.x*256 + threadIdx.x;   // 131072
    int o = id & 511, k = id >> 9;
    skwt[id] = skipw[(size_t)o*CIN + k];
}

// implicit-GEMM conv: y[pos][cout] = sum_k Wt[k][cout]*patch[k](pos) + b[cout]
__launch_bounds__(256)
__global__ void conv_gemm(const float* __restrict__ xmap, const float* __restrict__ wt,
                          const float* __restrict__ convb, float* __restrict__ y) {
    __shared__ __align__(16) float As[16][68];
    __shared__ __align__(16) float Bs[16][68];
    int n0 = blockIdx.x*64;   // pos tile (8192/64 = 128)
    int m0 = blockIdx.y*64;   // cout tile (512/64 = 8)
    int t = threadIdx.x, tx = t & 15, ty = t >> 4;
    float acc[4][4] = {};
    int mL = t & 63, kbL = t >> 6;       // A-load mapping
    int kkL = t & 15, jbL = t >> 4;      // B-load mapping
    for (int ko = 0; ko < KC; ko += 16) {
        #pragma unroll
        for (int r = 0; r < 4; ++r) {
            int kk = kbL + 4*r;
            As[kk][mL] = wt[(size_t)(ko + kk)*NCO + m0 + mL];
        }
        int g = (ko + kkL) >> 8;         // same for all lanes in chunk
        int ky = g/3, kx = g - ky*3;
        int cin = (ko + kkL) & 255;
        #pragma unroll
        for (int r = 0; r < 4; ++r) {
            int j = jbL + 16*r;
            int pos = n0 + j;
            int bb = pos >> 10, rem = pos & 1023;
            int oy = rem >> 5, ox = rem & 31;
            int iy = 2*oy - 1 + ky, ix = 2*ox - 1 + kx;
            float v = 0.f;
            if ((unsigned)iy < 64u && (unsigned)ix < 64u)
                v = xmap[(((size_t)bb*64 + iy)*64 + ix)*256 + cin];
            Bs[kkL][j] = v;
        }
        __syncthreads();
        #pragma unroll
        for (int kk = 0; kk < 16; ++kk) {
            float4 a  = *(const float4*)&As[kk][ty*4];
            float4 bv = *(const float4*)&Bs[kk][tx*4];
            acc[0][0]+=a.x*bv.x; acc[0][1]+=a.x*bv.y; acc[0][2]+=a.x*bv.z; acc[0][3]+=a.x*bv.w;
            acc[1][0]+=a.y*bv.x; acc[1][1]+=a.y*bv.y; acc[1][2]+=a.y*bv.z; acc[1][3]+=a.y*bv.w;
            acc[2][0]+=a.z*bv.x; acc[2][1]+=a.z*bv.y; acc[2][2]+=a.z*bv.z; acc[2][3]+=a.z*bv.w;
            acc[3][0]+=a.w*bv.x; acc[3][1]+=a.w*bv.y; acc[3][2]+=a.w*bv.z; acc[3][3]+=a.w*bv.w;
        }
        __syncthreads();
    }
    #pragma unroll
    for (int jj = 0; jj < 4; ++jj) {
        int pos = n0 + tx*4 + jj;
        float4 o;
        o.x = acc[0][jj] + convb[m0+ty*4+0];
        o.y = acc[1][jj] + convb[m0+ty*4+1];
        o.z = acc[2][jj] + convb[m0+ty*4+2];
        o.w = acc[3][jj] + convb[m0+ty*4+3];
        *(float4*)&y[(size_t)pos*NCO + m0 + ty*4] = o;
    }
}

// generic 64x64-tile GEMM: C[m][n] = sum_k A[m][k]*B[k][n]; row strides = K / Ncols / Ncols
__launch_bounds__(256)
__global__ void gemm64(const float* __restrict__ A, const float* __restrict__ Bm,
                       float* __restrict__ Cc, int K, int Ncols,
                       long sA, long sB, long sC) {
    __shared__ __align__(16) float As[16][68];
    __shared__ __align__(16) float Bs[16][68];
    const float* Ab = A  + (size_t)blockIdx.z * sA;
    const float* Bb = Bm + (size_t)blockIdx.z * sB;
    float*       Cb = Cc + (size_t)blockIdx.z * sC;
    int n0 = blockIdx.x*64, m0 = blockIdx.y*64;
    int t = threadIdx.x, tx = t & 15, ty = t >> 4;
    float acc[4][4] = {};
    int kkA = t & 15, mbA = t >> 4;
    int nB  = t & 63, kbB = t >> 6;
    for (int ko = 0; ko < K; ko += 16) {
        #pragma unroll
        for (int r = 0; r < 4; ++r) {
            int m = mbA + 16*r;
            As[kkA][m] = Ab[(size_t)(m0 + m)*K + ko + kkA];
        }
        #pragma unroll
        for (int r = 0; r < 4; ++r) {
            int kk = kbB + 4*r;
            Bs[kk][nB] = Bb[(size_t)(ko + kk)*Ncols + n0 + nB];
        }
        __syncthreads();
        #pragma unroll
        for (int kk = 0; kk < 16; ++kk) {
            float4 a  = *(const float4*)&As[kk][ty*4];
            float4 bv = *(const float4*)&Bs[kk][tx*4];
            acc[0][0]+=a.x*bv.x; acc[0][1]+=a.x*bv.y; acc[0][2]+=a.x*bv.z; acc[0][3]+=a.x*bv.w;
            acc[1][0]+=a.y*bv.x; acc[1][1]+=a.y*bv.y; acc[1][2]+=a.y*bv.z; acc[1][3]+=a.y*bv.w;
            acc[2][0]+=a.z*bv.x; acc[2][1]+=a.z*bv.y; acc[2][2]+=a.z*bv.z; acc[2][3]+=a.z*bv.w;
            acc[3][0]+=a.w*bv.x; acc[3][1]+=a.w*bv.y; acc[3][2]+=a.w*bv.z; acc[3][3]+=a.w*bv.w;
        }
        __syncthreads();
    }
    #pragma unroll
    for (int ii = 0; ii < 4; ++ii) {
        float4 o = make_float4(acc[ii][0], acc[ii][1], acc[ii][2], acc[ii][3]);
        *(float4*)&Cb[(size_t)(m0 + ty*4 + ii)*Ncols + n0 + tx*4] = o;
    }
}

// row sums of Amat -> wsum  (one wave per row)
__global__ void wsum_rows(const float* __restrict__ amat, float* __restrict__ wsum) {
    int row = blockIdx.x*4 + (threadIdx.x >> 6);
    int lane = threadIdx.x & 63;
    const float* ar = amat + (size_t)row*OHW;
    float s = 0.f;
    #pragma unroll
    for (int r = 0; r < 16; ++r) s += ar[lane + 64*r];
    #pragma unroll
    for (int off = 32; off; off >>= 1) s += __shfl_xor(s, off, 64);
    if (lane == 0) wsum[row] = s;
}

__device__ __forceinline__ float block_sum256(float v, float* red) {
    #pragma unroll
    for (int off = 32; off; off >>= 1) v += __shfl_xor(v, off, 64);
    __syncthreads();
    if ((threadIdx.x & 63) == 0) red[threadIdx.x >> 6] = v;
    __syncthreads();
    return red[0] + red[1] + red[2] + red[3];
}

// x_tok = LN(C2/(wsum+eps) + xskip)*g + b ; conf -> wexp ; sq = sum(x_tok^2)
__global__ void ln_conf(const float* __restrict__ C2, const float* __restrict__ wsum,
                        const float* __restrict__ xskip, const float* __restrict__ g,
                        const float* __restrict__ be, const float* __restrict__ confw,
                        const float* __restrict__ confb, float* __restrict__ xtok,
                        float* __restrict__ wexp, float* __restrict__ sqv) {
    __shared__ float red[4];
    int row = blockIdx.x, t = threadIdx.x;
    float ws = wsum[row] + EPS;
    size_t base = (size_t)row*NCO;
    float v0 = C2[base + t]       / ws + xskip[base + t];
    float v1 = C2[base + t + 256] / ws + xskip[base + t + 256];
    float mu  = block_sum256(v0 + v1, red) / 512.0f;
    float d0 = v0 - mu, d1 = v1 - mu;
    float var = block_sum256(d0*d0 + d1*d1, red) / 512.0f;
    float sv = sqrtf(var + 1e-5f);
    float x0 = d0/sv * g[t]       + be[t];
    float x1 = d1/sv * g[t + 256] + be[t + 256];
    xtok[base + t] = x0;
    xtok[base + t + 256] = x1;
    float cs = block_sum256(x0*confw[t] + x1*confw[t + 256], red);
    float qs = block_sum256(x0*x0 + x1*x1, red);
    if (t == 0) {
        wexp[row] = expf(cs + confb[0]);
        sqv[row]  = qs;
    }
}

__global__ void xtok_trans(const float* __restrict__ xtok, float* __restrict__ xtokt) {
    size_t id = (size_t)blockIdx.x*256 + threadIdx.x;   // over 8*512*256
    int n = (int)(id & 255);
    int c = (int)((id >> 8) & 511);
    int b = (int)(id >> 17);
    xtokt[id] = xtok[((size_t)(b*NTOK + n))*NCO + c];
}

// dist[i][j] = sqrt(max(sq_i+sq_j-2*G,0))/sqrt(512); track per-batch max
__launch_bounds__(256)
__global__ void dist_gemm(const float* __restrict__ xtok, const float* __restrict__ xtokt,
                          const float* __restrict__ sq, float* __restrict__ dist,
                          unsigned* __restrict__ dmaxU) {
    __shared__ __align__(16) float As[16][68];
    __shared__ __align__(16) float Bs[16][68];
    int z = blockIdx.z;
    const float* Ab = xtok  + (size_t)z*NTOK*NCO;
    const float* Bb = xtokt + (size_t)z*NCO*NTOK;
    int n0 = blockIdx.x*64, m0 = blockIdx.y*64;
    int t = threadIdx.x, tx = t & 15, ty = t >> 4;
    float acc[4][4] = {};
    int kkA = t & 15, mbA = t >> 4;
    int nB  = t & 63, kbB = t >> 6;
    for (int ko = 0; ko < NCO; ko += 16) {
        #pragma unroll
        for (int r = 0; r < 4; ++r) {
            int m = mbA + 16*r;
            As[kkA][m] = Ab[(size_t)(m0 + m)*NCO + ko + kkA];
        }
        #pragma unroll
        for (int r = 0; r < 4; ++r) {
            int kk = kbB + 4*r;
            Bs[kk][nB] = Bb[(size_t)(ko + kk)*NTOK + n0 + nB];
        }
        __syncthreads();
        #pragma unroll
        for (int kk = 0; kk < 16; ++kk) {
            float4 a  = *(const float4*)&As[kk][ty*4];
            float4 bv = *(const float4*)&Bs[kk][tx*4];
            acc[0][0]+=a.x*bv.x; acc[0][1]+=a.x*bv.y; acc[0][2]+=a.x*bv.z; acc[0][3]+=a.x*bv.w;
            acc[1][0]+=a.y*bv.x; acc[1][1]+=a.y*bv.y; acc[1][2]+=a.y*bv.z; acc[1][3]+=a.y*bv.w;
            acc[2][0]+=a.z*bv.x; acc[2][1]+=a.z*bv.y; acc[2][2]+=a.z*bv.z; acc[2][3]+=a.z*bv.w;
            acc[3][0]+=a.w*bv.x; acc[3][1]+=a.w*bv.y; acc[3][2]+=a.w*bv.z; acc[3][3]+=a.w*bv.w;
        }
        __syncthreads();
    }
    const float s512 = sqrtf(512.0f);
    const float* sqb = sq + z*NTOK;
    float tmax = 0.f;
    #pragma unroll
    for (int ii = 0; ii < 4; ++ii) {
        int m = m0 + ty*4 + ii;
        float sm = sqb[m];
        #pragma unroll
        for (int jj = 0; jj < 4; ++jj) {
            int n = n0 + tx*4 + jj;
            float d2 = sm + sqb[n] - 2.0f*acc[ii][jj];
            float d = sqrtf(fmaxf(d2, 0.0f)) / s512;
            dist[((size_t)(z*NTOK + m))*NTOK + n] = d;
            tmax = fmaxf(tmax, d);
        }
    }
    // block-reduce max, one atomic per block
    __shared__ float redm[4];
    #pragma unroll
    for (int off = 32; off; off >>= 1) tmax = fmaxf(tmax, __shfl_xor(tmax, off, 64));
    if ((t & 63) == 0) redm[t >> 6] = tmax;
    __syncthreads();
    if (t == 0) {
        float m = fmaxf(fmaxf(redm[0], redm[1]), fmaxf(redm[2], redm[3]));
        atomicMax(&dmaxU[z], __float_as_uint(m));
    }
}

// density = exp(-mean of 5 smallest dist^2) ; one wave per row
__global__ void knn_dens(const float* __restrict__ dist, float* __restrict__ dens) {
    int row = blockIdx.x*4 + (threadIdx.x >> 6);
    int lane = threadIdx.x & 63;
    const float* dr = dist + (size_t)row*NTOK;
    float v0 = dr[lane], v1 = dr[lane+64], v2 = dr[lane+128], v3 = dr[lane+192];
    float acc = 0.f;
    #pragma unroll
    for (int it = 0; it < 5; ++it) {
        float lm = fminf(fminf(v0, v1), fminf(v2, v3));
        float gm = lm;
        #pragma unroll
        for (int off = 32; off; off >>= 1) gm = fminf(gm, __shfl_xor(gm, off, 64));
        acc += gm*gm;
        ull ball = __ballot(lm == gm);
        int first = __ffsll(ball) - 1;
        if (lane == first) {
            if      (v0 == gm) v0 = 1e30f;
            else if (v1 == gm) v1 = 1e30f;
            else if (v2 == gm) v2 = 1e30f;
            else               v3 = 1e30f;
        }
    }
    if (lane == 0) dens[row] = expf(-(acc/5.0f));
}

// parent_dist = min_j (dens_j > dens_i ? dist_ij : dmax); score = pd * dens_i
__global__ void parent_score(const float* __restrict__ dist, const float* __restrict__ dens,
                             const unsigned* __restrict__ dmaxU, float* __restrict__ score) {
    int row = blockIdx.x*4 + (threadIdx.x >> 6);
    int lane = threadIdx.x & 63;
    int b = row >> 8;
    float di = dens[row];
    float dm = __uint_as_float(dmaxU[b]);
    const float* dr = dist + (size_t)row*NTOK;
    const float* db = dens + (size_t)b*NTOK;
    float pd = dm;
    #pragma unroll
    for (int r = 0; r < 4; ++r) {
        int j = lane + 64*r;
        pd = fminf(pd, (db[j] > di) ? dr[j] : dm);
    }
    #pragma unroll
    for (int off = 32; off; off >>= 1) pd = fminf(pd, __shfl_xor(pd, off, 64));
    if (lane == 0) score[row] = pd * di;
}

// top-64 scores per batch, descending, lower index first on ties. one wave per batch.
__global__ void topk64(const float* __restrict__ score, int* __restrict__ ind) {
    int b = blockIdx.x, lane = threadIdx.x;
    const float* sb = score + b*NTOK;
    ull k0, k1, k2, k3;
    {
        unsigned i0 = lane, i1 = lane+64, i2 = lane+128, i3 = lane+192;
        k0 = ((ull)(__float_as_uint(sb[i0]) + 1u) << 32) | (unsigned)(4095 - i0);
        k1 = ((ull)(__float_as_uint(sb[i1]) + 1u) << 32) | (unsigned)(4095 - i1);
        k2 = ((ull)(__float_as_uint(sb[i2]) + 1u) << 32) | (unsigned)(4095 - i2);
        k3 = ((ull)(__float_as_uint(sb[i3]) + 1u) << 32) | (unsigned)(4095 - i3);
    }
    for (int it = 0; it < 64; ++it) {
        ull lm = k0;
        if (k1 > lm) lm = k1;
        if (k2 > lm) lm = k2;
        if (k3 > lm) lm = k3;
        ull gm = lm;
        #pragma unroll
        for (int off = 32; off; off >>= 1) {
            ull o = __shfl_xor(gm, off, 64);
            if (o > gm) gm = o;
        }
        if (lane == 0) ind[b*NS + it] = 4095 - (int)(gm & 0xffffffffull);
        if      (k0 == gm) k0 = 0;
        else if (k1 == gm) k1 = 0;
        else if (k2 == gm) k2 = 0;
        else if (k3 == gm) k3 = 0;
    }
}

// idx_cluster[i] = argmin_s dist[center_s][i] (first min). one wave per token.
__global__ void assign_k(const float* __restrict__ dist, const int* __restrict__ ind,
                         int* __restrict__ idxcl) {
    int row = blockIdx.x*4 + (threadIdx.x >> 6);   // b*256+i
    int lane = threadIdx.x & 63;
    int b = row >> 8, i = row & 255;
    int center = ind[b*NS + lane];
    float d = dist[((size_t)(b*NTOK + center))*NTOK + i];
    ull key = ((ull)__float_as_uint(d) << 32) | (unsigned)lane;
    #pragma unroll
    for (int off = 32; off; off >>= 1) {
        ull o = __shfl_xor(key, off, 64);
        if (o < key) key = o;
    }
    if (lane == 0) idxcl[row] = (int)(key & 0xffffffffull);
}

__global__ void center_set(const int* __restrict__ ind, int* __restrict__ idxcl) {
    int id = threadIdx.x;   // 512
    int b = id >> 6, s = id & 63;
    idxcl[b*NTOK + ind[id]] = s;
}

__global__ void allw_acc(const int* __restrict__ idxcl, const float* __restrict__ wexp,
                         float* __restrict__ allw) {
    int b = blockIdx.x, i = threadIdx.x;
    atomicAdd(&allw[b*NS + idxcl[b*NTOK + i]], wexp[b*NTOK + i]);
}

__global__ void normw_k(const int* __restrict__ idxcl, const float* __restrict__ wexp,
                        const float* __restrict__ allw, float* __restrict__ normw) {
    int b = blockIdx.x, i = threadIdx.x;
    normw[b*NTOK + i] = wexp[b*NTOK + i] / (allw[b*NS + idxcl[b*NTOK + i]] + EPS);
}

// x_down accumulated directly into d_out (pre-zeroed)
__global__ void merge_k(const float* __restrict__ xtok, const int* __restrict__ idxcl,
                        const float* __restrict__ normw, float* __restrict__ xout) {
    int row = blockIdx.x, t = threadIdx.x;
    int b = row >> 8;
    int cl = idxcl[row];
    float nw = normw[row];
    float* o = xout + ((size_t)(b*NS + cl))*NCO;
    const float* xr = xtok + (size_t)row*NCO;
    atomicAdd(&o[t],       xr[t]       * nw);
    atomicAdd(&o[t + 256], xr[t + 256] * nw);
}

// write idx_agg_down + awbuf; per-block max reduce, ONE atomicMax per block (was: per thread -> 1.49ms serialization)
__global__ void out_idx_aw(const int* __restrict__ idxagg, const float* __restrict__ aggw,
                           const int* __restrict__ idxcl, const float* __restrict__ normw,
                           float* __restrict__ dout, float* __restrict__ awbuf,
                           unsigned* __restrict__ maxw) {
    __shared__ float red[4];
    int bp = blockIdx.x*256 + threadIdx.x;
    int b = bp >> 14;                     // uniform within block (64 blocks per batch)
    int tok = idxagg[bp];
    int cl = idxcl[b*NTOK + tok];
    dout[(size_t)NB*NS*NCO + bp] = (float)cl;
    float aw = aggw[bp] * normw[b*NTOK + tok];
    awbuf[bp] = aw;
    float m = aw;
    #pragma unroll
    for (int off = 32; off; off >>= 1) m = fmaxf(m, __shfl_xor(m, off, 64));
    if ((threadIdx.x & 63) == 0) red[threadIdx.x >> 6] = m;
    __syncthreads();
    if (threadIdx.x == 0) {
        float mm = fmaxf(fmaxf(red[0], red[1]), fmaxf(red[2], red[3]));
        atomicMax(&maxw[b], __float_as_uint(mm));  // aw > 0: uint-bits compare == float compare
    }
}

__global__ void aw_final(const float* __restrict__ awbuf, const float* __restrict__ maxw,
                         float* __restrict__ dout) {
    int bp = blockIdx.x*256 + threadIdx.x;
    int b = bp >> 14;
    dout[(size_t)NB*NS*NCO + (size_t)NB*NP + bp] = awbuf[bp] / maxw[b];
}

// ---------------- launch ----------------
extern "C" void kernel_launch(void* const* d_in, const int* in_sizes, int n_in,
                              void* d_out, int out_size, void* d_ws, size_t ws_size,
                              hipStream_t stream) {
    const float* x      = (const float*)d_in[0];
    const float* loc    = (const float*)d_in[1];
    const int*   idxagg = (const int*)  d_in[2];
    const float* aggw   = (const float*)d_in[3];
    // d_in[4] idx_k_loc, d_in[5] H, d_in[6] W: unused (H=W=64 fixed by problem)
    const float* convw  = (const float*)d_in[7];
    const float* convb  = (const float*)d_in[8];
    const float* skipw  = (const float*)d_in[9];
    const float* lng    = (const float*)d_in[10];
    const float* lnb    = (const float*)d_in[11];
    const float* confw  = (const float*)d_in[12];
    const float* confb  = (const float*)d_in[13];

    float* ws = (float*)d_ws;
    float* dout = (float*)d_out;

    (void)hipMemsetAsync(ws, 0, ZERO_END*sizeof(float), stream);
    (void)hipMemsetAsync(dout, 0, (size_t)NB*NS*NCO*sizeof(float), stream);

    scatter_map<<<dim3(NB*NP), 256, 0, stream>>>(x, loc, idxagg, aggw,
                                                 ws + OFF_SUMS, ws + OFF_CNT, ws + OFF_AMAT);
    wtrans<<<dim3(KC*NCO/256), 256, 0, stream>>>(convw, ws + OFF_WT);
    skiptrans<<<dim3(CIN*NCO/256), 256, 0, stream>>>(skipw, ws + OFF_SKWT);
    finalize_map<<<dim3((NB*HW64*CIN/4)/256), 256, 0, stream>>>((float4*)(ws + OFF_SUMS), ws + OFF_CNT);

    conv_gemm<<<dim3(128, 8), 256, 0, stream>>>(ws + OFF_SUMS, ws + OFF_WT, convb, ws + OFF_Y);

    wsum_rows<<<dim3(NB*NTOK/4), 256, 0, stream>>>(ws + OFF_AMAT, ws + OFF_WSUM);
    // ssum = Amat @ y : M=256,N=512,K=1024 per batch
    gemm64<<<dim3(8, 4, 8), 256, 0, stream>>>(ws + OFF_AMAT, ws + OFF_Y, ws + OFF_C2,
                                              OHW, NCO,
                                              (long)NTOK*OHW, (long)OHW*NCO, (long)NTOK*NCO);
    // xskip = x @ skip_wt : M=2048,N=512,K=256
    gemm64<<<dim3(8, 32, 1), 256, 0, stream>>>(x, ws + OFF_SKWT, ws + OFF_XSKIP,
                                               CIN, NCO, 0, 0, 0);

    ln_conf<<<dim3(NB*NTOK), 256, 0, stream>>>(ws + OFF_C2, ws + OFF_WSUM, ws + OFF_XSKIP,
                                               lng, lnb, confw, confb,
                                               ws + OFF_XTOK, ws + OFF_WEXP, ws + OFF_SQ);

    xtok_trans<<<dim3(NB*NCO*NTOK/256), 256, 0, stream>>>(ws + OFF_XTOK, ws + OFF_XTOKT);
    dist_gemm<<<dim3(4, 4, 8), 256, 0, stream>>>(ws + OFF_XTOK, ws + OFF_XTOKT, ws + OFF_SQ,
                                                 ws + OFF_DIST, (unsigned*)(ws + OFF_DMAX));

    knn_dens<<<dim3(NB*NTOK/4), 256, 0, stream>>>(ws + OFF_DIST, ws + OFF_DENS);
    parent_score<<<dim3(NB*NTOK/4), 256, 0, stream>>>(ws + OFF_DIST, ws + OFF_DENS,
                                                      (const unsigned*)(ws + OFF_DMAX), ws + OFF_SCORE);
    topk64<<<dim3(NB), 64, 0, stream>>>(ws + OFF_SCORE, (int*)(ws + OFF_IND));
    assign_k<<<dim3(NB*NTOK/4), 256, 0, stream>>>(ws + OFF_DIST, (const int*)(ws + OFF_IND),
                                                  (int*)(ws + OFF_IDXCL));
    center_set<<<dim3(1), 512, 0, stream>>>((const int*)(ws + OFF_IND), (int*)(ws + OFF_IDXCL));
    allw_acc<<<dim3(NB), 256, 0, stream>>>((const int*)(ws + OFF_IDXCL), ws + OFF_WEXP, ws + OFF_ALLW);
    normw_k<<<dim3(NB), 256, 0, stream>>>((const int*)(ws + OFF_IDXCL), ws + OFF_WEXP,
                                          ws + OFF_ALLW, ws + OFF_NORMW);
    merge_k<<<dim3(NB*NTOK), 256, 0, stream>>>(ws + OFF_XTOK, (const int*)(ws + OFF_IDXCL),
                                               ws + OFF_NORMW, dout);
    out_idx_aw<<<dim3(NB*NP/256), 256, 0, stream>>>(idxagg, aggw, (const int*)(ws + OFF_IDXCL),
                                                    ws + OFF_NORMW, dout, ws + OFF_AWBUF,
                                                    (unsigned*)(ws + OFF_MAXW));
    aw_final<<<dim3(NB*NP/256), 256, 0, stream>>>(ws + OFF_AWBUF, (const float*)(ws + OFF_MAXW), dout);
}

// Round 3
// 514.340 us; speedup vs baseline: 4.2889x; 1.3328x over previous
//
#include <hip/hip_runtime.h>
#include <math.h>

typedef unsigned long long ull;
typedef __attribute__((ext_vector_type(8))) short short8v;   // 8 bf16 in 4 VGPRs
typedef __attribute__((ext_vector_type(4))) float float4v;

#define NB   8
#define NTOK 256
#define CIN  256
#define NP   16384
#define NCO  512
#define HW64 4096
#define OHW  1024
#define NS   64
#define EPS  1e-6f
#define KC   2304   // 9*256 conv K

// ---------------- workspace layout (float offsets) ----------------
constexpr size_t OFF_SUMS = 0;                                   // 8*4096*256 (zero) -> x_map, repacked hi|lo in place
constexpr size_t OFF_CNT  = OFF_SUMS + (size_t)NB*HW64*CIN;      // 8*4096 (zero)
constexpr size_t OFF_AMAT = OFF_CNT  + (size_t)NB*HW64;          // 8*256*1024 (zero) tok x cell32 weights
constexpr size_t OFF_ALLW = OFF_AMAT + (size_t)NB*NTOK*OHW;      // 8*64 (zero)
constexpr size_t OFF_DMAX = OFF_ALLW + (size_t)NB*NS;            // 8 (zero, uint bits)
constexpr size_t OFF_MAXW = OFF_DMAX + NB;                       // 8 (zero, uint bits)
constexpr size_t ZERO_END = OFF_MAXW + NB;
constexpr size_t OFF_WT   = ZERO_END;                            // 512*2304 packed hi|lo, [cout][k]
constexpr size_t OFF_SKWT = OFF_WT   + (size_t)KC*NCO;           // 256*512
constexpr size_t OFF_Y    = OFF_SKWT + (size_t)CIN*NCO;          // 8*1024*512 conv out (B,cell32,Cout) f32
constexpr size_t OFF_C2   = OFF_Y    + (size_t)NB*OHW*NCO;       // 8*256*512 ssum
constexpr size_t OFF_WSUM = OFF_C2   + (size_t)NB*NTOK*NCO;      // 2048
constexpr size_t OFF_XSKIP= OFF_WSUM + (size_t)NB*NTOK;          // 8*256*512
constexpr size_t OFF_XTOK = OFF_XSKIP+ (size_t)NB*NTOK*NCO;      // 8*256*512
constexpr size_t OFF_XTOKT= OFF_XTOK + (size_t)NB*NTOK*NCO;      // 8*512*256
constexpr size_t OFF_WEXP = OFF_XTOKT+ (size_t)NB*NTOK*NCO;      // 2048
constexpr size_t OFF_SQ   = OFF_WEXP + (size_t)NB*NTOK;          // 2048
constexpr size_t OFF_DIST = OFF_SQ   + (size_t)NB*NTOK;          // 8*256*256
constexpr size_t OFF_DENS = OFF_DIST + (size_t)NB*NTOK*NTOK;     // 2048
constexpr size_t OFF_SCORE= OFF_DENS + (size_t)NB*NTOK;          // 2048
constexpr size_t OFF_IND  = OFF_SCORE+ (size_t)NB*NTOK;          // 512 (int)
constexpr size_t OFF_IDXCL= OFF_IND  + (size_t)NB*NS;            // 2048 (int)
constexpr size_t OFF_NORMW= OFF_IDXCL+ (size_t)NB*NTOK;          // 2048
constexpr size_t OFF_AWBUF= OFF_NORMW+ (size_t)NB*NTOK;          // 8*16384

// pack fp32 -> (bf16_hi << 16) | bf16_lo, both RNE; hi+lo reconstructs x to ~2^-17 rel
__device__ __forceinline__ unsigned pack_hl(float x) {
    unsigned u = __float_as_uint(x);
    unsigned t = u + 0x7fffu + ((u >> 16) & 1u);
    unsigned hibits = t & 0xffff0000u;
    float lo = x - __uint_as_float(hibits);
    unsigned ul = __float_as_uint(lo);
    unsigned lt = ul + 0x7fffu + ((ul >> 16) & 1u);
    return hibits | (lt >> 16);
}
// v_perm packers: result = [hi16(w0), hi16(w1)] / [lo16(w0), lo16(w1)]
__device__ __forceinline__ unsigned hp2(unsigned w0, unsigned w1) {
    return __builtin_amdgcn_perm(w1, w0, 0x07060302u);
}
__device__ __forceinline__ unsigned lp2(unsigned w0, unsigned w1) {
    return __builtin_amdgcn_perm(w1, w0, 0x05040100u);
}

// ---------------- kernels ----------------

// one block per point: scatter x row into sums[cell64], count, and agg_weight into Amat[tok][cell32]
__global__ void scatter_map(const float* __restrict__ x, const float* __restrict__ loc,
                            const int* __restrict__ idxagg, const float* __restrict__ aggw,
                            float* __restrict__ sums, float* __restrict__ cnt,
                            float* __restrict__ amat) {
    int bp = blockIdx.x;              // b*16384+p
    int b  = bp >> 14;
    float lx = loc[2*bp+0], ly = loc[2*bp+1];
    lx = fminf(fmaxf(lx, -1.f), 1.f);
    ly = fminf(fmaxf(ly, -1.f), 1.f);
    int px = (int)rintf((lx + 1.f)*32.f - 0.5f); px = min(max(px,0),63);
    int py = (int)rintf((ly + 1.f)*32.f - 0.5f); py = min(max(py,0),63);
    int cell = py*64 + px;
    int tok = idxagg[bp];
    const float* xr = x    + ((size_t)(b*NTOK + tok))*CIN;
    float*       sr = sums + ((size_t)(b*HW64 + cell))*CIN;
    int t = threadIdx.x;
    atomicAdd(sr + t, xr[t]);
    if (t == 0) {
        atomicAdd(cnt + b*HW64 + cell, 1.0f);
        int qx = (int)rintf((lx + 1.f)*16.f - 0.5f); qx = min(max(qx,0),31);
        int qy = (int)rintf((ly + 1.f)*16.f - 0.5f); qy = min(max(qy,0),31);
        atomicAdd(amat + ((size_t)(b*NTOK + tok))*OHW + qy*32 + qx, aggw[bp]);
    }
}

// divide by count and REPACK IN PLACE to (bf16hi<<16)|bf16lo for the MFMA conv
__global__ void finalize_map(unsigned* __restrict__ sums_u, const float* __restrict__ cnt) {
    size_t i = (size_t)blockIdx.x*256 + threadIdx.x;      // float4 index, total 2097152
    float c = cnt[i >> 6] + EPS;
    float4 v = ((float4*)sums_u)[i];
    uint4 o;
    o.x = pack_hl(v.x / c); o.y = pack_hl(v.y / c);
    o.z = pack_hl(v.z / c); o.w = pack_hl(v.w / c);
    ((uint4*)sums_u)[i] = o;
}

// wt_t[cout][k] packed hi|lo, k=(ky*3+kx)*256+cin
__global__ void wtrans(const float* __restrict__ convw, unsigned* __restrict__ wt) {
    int id = blockIdx.x*256 + threadIdx.x;   // 512*2304 = 1179648
    int cout = id / KC, k = id - cout*KC;
    int grp = k >> 8, cin = k & 255;
    wt[id] = pack_hl(convw[(size_t)cout*KC + cin*9 + grp]);
}

__global__ void skiptrans(const float* __restrict__ skipw, float* __restrict__ skwt) {
    int id = blockIdx.x*256 + threadIdx.x;   // 131072
    int o = id & 511, k = id >> 9;
    skwt[id] = skipw[(size_t)o*CIN + k];
}

// split-bf16 3-pass MFMA implicit-GEMM conv:
// y[pos][cout] = sum_k patch[pos][k]*W[k][cout] + b[cout]
// block tile: 64 pos x 64 cout; 4 waves, each 32x32 via 2x2 mfma_f32_16x16x32_bf16 tiles
__launch_bounds__(256)
__global__ void conv_gemm(const unsigned* __restrict__ xmap, const unsigned* __restrict__ wt,
                          const float* __restrict__ convb, float* __restrict__ y) {
    __shared__ __align__(16) unsigned short Ahi[64][40], Alo[64][40];  // [pos][k] pad->80B rows
    __shared__ __align__(16) unsigned short Bhi[64][40], Blo[64][40];  // [cout][k]
    int n0 = blockIdx.x*64;   // pos tile (8192/64 = 128)
    int m0 = blockIdx.y*64;   // cout tile (512/64 = 8)
    int t = threadIdx.x;
    int lane = t & 63, wid = t >> 6;
    int wy = wid >> 1, wx = wid & 1;          // wave -> (pos half, cout half)
    int l15 = lane & 15, l4 = lane >> 4;

    // staging mapping: thread -> (row 0..63, k8 0..3), 8 consecutive k
    int rowL = t & 63, k8 = t >> 6;
    int posG = n0 + rowL;
    int bb = posG >> 10, rem = posG & 1023;
    int oy = rem >> 5, ox = rem & 31;
    const unsigned* wrow = wt + (size_t)(m0 + rowL)*KC + k8*8;

    float4v acc[2][2] = {};

    for (int kc = 0; kc < KC/32; ++kc) {
        int grp = kc >> 3;                    // 32 | 256 so one grp per chunk
        int ky = grp/3, kx = grp - ky*3;
        int cinb = (kc & 7)*32 + k8*8;
        int iy = 2*oy - 1 + ky, ix = 2*ox - 1 + kx;

        uint4 a0 = {}, a1 = {};
        if ((unsigned)iy < 64u && (unsigned)ix < 64u) {
            const unsigned* xp = xmap + ((((size_t)bb*64 + iy)*64 + ix)*256 + cinb);
            a0 = *(const uint4*)xp;
            a1 = *(const uint4*)(xp + 4);
        }
        const unsigned* wp = wrow + kc*32;
        uint4 b0 = *(const uint4*)wp;
        uint4 b1 = *(const uint4*)(wp + 4);

        __syncthreads();   // previous iteration's frag reads done
        uint4 h, l;
        h.x = hp2(a0.x,a0.y); h.y = hp2(a0.z,a0.w); h.z = hp2(a1.x,a1.y); h.w = hp2(a1.z,a1.w);
        l.x = lp2(a0.x,a0.y); l.y = lp2(a0.z,a0.w); l.z = lp2(a1.x,a1.y); l.w = lp2(a1.z,a1.w);
        *(uint4*)&Ahi[rowL][k8*8] = h;
        *(uint4*)&Alo[rowL][k8*8] = l;
        h.x = hp2(b0.x,b0.y); h.y = hp2(b0.z,b0.w); h.z = hp2(b1.x,b1.y); h.w = hp2(b1.z,b1.w);
        l.x = lp2(b0.x,b0.y); l.y = lp2(b0.z,b0.w); l.z = lp2(b1.x,b1.y); l.w = lp2(b1.z,b1.w);
        *(uint4*)&Bhi[rowL][k8*8] = h;
        *(uint4*)&Blo[rowL][k8*8] = l;
        __syncthreads();

        short8v ah[2], al[2], bh[2], bl[2];
        #pragma unroll
        for (int p = 0; p < 2; ++p) {
            int r = wy*32 + p*16 + l15;
            ah[p] = *(const short8v*)&Ahi[r][l4*8];
            al[p] = *(const short8v*)&Alo[r][l4*8];
        }
        #pragma unroll
        for (int q = 0; q < 2; ++q) {
            int c = wx*32 + q*16 + l15;
            bh[q] = *(const short8v*)&Bhi[c][l4*8];
            bl[q] = *(const short8v*)&Blo[c][l4*8];
        }
        #pragma unroll
        for (int p = 0; p < 2; ++p)
            #pragma unroll
            for (int q = 0; q < 2; ++q) {
                acc[p][q] = __builtin_amdgcn_mfma_f32_16x16x32_bf16(ah[p], bh[q], acc[p][q], 0, 0, 0);
                acc[p][q] = __builtin_amdgcn_mfma_f32_16x16x32_bf16(ah[p], bl[q], acc[p][q], 0, 0, 0);
                acc[p][q] = __builtin_amdgcn_mfma_f32_16x16x32_bf16(al[p], bh[q], acc[p][q], 0, 0, 0);
            }
    }

    #pragma unroll
    for (int p = 0; p < 2; ++p) {
        int rowbase = n0 + wy*32 + p*16 + l4*4;
        #pragma unroll
        for (int q = 0; q < 2; ++q) {
            int col = m0 + wx*32 + q*16 + l15;
            float bv = convb[col];
            #pragma unroll
            for (int r = 0; r < 4; ++r)
                y[(size_t)(rowbase + r)*NCO + col] = acc[p][q][r] + bv;
        }
    }
}

// generic 64x64-tile fp32 GEMM
__launch_bounds__(256)
__global__ void gemm64(const float* __restrict__ A, const float* __restrict__ Bm,
                       float* __restrict__ Cc, int K, int Ncols,
                       long sA, long sB, long sC) {
    __shared__ __align__(16) float As[16][68];
    __shared__ __align__(16) float Bs[16][68];
    const float* Ab = A  + (size_t)blockIdx.z * sA;
    const float* Bb = Bm + (size_t)blockIdx.z * sB;
    float*       Cb = Cc + (size_t)blockIdx.z * sC;
    int n0 = blockIdx.x*64, m0 = blockIdx.y*64;
    int t = threadIdx.x, tx = t & 15, ty = t >> 4;
    float acc[4][4] = {};
    int kkA = t & 15, mbA = t >> 4;
    int nB  = t & 63, kbB = t >> 6;
    for (int ko = 0; ko < K; ko += 16) {
        #pragma unroll
        for (int r = 0; r < 4; ++r) {
            int m = mbA + 16*r;
            As[kkA][m] = Ab[(size_t)(m0 + m)*K + ko + kkA];
        }
        #pragma unroll
        for (int r = 0; r < 4; ++r) {
            int kk = kbB + 4*r;
            Bs[kk][nB] = Bb[(size_t)(ko + kk)*Ncols + n0 + nB];
        }
        __syncthreads();
        #pragma unroll
        for (int kk = 0; kk < 16; ++kk) {
            float4 a  = *(const float4*)&As[kk][ty*4];
            float4 bv = *(const float4*)&Bs[kk][tx*4];
            acc[0][0]+=a.x*bv.x; acc[0][1]+=a.x*bv.y; acc[0][2]+=a.x*bv.z; acc[0][3]+=a.x*bv.w;
            acc[1][0]+=a.y*bv.x; acc[1][1]+=a.y*bv.y; acc[1][2]+=a.y*bv.z; acc[1][3]+=a.y*bv.w;
            acc[2][0]+=a.z*bv.x; acc[2][1]+=a.z*bv.y; acc[2][2]+=a.z*bv.z; acc[2][3]+=a.z*bv.w;
            acc[3][0]+=a.w*bv.x; acc[3][1]+=a.w*bv.y; acc[3][2]+=a.w*bv.z; acc[3][3]+=a.w*bv.w;
        }
        __syncthreads();
    }
    #pragma unroll
    for (int ii = 0; ii < 4; ++ii) {
        float4 o = make_float4(acc[ii][0], acc[ii][1], acc[ii][2], acc[ii][3]);
        *(float4*)&Cb[(size_t)(m0 + ty*4 + ii)*Ncols + n0 + tx*4] = o;
    }
}

// row sums of Amat -> wsum  (one wave per row)
__global__ void wsum_rows(const float* __restrict__ amat, float* __restrict__ wsum) {
    int row = blockIdx.x*4 + (threadIdx.x >> 6);
    int lane = threadIdx.x & 63;
    const float* ar = amat + (size_t)row*OHW;
    float s = 0.f;
    #pragma unroll
    for (int r = 0; r < 16; ++r) s += ar[lane + 64*r];
    #pragma unroll
    for (int off = 32; off; off >>= 1) s += __shfl_xor(s, off, 64);
    if (lane == 0) wsum[row] = s;
}

__device__ __forceinline__ float block_sum256(float v, float* red) {
    #pragma unroll
    for (int off = 32; off; off >>= 1) v += __shfl_xor(v, off, 64);
    __syncthreads();
    if ((threadIdx.x & 63) == 0) red[threadIdx.x >> 6] = v;
    __syncthreads();
    return red[0] + red[1] + red[2] + red[3];
}

// x_tok = LN(C2/(wsum+eps) + xskip)*g + b ; conf -> wexp ; sq = sum(x_tok^2)
__global__ void ln_conf(const float* __restrict__ C2, const float* __restrict__ wsum,
                        const float* __restrict__ xskip, const float* __restrict__ g,
                        const float* __restrict__ be, const float* __restrict__ confw,
                        const float* __restrict__ confb, float* __restrict__ xtok,
                        float* __restrict__ wexp, float* __restrict__ sqv) {
    __shared__ float red[4];
    int row = blockIdx.x, t = threadIdx.x;
    float ws = wsum[row] + EPS;
    size_t base = (size_t)row*NCO;
    float v0 = C2[base + t]       / ws + xskip[base + t];
    float v1 = C2[base + t + 256] / ws + xskip[base + t + 256];
    float mu  = block_sum256(v0 + v1, red) / 512.0f;
    float d0 = v0 - mu, d1 = v1 - mu;
    float var = block_sum256(d0*d0 + d1*d1, red) / 512.0f;
    float sv = sqrtf(var + 1e-5f);
    float x0 = d0/sv * g[t]       + be[t];
    float x1 = d1/sv * g[t + 256] + be[t + 256];
    xtok[base + t] = x0;
    xtok[base + t + 256] = x1;
    float cs = block_sum256(x0*confw[t] + x1*confw[t + 256], red);
    float qs = block_sum256(x0*x0 + x1*x1, red);
    if (t == 0) {
        wexp[row] = expf(cs + confb[0]);
        sqv[row]  = qs;
    }
}

__global__ void xtok_trans(const float* __restrict__ xtok, float* __restrict__ xtokt) {
    size_t id = (size_t)blockIdx.x*256 + threadIdx.x;   // over 8*512*256
    int n = (int)(id & 255);
    int c = (int)((id >> 8) & 511);
    int b = (int)(id >> 17);
    xtokt[id] = xtok[((size_t)(b*NTOK + n))*NCO + c];
}

// dist[i][j] = sqrt(max(sq_i+sq_j-2*G,0))/sqrt(512); track per-batch max
__launch_bounds__(256)
__global__ void dist_gemm(const float* __restrict__ xtok, const float* __restrict__ xtokt,
                          const float* __restrict__ sq, float* __restrict__ dist,
                          unsigned* __restrict__ dmaxU) {
    __shared__ __align__(16) float As[16][68];
    __shared__ __align__(16) float Bs[16][68];
    int z = blockIdx.z;
    const float* Ab = xtok  + (size_t)z*NTOK*NCO;
    const float* Bb = xtokt + (size_t)z*NCO*NTOK;
    int n0 = blockIdx.x*64, m0 = blockIdx.y*64;
    int t = threadIdx.x, tx = t & 15, ty = t >> 4;
    float acc[4][4] = {};
    int kkA = t & 15, mbA = t >> 4;
    int nB  = t & 63, kbB = t >> 6;
    for (int ko = 0; ko < NCO; ko += 16) {
        #pragma unroll
        for (int r = 0; r < 4; ++r) {
            int m = mbA + 16*r;
            As[kkA][m] = Ab[(size_t)(m0 + m)*NCO + ko + kkA];
        }
        #pragma unroll
        for (int r = 0; r < 4; ++r) {
            int kk = kbB + 4*r;
            Bs[kk][nB] = Bb[(size_t)(ko + kk)*NTOK + n0 + nB];
        }
        __syncthreads();
        #pragma unroll
        for (int kk = 0; kk < 16; ++kk) {
            float4 a  = *(const float4*)&As[kk][ty*4];
            float4 bv = *(const float4*)&Bs[kk][tx*4];
            acc[0][0]+=a.x*bv.x; acc[0][1]+=a.x*bv.y; acc[0][2]+=a.x*bv.z; acc[0][3]+=a.x*bv.w;
            acc[1][0]+=a.y*bv.x; acc[1][1]+=a.y*bv.y; acc[1][2]+=a.y*bv.z; acc[1][3]+=a.y*bv.w;
            acc[2][0]+=a.z*bv.x; acc[2][1]+=a.z*bv.y; acc[2][2]+=a.z*bv.z; acc[2][3]+=a.z*bv.w;
            acc[3][0]+=a.w*bv.x; acc[3][1]+=a.w*bv.y; acc[3][2]+=a.w*bv.z; acc[3][3]+=a.w*bv.w;
        }
        __syncthreads();
    }
    const float s512 = sqrtf(512.0f);
    const float* sqb = sq + z*NTOK;
    float tmax = 0.f;
    #pragma unroll
    for (int ii = 0; ii < 4; ++ii) {
        int m = m0 + ty*4 + ii;
        float sm = sqb[m];
        #pragma unroll
        for (int jj = 0; jj < 4; ++jj) {
            int n = n0 + tx*4 + jj;
            float d2 = sm + sqb[n] - 2.0f*acc[ii][jj];
            float d = sqrtf(fmaxf(d2, 0.0f)) / s512;
            dist[((size_t)(z*NTOK + m))*NTOK + n] = d;
            tmax = fmaxf(tmax, d);
        }
    }
    __shared__ float redm[4];
    #pragma unroll
    for (int off = 32; off; off >>= 1) tmax = fmaxf(tmax, __shfl_xor(tmax, off, 64));
    if ((t & 63) == 0) redm[t >> 6] = tmax;
    __syncthreads();
    if (t == 0) {
        float m = fmaxf(fmaxf(redm[0], redm[1]), fmaxf(redm[2], redm[3]));
        atomicMax(&dmaxU[z], __float_as_uint(m));
    }
}

// density = exp(-mean of 5 smallest dist^2) ; one wave per row
__global__ void knn_dens(const float* __restrict__ dist, float* __restrict__ dens) {
    int row = blockIdx.x*4 + (threadIdx.x >> 6);
    int lane = threadIdx.x & 63;
    const float* dr = dist + (size_t)row*NTOK;
    float v0 = dr[lane], v1 = dr[lane+64], v2 = dr[lane+128], v3 = dr[lane+192];
    float acc = 0.f;
    #pragma unroll
    for (int it = 0; it < 5; ++it) {
        float lm = fminf(fminf(v0, v1), fminf(v2, v3));
        float gm = lm;
        #pragma unroll
        for (int off = 32; off; off >>= 1) gm = fminf(gm, __shfl_xor(gm, off, 64));
        acc += gm*gm;
        ull ball = __ballot(lm == gm);
        int first = __ffsll(ball) - 1;
        if (lane == first) {
            if      (v0 == gm) v0 = 1e30f;
            else if (v1 == gm) v1 = 1e30f;
            else if (v2 == gm) v2 = 1e30f;
            else               v3 = 1e30f;
        }
    }
    if (lane == 0) dens[row] = expf(-(acc/5.0f));
}

// parent_dist = min_j (dens_j > dens_i ? dist_ij : dmax); score = pd * dens_i
__global__ void parent_score(const float* __restrict__ dist, const float* __restrict__ dens,
                             const unsigned* __restrict__ dmaxU, float* __restrict__ score) {
    int row = blockIdx.x*4 + (threadIdx.x >> 6);
    int lane = threadIdx.x & 63;
    int b = row >> 8;
    float di = dens[row];
    float dm = __uint_as_float(dmaxU[b]);
    const float* dr = dist + (size_t)row*NTOK;
    const float* db = dens + (size_t)b*NTOK;
    float pd = dm;
    #pragma unroll
    for (int r = 0; r < 4; ++r) {
        int j = lane + 64*r;
        pd = fminf(pd, (db[j] > di) ? dr[j] : dm);
    }
    #pragma unroll
    for (int off = 32; off; off >>= 1) pd = fminf(pd, __shfl_xor(pd, off, 64));
    if (lane == 0) score[row] = pd * di;
}

// top-64 scores per batch, descending, lower index first on ties. one wave per batch.
__global__ void topk64(const float* __restrict__ score, int* __restrict__ ind) {
    int b = blockIdx.x, lane = threadIdx.x;
    const float* sb = score + b*NTOK;
    ull k0, k1, k2, k3;
    {
        unsigned i0 = lane, i1 = lane+64, i2 = lane+128, i3 = lane+192;
        k0 = ((ull)(__float_as_uint(sb[i0]) + 1u) << 32) | (unsigned)(4095 - i0);
        k1 = ((ull)(__float_as_uint(sb[i1]) + 1u) << 32) | (unsigned)(4095 - i1);
        k2 = ((ull)(__float_as_uint(sb[i2]) + 1u) << 32) | (unsigned)(4095 - i2);
        k3 = ((ull)(__float_as_uint(sb[i3]) + 1u) << 32) | (unsigned)(4095 - i3);
    }
    for (int it = 0; it < 64; ++it) {
        ull lm = k0;
        if (k1 > lm) lm = k1;
        if (k2 > lm) lm = k2;
        if (k3 > lm) lm = k3;
        ull gm = lm;
        #pragma unroll
        for (int off = 32; off; off >>= 1) {
            ull o = __shfl_xor(gm, off, 64);
            if (o > gm) gm = o;
        }
        if (lane == 0) ind[b*NS + it] = 4095 - (int)(gm & 0xffffffffull);
        if      (k0 == gm) k0 = 0;
        else if (k1 == gm) k1 = 0;
        else if (k2 == gm) k2 = 0;
        else if (k3 == gm) k3 = 0;
    }
}

// idx_cluster[i] = argmin_s dist[center_s][i] (first min). one wave per token.
__global__ void assign_k(const float* __restrict__ dist, const int* __restrict__ ind,
                         int* __restrict__ idxcl) {
    int row = blockIdx.x*4 + (threadIdx.x >> 6);   // b*256+i
    int lane = threadIdx.x & 63;
    int b = row >> 8, i = row & 255;
    int center = ind[b*NS + lane];
    float d = dist[((size_t)(b*NTOK + center))*NTOK + i];
    ull key = ((ull)__float_as_uint(d) << 32) | (unsigned)lane;
    #pragma unroll
    for (int off = 32; off; off >>= 1) {
        ull o = __shfl_xor(key, off, 64);
        if (o < key) key = o;
    }
    if (lane == 0) idxcl[row] = (int)(key & 0xffffffffull);
}

__global__ void center_set(const int* __restrict__ ind, int* __restrict__ idxcl) {
    int id = threadIdx.x;   // 512
    int b = id >> 6, s = id & 63;
    idxcl[b*NTOK + ind[id]] = s;
}

__global__ void allw_acc(const int* __restrict__ idxcl, const float* __restrict__ wexp,
                         float* __restrict__ allw) {
    int b = blockIdx.x, i = threadIdx.x;
    atomicAdd(&allw[b*NS + idxcl[b*NTOK + i]], wexp[b*NTOK + i]);
}

__global__ void normw_k(const int* __restrict__ idxcl, const float* __restrict__ wexp,
                        const float* __restrict__ allw, float* __restrict__ normw) {
    int b = blockIdx.x, i = threadIdx.x;
    normw[b*NTOK + i] = wexp[b*NTOK + i] / (allw[b*NS + idxcl[b*NTOK + i]] + EPS);
}

// x_down accumulated directly into d_out (pre-zeroed)
__global__ void merge_k(const float* __restrict__ xtok, const int* __restrict__ idxcl,
                        const float* __restrict__ normw, float* __restrict__ xout) {
    int row = blockIdx.x, t = threadIdx.x;
    int b = row >> 8;
    int cl = idxcl[row];
    float nw = normw[row];
    float* o = xout + ((size_t)(b*NS + cl))*NCO;
    const float* xr = xtok + (size_t)row*NCO;
    atomicAdd(&o[t],       xr[t]       * nw);
    atomicAdd(&o[t + 256], xr[t + 256] * nw);
}

// write idx_agg_down + awbuf; per-block max reduce, ONE atomicMax per block
__global__ void out_idx_aw(const int* __restrict__ idxagg, const float* __restrict__ aggw,
                           const int* __restrict__ idxcl, const float* __restrict__ normw,
                           float* __restrict__ dout, float* __restrict__ awbuf,
                           unsigned* __restrict__ maxw) {
    __shared__ float red[4];
    int bp = blockIdx.x*256 + threadIdx.x;
    int b = bp >> 14;                     // uniform within block (64 blocks per batch)
    int tok = idxagg[bp];
    int cl = idxcl[b*NTOK + tok];
    dout[(size_t)NB*NS*NCO + bp] = (float)cl;
    float aw = aggw[bp] * normw[b*NTOK + tok];
    awbuf[bp] = aw;
    float m = aw;
    #pragma unroll
    for (int off = 32; off; off >>= 1) m = fmaxf(m, __shfl_xor(m, off, 64));
    if ((threadIdx.x & 63) == 0) red[threadIdx.x >> 6] = m;
    __syncthreads();
    if (threadIdx.x == 0) {
        float mm = fmaxf(fmaxf(red[0], red[1]), fmaxf(red[2], red[3]));
        atomicMax(&maxw[b], __float_as_uint(mm));
    }
}

__global__ void aw_final(const float* __restrict__ awbuf, const float* __restrict__ maxw,
                         float* __restrict__ dout) {
    int bp = blockIdx.x*256 + threadIdx.x;
    int b = bp >> 14;
    dout[(size_t)NB*NS*NCO + (size_t)NB*NP + bp] = awbuf[bp] / maxw[b];
}

// ---------------- launch ----------------
extern "C" void kernel_launch(void* const* d_in, const int* in_sizes, int n_in,
                              void* d_out, int out_size, void* d_ws, size_t ws_size,
                              hipStream_t stream) {
    const float* x      = (const float*)d_in[0];
    const float* loc    = (const float*)d_in[1];
    const int*   idxagg = (const int*)  d_in[2];
    const float* aggw   = (const float*)d_in[3];
    const float* convw  = (const float*)d_in[7];
    const float* convb  = (const float*)d_in[8];
    const float* skipw  = (const float*)d_in[9];
    const float* lng    = (const float*)d_in[10];
    const float* lnb    = (const float*)d_in[11];
    const float* confw  = (const float*)d_in[12];
    const float* confb  = (const float*)d_in[13];

    float* ws = (float*)d_ws;
    float* dout = (float*)d_out;

    (void)hipMemsetAsync(ws, 0, ZERO_END*sizeof(float), stream);
    (void)hipMemsetAsync(dout, 0, (size_t)NB*NS*NCO*sizeof(float), stream);

    scatter_map<<<dim3(NB*NP), 256, 0, stream>>>(x, loc, idxagg, aggw,
                                                 ws + OFF_SUMS, ws + OFF_CNT, ws + OFF_AMAT);
    wtrans<<<dim3(KC*NCO/256), 256, 0, stream>>>(convw, (unsigned*)(ws + OFF_WT));
    skiptrans<<<dim3(CIN*NCO/256), 256, 0, stream>>>(skipw, ws + OFF_SKWT);
    finalize_map<<<dim3((NB*HW64*CIN/4)/256), 256, 0, stream>>>((unsigned*)(ws + OFF_SUMS), ws + OFF_CNT);

    conv_gemm<<<dim3(128, 8), 256, 0, stream>>>((const unsigned*)(ws + OFF_SUMS),
                                                (const unsigned*)(ws + OFF_WT), convb, ws + OFF_Y);

    wsum_rows<<<dim3(NB*NTOK/4), 256, 0, stream>>>(ws + OFF_AMAT, ws + OFF_WSUM);
    gemm64<<<dim3(8, 4, 8), 256, 0, stream>>>(ws + OFF_AMAT, ws + OFF_Y, ws + OFF_C2,
                                              OHW, NCO,
                                              (long)NTOK*OHW, (long)OHW*NCO, (long)NTOK*NCO);
    gemm64<<<dim3(8, 32, 1), 256, 0, stream>>>(x, ws + OFF_SKWT, ws + OFF_XSKIP,
                                               CIN, NCO, 0, 0, 0);

    ln_conf<<<dim3(NB*NTOK), 256, 0, stream>>>(ws + OFF_C2, ws + OFF_WSUM, ws + OFF_XSKIP,
                                               lng, lnb, confw, confb,
                                               ws + OFF_XTOK, ws + OFF_WEXP, ws + OFF_SQ);

    xtok_trans<<<dim3(NB*NCO*NTOK/256), 256, 0, stream>>>(ws + OFF_XTOK, ws + OFF_XTOKT);
    dist_gemm<<<dim3(4, 4, 8), 256, 0, stream>>>(ws + OFF_XTOK, ws + OFF_XTOKT, ws + OFF_SQ,
                                                 ws + OFF_DIST, (unsigned*)(ws + OFF_DMAX));

    knn_dens<<<dim3(NB*NTOK/4), 256, 0, stream>>>(ws + OFF_DIST, ws + OFF_DENS);
    parent_score<<<dim3(NB*NTOK/4), 256, 0, stream>>>(ws + OFF_DIST, ws + OFF_DENS,
                                                      (const unsigned*)(ws + OFF_DMAX), ws + OFF_SCORE);
    topk64<<<dim3(NB), 64, 0, stream>>>(ws + OFF_SCORE, (int*)(ws + OFF_IND));
    assign_k<<<dim3(NB*NTOK/4), 256, 0, stream>>>(ws + OFF_DIST, (const int*)(ws + OFF_IND),
                                                  (int*)(ws + OFF_IDXCL));
    center_set<<<dim3(1), 512, 0, stream>>>((const int*)(ws + OFF_IND), (int*)(ws + OFF_IDXCL));
    allw_acc<<<dim3(NB), 256, 0, stream>>>((const int*)(ws + OFF_IDXCL), ws + OFF_WEXP, ws + OFF_ALLW);
    normw_k<<<dim3(NB), 256, 0, stream>>>((const int*)(ws + OFF_IDXCL), ws + OFF_WEXP,
                                          ws + OFF_ALLW, ws + OFF_NORMW);
    merge_k<<<dim3(NB*NTOK), 256, 0, stream>>>(ws + OFF_XTOK, (const int*)(ws + OFF_IDXCL),
                                               ws + OFF_NORMW, dout);
    out_idx_aw<<<dim3(NB*NP/256), 256, 0, stream>>>(idxagg, aggw, (const int*)(ws + OFF_IDXCL),
                                                    ws + OFF_NORMW, dout, ws + OFF_AWBUF,
                                                    (unsigned*)(ws + OFF_MAXW));
    aw_final<<<dim3(NB*NP/256), 256, 0, stream>>>(ws + OFF_AWBUF, (const float*)(ws + OFF_MAXW), dout);
}

// Round 4
// 446.390 us; speedup vs baseline: 4.9418x; 1.1522x over previous
//
#include <hip/hip_runtime.h>
#include <math.h>

typedef unsigned long long ull;
typedef __attribute__((ext_vector_type(8))) short short8v;   // 8 bf16 in 4 VGPRs
typedef __attribute__((ext_vector_type(4))) float float4v;

#define NB   8
#define NTOK 256
#define CIN  256
#define NP   16384
#define NCO  512
#define HW64 4096
#define OHW  1024
#define NS   64
#define EPS  1e-6f
#define KC   2304   // 9*256 conv K

// ---------------- workspace layout (float offsets) ----------------
constexpr size_t OFF_SUMS = 0;                                   // 8*4096*256 (zero) -> x_map packed; after conv: AMATP alias
constexpr size_t OFF_CNT  = OFF_SUMS + (size_t)NB*HW64*CIN;
constexpr size_t OFF_AMAT = OFF_CNT  + (size_t)NB*HW64;          // fp32 tok x cell32 weights
constexpr size_t OFF_ALLW = OFF_AMAT + (size_t)NB*NTOK*OHW;
constexpr size_t OFF_DMAX = OFF_ALLW + (size_t)NB*NS;
constexpr size_t OFF_MAXW = OFF_DMAX + NB;
constexpr size_t ZERO_END = OFF_MAXW + NB;
constexpr size_t OFF_WT   = ZERO_END;                            // 512*2304 packed hi|lo [cout][k]
constexpr size_t OFF_SKWT = OFF_WT   + (size_t)KC*NCO;           // 512*256 packed [cout][cin]
constexpr size_t OFF_Y    = OFF_SKWT + (size_t)CIN*NCO;          // yT packed [b][cout][cell]; after ssum: XTOKPK alias
constexpr size_t OFF_C2   = OFF_Y    + (size_t)NB*OHW*NCO;       // ssum fp32
constexpr size_t OFF_WSUM = OFF_C2   + (size_t)NB*NTOK*NCO;
constexpr size_t OFF_XSKIP= OFF_WSUM + (size_t)NB*NTOK;
constexpr size_t OFF_XTOK = OFF_XSKIP+ (size_t)NB*NTOK*NCO;      // fp32
constexpr size_t OFF_XPK  = OFF_XTOK + (size_t)NB*NTOK*NCO;      // x packed (512K; old XTOKT slot)
constexpr size_t OFF_WEXP = OFF_XPK  + (size_t)NB*NTOK*NCO;      // (keeps old layout width 1M)
constexpr size_t OFF_SQ   = OFF_WEXP + (size_t)NB*NTOK;
constexpr size_t OFF_DIST = OFF_SQ   + (size_t)NB*NTOK;
constexpr size_t OFF_DENS = OFF_DIST + (size_t)NB*NTOK*NTOK;
constexpr size_t OFF_SCORE= OFF_DENS + (size_t)NB*NTOK;
constexpr size_t OFF_IND  = OFF_SCORE+ (size_t)NB*NTOK;
constexpr size_t OFF_IDXCL= OFF_IND  + (size_t)NB*NS;
constexpr size_t OFF_NORMW= OFF_IDXCL+ (size_t)NB*NTOK;
constexpr size_t OFF_AWBUF= OFF_NORMW+ (size_t)NB*NTOK;
// aliases (regions dead by the time these are written)
constexpr size_t OFF_AMATP = OFF_SUMS;   // 2M uints, written after conv consumed xmap
constexpr size_t OFF_XTOKPK= OFF_Y;      // 1M uints, written after ssum consumed yT

// pack fp32 -> (bf16_hi << 16) | bf16_lo, both RNE; hi+lo reconstructs x to ~2^-17 rel
__device__ __forceinline__ unsigned pack_hl(float x) {
    unsigned u = __float_as_uint(x);
    unsigned t = u + 0x7fffu + ((u >> 16) & 1u);
    unsigned hibits = t & 0xffff0000u;
    float lo = x - __uint_as_float(hibits);
    unsigned ul = __float_as_uint(lo);
    unsigned lt = ul + 0x7fffu + ((ul >> 16) & 1u);
    return hibits | (lt >> 16);
}
__device__ __forceinline__ unsigned hp2(unsigned w0, unsigned w1) {
    return __builtin_amdgcn_perm(w1, w0, 0x07060302u);
}
__device__ __forceinline__ unsigned lp2(unsigned w0, unsigned w1) {
    return __builtin_amdgcn_perm(w1, w0, 0x05040100u);
}

// ---------------- scatter / prep ----------------
__global__ void scatter_map(const float* __restrict__ x, const float* __restrict__ loc,
                            const int* __restrict__ idxagg, const float* __restrict__ aggw,
                            float* __restrict__ sums, float* __restrict__ cnt,
                            float* __restrict__ amat) {
    int bp = blockIdx.x;
    int b  = bp >> 14;
    float lx = loc[2*bp+0], ly = loc[2*bp+1];
    lx = fminf(fmaxf(lx, -1.f), 1.f);
    ly = fminf(fmaxf(ly, -1.f), 1.f);
    int px = (int)rintf((lx + 1.f)*32.f - 0.5f); px = min(max(px,0),63);
    int py = (int)rintf((ly + 1.f)*32.f - 0.5f); py = min(max(py,0),63);
    int cell = py*64 + px;
    int tok = idxagg[bp];
    const float* xr = x    + ((size_t)(b*NTOK + tok))*CIN;
    float*       sr = sums + ((size_t)(b*HW64 + cell))*CIN;
    int t = threadIdx.x;
    atomicAdd(sr + t, xr[t]);
    if (t == 0) {
        atomicAdd(cnt + b*HW64 + cell, 1.0f);
        int qx = (int)rintf((lx + 1.f)*16.f - 0.5f); qx = min(max(qx,0),31);
        int qy = (int)rintf((ly + 1.f)*16.f - 0.5f); qy = min(max(qy,0),31);
        atomicAdd(amat + ((size_t)(b*NTOK + tok))*OHW + qy*32 + qx, aggw[bp]);
    }
}

__global__ void finalize_map(unsigned* __restrict__ sums_u, const float* __restrict__ cnt) {
    size_t i = (size_t)blockIdx.x*256 + threadIdx.x;
    float c = cnt[i >> 6] + EPS;
    float4 v = ((float4*)sums_u)[i];
    uint4 o;
    o.x = pack_hl(v.x / c); o.y = pack_hl(v.y / c);
    o.z = pack_hl(v.z / c); o.w = pack_hl(v.w / c);
    ((uint4*)sums_u)[i] = o;
}

__global__ void wtrans(const float* __restrict__ convw, unsigned* __restrict__ wt) {
    int id = blockIdx.x*256 + threadIdx.x;
    int cout = id / KC, k = id - cout*KC;
    int grp = k >> 8, cin = k & 255;
    wt[id] = pack_hl(convw[(size_t)cout*KC + cin*9 + grp]);
}

// elementwise float4 -> packed uint4
__global__ void pack4(const float4* __restrict__ src, uint4* __restrict__ dst) {
    size_t i = (size_t)blockIdx.x*256 + threadIdx.x;
    float4 v = src[i];
    uint4 o;
    o.x = pack_hl(v.x); o.y = pack_hl(v.y); o.z = pack_hl(v.z); o.w = pack_hl(v.w);
    dst[i] = o;
}

// ---------------- split-bf16 MFMA conv (128x128 tile, frag-major LDS) ----------------
// y^T packed out: ytp[(b*512+cout)*1024 + cell]
__launch_bounds__(256)
__global__ void conv_gemm(const unsigned* __restrict__ xmap, const unsigned* __restrict__ wt,
                          const float* __restrict__ convb, unsigned* __restrict__ ytp) {
    __shared__ __align__(16) unsigned short Ahi[4096], Alo[4096], Bhi[4096], Blo[4096];
    int n0 = blockIdx.x * 128;          // pos tile (8192/128 = 64)
    int m0 = blockIdx.y * 128;          // cout tile (512/128 = 4)
    int t = threadIdx.x;
    int lane = t & 63, wid = t >> 6;
    int wm = wid >> 1, wn = wid & 1;
    int l15 = lane & 15, l4 = lane >> 4;

    int rowL = t & 127, kg = t >> 7;    // each thread: tasks (rowL,kg) and (rowL,kg+2)
    int posG = n0 + rowL;
    int bb = posG >> 10, rem = posG & 1023;
    int oy = rem >> 5, ox = rem & 31;
    const unsigned* brow = wt + (size_t)(m0 + rowL)*KC + kg*8;

    // frag-major LDS index: tile*512 + kch*128 + r15*8 (ushorts)
    int wb0 = (rowL>>4)*512 + kg*128 + (rowL&15)*8;
    int wb1 = wb0 + 256;                // kg+2

    float4v acc[4][4] = {};
    uint4 a00,a01,a10,a11, b00,b01,b10,b11;

    auto loadA = [&](int kc) {
        int grp = kc >> 3;
        int ky = grp/3, kx = grp - 3*ky;
        int iy = 2*oy - 1 + ky, ix = 2*ox - 1 + kx;
        if ((unsigned)iy < 64u && (unsigned)ix < 64u) {
            const unsigned* ap = xmap + ((((size_t)bb*64 + iy)*64 + ix)*256 + (kc&7)*32 + kg*8);
            a00 = *(const uint4*)ap;       a01 = *(const uint4*)(ap + 4);
            a10 = *(const uint4*)(ap + 16); a11 = *(const uint4*)(ap + 20);
        } else {
            a00 = make_uint4(0,0,0,0); a01 = a00; a10 = a00; a11 = a00;
        }
    };
    auto loadB = [&](int kc) {
        const unsigned* bp = brow + (size_t)kc*32;
        b00 = *(const uint4*)bp;        b01 = *(const uint4*)(bp + 4);
        b10 = *(const uint4*)(bp + 16); b11 = *(const uint4*)(bp + 20);
    };
    loadA(0); loadB(0);

    for (int kc = 0; kc < KC/32; ++kc) {
        __syncthreads();   // prior chunk's LDS reads complete
        uint4 h, l;
        h.x=hp2(a00.x,a00.y); h.y=hp2(a00.z,a00.w); h.z=hp2(a01.x,a01.y); h.w=hp2(a01.z,a01.w);
        l.x=lp2(a00.x,a00.y); l.y=lp2(a00.z,a00.w); l.z=lp2(a01.x,a01.y); l.w=lp2(a01.z,a01.w);
        *(uint4*)&Ahi[wb0] = h; *(uint4*)&Alo[wb0] = l;
        h.x=hp2(a10.x,a10.y); h.y=hp2(a10.z,a10.w); h.z=hp2(a11.x,a11.y); h.w=hp2(a11.z,a11.w);
        l.x=lp2(a10.x,a10.y); l.y=lp2(a10.z,a10.w); l.z=lp2(a11.x,a11.y); l.w=lp2(a11.z,a11.w);
        *(uint4*)&Ahi[wb1] = h; *(uint4*)&Alo[wb1] = l;
        h.x=hp2(b00.x,b00.y); h.y=hp2(b00.z,b00.w); h.z=hp2(b01.x,b01.y); h.w=hp2(b01.z,b01.w);
        l.x=lp2(b00.x,b00.y); l.y=lp2(b00.z,b00.w); l.z=lp2(b01.x,b01.y); l.w=lp2(b01.z,b01.w);
        *(uint4*)&Bhi[wb0] = h; *(uint4*)&Blo[wb0] = l;
        h.x=hp2(b10.x,b10.y); h.y=hp2(b10.z,b10.w); h.z=hp2(b11.x,b11.y); h.w=hp2(b11.z,b11.w);
        l.x=lp2(b10.x,b10.y); l.y=lp2(b10.z,b10.w); l.z=lp2(b11.x,b11.y); l.w=lp2(b11.z,b11.w);
        *(uint4*)&Bhi[wb1] = h; *(uint4*)&Blo[wb1] = l;
        __syncthreads();
        if (kc + 1 < KC/32) { loadA(kc+1); loadB(kc+1); }   // overlap HBM with MFMA

        short8v bh[4], bl[4];
        #pragma unroll
        for (int q = 0; q < 4; ++q) {
            int off = (wn*4 + q)*512 + l4*128 + l15*8;
            bh[q] = *(const short8v*)&Bhi[off];
            bl[q] = *(const short8v*)&Blo[off];
        }
        #pragma unroll
        for (int p = 0; p < 4; ++p) {
            int off = (wm*4 + p)*512 + l4*128 + l15*8;
            short8v ah = *(const short8v*)&Ahi[off];
            short8v al = *(const short8v*)&Alo[off];
            #pragma unroll
            for (int q = 0; q < 4; ++q) {
                acc[p][q] = __builtin_amdgcn_mfma_f32_16x16x32_bf16(ah, bh[q], acc[p][q], 0, 0, 0);
                acc[p][q] = __builtin_amdgcn_mfma_f32_16x16x32_bf16(ah, bl[q], acc[p][q], 0, 0, 0);
                acc[p][q] = __builtin_amdgcn_mfma_f32_16x16x32_bf16(al, bh[q], acc[p][q], 0, 0, 0);
            }
        }
    }

    int bbk = n0 >> 10;                 // batch (block never straddles)
    int pos0 = (n0 & 1023) + wm*64;
    #pragma unroll
    for (int p = 0; p < 4; ++p) {
        int posb = pos0 + p*16 + l4*4;
        #pragma unroll
        for (int q = 0; q < 4; ++q) {
            int col = m0 + wn*64 + q*16 + l15;
            float bv = convb[col];
            uint4 o;
            o.x = pack_hl(acc[p][q][0] + bv);
            o.y = pack_hl(acc[p][q][1] + bv);
            o.z = pack_hl(acc[p][q][2] + bv);
            o.w = pack_hl(acc[p][q][3] + bv);
            *(uint4*)&ytp[((size_t)(bbk*NCO + col))*OHW + posb] = o;
        }
    }
}

// ---------------- generic split-bf16 MFMA GEMM, 128x128 tile ----------------
// A_pk[b][M][K], B_pk[b][N][K] (both K-contiguous packed). MODE 0: C=fp32 A*B^T-style.
// MODE 1: dist epilogue (sqrt((sq_m+sq_n-2G)_+)/sqrt(512), per-batch max).
template<int MODE>
__launch_bounds__(256)
__global__ void gemm_pk(const unsigned* __restrict__ A, const unsigned* __restrict__ B,
                        float* __restrict__ C, int K, int N,
                        long sA, long sB, long sC,
                        const float* __restrict__ sq, unsigned* __restrict__ dmaxU) {
    __shared__ __align__(16) unsigned short Ahi[4096], Alo[4096], Bhi[4096], Blo[4096];
    int z = blockIdx.z;
    const unsigned* Ab = A + (size_t)z*sA;
    const unsigned* Bb = B + (size_t)z*sB;
    float* Cb = C + (size_t)z*sC;
    int n0 = blockIdx.x*128, m0 = blockIdx.y*128;
    int t = threadIdx.x;
    int lane = t & 63, wid = t >> 6;
    int wm = wid >> 1, wn = wid & 1;
    int l15 = lane & 15, l4 = lane >> 4;

    int rowL = t & 127, kg = t >> 7;
    const unsigned* arow = Ab + (size_t)(m0 + rowL)*K + kg*8;
    const unsigned* brw  = Bb + (size_t)(n0 + rowL)*K + kg*8;
    int wb0 = (rowL>>4)*512 + kg*128 + (rowL&15)*8;
    int wb1 = wb0 + 256;

    float4v acc[4][4] = {};
    uint4 a00,a01,a10,a11, b00,b01,b10,b11;
    auto loadA = [&](int kc) {
        const unsigned* p = arow + (size_t)kc*32;
        a00 = *(const uint4*)p;        a01 = *(const uint4*)(p + 4);
        a10 = *(const uint4*)(p + 16); a11 = *(const uint4*)(p + 20);
    };
    auto loadB = [&](int kc) {
        const unsigned* p = brw + (size_t)kc*32;
        b00 = *(const uint4*)p;        b01 = *(const uint4*)(p + 4);
        b10 = *(const uint4*)(p + 16); b11 = *(const uint4*)(p + 20);
    };
    loadA(0); loadB(0);
    int nkc = K >> 5;

    for (int kc = 0; kc < nkc; ++kc) {
        __syncthreads();
        uint4 h, l;
        h.x=hp2(a00.x,a00.y); h.y=hp2(a00.z,a00.w); h.z=hp2(a01.x,a01.y); h.w=hp2(a01.z,a01.w);
        l.x=lp2(a00.x,a00.y); l.y=lp2(a00.z,a00.w); l.z=lp2(a01.x,a01.y); l.w=lp2(a01.z,a01.w);
        *(uint4*)&Ahi[wb0] = h; *(uint4*)&Alo[wb0] = l;
        h.x=hp2(a10.x,a10.y); h.y=hp2(a10.z,a10.w); h.z=hp2(a11.x,a11.y); h.w=hp2(a11.z,a11.w);
        l.x=lp2(a10.x,a10.y); l.y=lp2(a10.z,a10.w); l.z=lp2(a11.x,a11.y); l.w=lp2(a11.z,a11.w);
        *(uint4*)&Ahi[wb1] = h; *(uint4*)&Alo[wb1] = l;
        h.x=hp2(b00.x,b00.y); h.y=hp2(b00.z,b00.w); h.z=hp2(b01.x,b01.y); h.w=hp2(b01.z,b01.w);
        l.x=lp2(b00.x,b00.y); l.y=lp2(b00.z,b00.w); l.z=lp2(b01.x,b01.y); l.w=lp2(b01.z,b01.w);
        *(uint4*)&Bhi[wb0] = h; *(uint4*)&Blo[wb0] = l;
        h.x=hp2(b10.x,b10.y); h.y=hp2(b10.z,b10.w); h.z=hp2(b11.x,b11.y); h.w=hp2(b11.z,b11.w);
        l.x=lp2(b10.x,b10.y); l.y=lp2(b10.z,b10.w); l.z=lp2(b11.x,b11.y); l.w=lp2(b11.z,b11.w);
        *(uint4*)&Bhi[wb1] = h; *(uint4*)&Blo[wb1] = l;
        __syncthreads();
        if (kc + 1 < nkc) { loadA(kc+1); loadB(kc+1); }

        short8v bh[4], bl[4];
        #pragma unroll
        for (int q = 0; q < 4; ++q) {
            int off = (wn*4 + q)*512 + l4*128 + l15*8;
            bh[q] = *(const short8v*)&Bhi[off];
            bl[q] = *(const short8v*)&Blo[off];
        }
        #pragma unroll
        for (int p = 0; p < 4; ++p) {
            int off = (wm*4 + p)*512 + l4*128 + l15*8;
            short8v ah = *(const short8v*)&Ahi[off];
            short8v al = *(const short8v*)&Alo[off];
            #pragma unroll
            for (int q = 0; q < 4; ++q) {
                acc[p][q] = __builtin_amdgcn_mfma_f32_16x16x32_bf16(ah, bh[q], acc[p][q], 0, 0, 0);
                acc[p][q] = __builtin_amdgcn_mfma_f32_16x16x32_bf16(ah, bl[q], acc[p][q], 0, 0, 0);
                acc[p][q] = __builtin_amdgcn_mfma_f32_16x16x32_bf16(al, bh[q], acc[p][q], 0, 0, 0);
            }
        }
    }

    if (MODE == 0) {
        #pragma unroll
        for (int p = 0; p < 4; ++p) {
            int mb = m0 + wm*64 + p*16 + l4*4;
            #pragma unroll
            for (int q = 0; q < 4; ++q) {
                int n = n0 + wn*64 + q*16 + l15;
                #pragma unroll
                for (int r = 0; r < 4; ++r)
                    Cb[(size_t)(mb + r)*N + n] = acc[p][q][r];
            }
        }
    } else {
        const float inv = 1.0f / sqrtf(512.0f);
        const float* sqb = sq + z*NTOK;
        float tmax = 0.f;
        #pragma unroll
        for (int p = 0; p < 4; ++p) {
            int mb = m0 + wm*64 + p*16 + l4*4;
            #pragma unroll
            for (int q = 0; q < 4; ++q) {
                int n = n0 + wn*64 + q*16 + l15;
                float sn = sqb[n];
                #pragma unroll
                for (int r = 0; r < 4; ++r) {
                    float d2 = sqb[mb + r] + sn - 2.0f*acc[p][q][r];
                    float d = sqrtf(fmaxf(d2, 0.0f)) * inv;
                    Cb[(size_t)(mb + r)*N + n] = d;
                    tmax = fmaxf(tmax, d);
                }
            }
        }
        __shared__ float redm[4];
        #pragma unroll
        for (int off = 32; off; off >>= 1) tmax = fmaxf(tmax, __shfl_xor(tmax, off, 64));
        if (lane == 0) redm[wid] = tmax;
        __syncthreads();
        if (t == 0) {
            float m = fmaxf(fmaxf(redm[0], redm[1]), fmaxf(redm[2], redm[3]));
            atomicMax(dmaxU + z, __float_as_uint(m));
        }
    }
}

// ---------------- remaining pipeline ----------------
__global__ void wsum_rows(const float* __restrict__ amat, float* __restrict__ wsum) {
    int row = blockIdx.x*4 + (threadIdx.x >> 6);
    int lane = threadIdx.x & 63;
    const float* ar = amat + (size_t)row*OHW;
    float s = 0.f;
    #pragma unroll
    for (int r = 0; r < 16; ++r) s += ar[lane + 64*r];
    #pragma unroll
    for (int off = 32; off; off >>= 1) s += __shfl_xor(s, off, 64);
    if (lane == 0) wsum[row] = s;
}

__device__ __forceinline__ float block_sum256(float v, float* red) {
    #pragma unroll
    for (int off = 32; off; off >>= 1) v += __shfl_xor(v, off, 64);
    __syncthreads();
    if ((threadIdx.x & 63) == 0) red[threadIdx.x >> 6] = v;
    __syncthreads();
    return red[0] + red[1] + red[2] + red[3];
}

__global__ void ln_conf(const float* __restrict__ C2, const float* __restrict__ wsum,
                        const float* __restrict__ xskip, const float* __restrict__ g,
                        const float* __restrict__ be, const float* __restrict__ confw,
                        const float* __restrict__ confb, float* __restrict__ xtok,
                        unsigned* __restrict__ xtokpk,
                        float* __restrict__ wexp, float* __restrict__ sqv) {
    __shared__ float red[4];
    int row = blockIdx.x, t = threadIdx.x;
    float ws = wsum[row] + EPS;
    size_t base = (size_t)row*NCO;
    float v0 = C2[base + t]       / ws + xskip[base + t];
    float v1 = C2[base + t + 256] / ws + xskip[base + t + 256];
    float mu  = block_sum256(v0 + v1, red) / 512.0f;
    float d0 = v0 - mu, d1 = v1 - mu;
    float var = block_sum256(d0*d0 + d1*d1, red) / 512.0f;
    float sv = sqrtf(var + 1e-5f);
    float x0 = d0/sv * g[t]       + be[t];
    float x1 = d1/sv * g[t + 256] + be[t + 256];
    xtok[base + t] = x0;
    xtok[base + t + 256] = x1;
    xtokpk[base + t] = pack_hl(x0);
    xtokpk[base + t + 256] = pack_hl(x1);
    float cs = block_sum256(x0*confw[t] + x1*confw[t + 256], red);
    float qs = block_sum256(x0*x0 + x1*x1, red);
    if (t == 0) {
        wexp[row] = expf(cs + confb[0]);
        sqv[row]  = qs;
    }
}

__global__ void knn_dens(const float* __restrict__ dist, float* __restrict__ dens) {
    int row = blockIdx.x*4 + (threadIdx.x >> 6);
    int lane = threadIdx.x & 63;
    const float* dr = dist + (size_t)row*NTOK;
    float v0 = dr[lane], v1 = dr[lane+64], v2 = dr[lane+128], v3 = dr[lane+192];
    float acc = 0.f;
    #pragma unroll
    for (int it = 0; it < 5; ++it) {
        float lm = fminf(fminf(v0, v1), fminf(v2, v3));
        float gm = lm;
        #pragma unroll
        for (int off = 32; off; off >>= 1) gm = fminf(gm, __shfl_xor(gm, off, 64));
        acc += gm*gm;
        ull ball = __ballot(lm == gm);
        int first = __ffsll(ball) - 1;
        if (lane == first) {
            if      (v0 == gm) v0 = 1e30f;
            else if (v1 == gm) v1 = 1e30f;
            else if (v2 == gm) v2 = 1e30f;
            else               v3 = 1e30f;
        }
    }
    if (lane == 0) dens[row] = expf(-(acc/5.0f));
}

__global__ void parent_score(const float* __restrict__ dist, const float* __restrict__ dens,
                             const unsigned* __restrict__ dmaxU, float* __restrict__ score) {
    int row = blockIdx.x*4 + (threadIdx.x >> 6);
    int lane = threadIdx.x & 63;
    int b = row >> 8;
    float di = dens[row];
    float dm = __uint_as_float(dmaxU[b]);
    const float* dr = dist + (size_t)row*NTOK;
    const float* db = dens + (size_t)b*NTOK;
    float pd = dm;
    #pragma unroll
    for (int r = 0; r < 4; ++r) {
        int j = lane + 64*r;
        pd = fminf(pd, (db[j] > di) ? dr[j] : dm);
    }
    #pragma unroll
    for (int off = 32; off; off >>= 1) pd = fminf(pd, __shfl_xor(pd, off, 64));
    if (lane == 0) score[row] = pd * di;
}

__global__ void topk64(const float* __restrict__ score, int* __restrict__ ind) {
    int b = blockIdx.x, lane = threadIdx.x;
    const float* sb = score + b*NTOK;
    ull k0, k1, k2, k3;
    {
        unsigned i0 = lane, i1 = lane+64, i2 = lane+128, i3 = lane+192;
        k0 = ((ull)(__float_as_uint(sb[i0]) + 1u) << 32) | (unsigned)(4095 - i0);
        k1 = ((ull)(__float_as_uint(sb[i1]) + 1u) << 32) | (unsigned)(4095 - i1);
        k2 = ((ull)(__float_as_uint(sb[i2]) + 1u) << 32) | (unsigned)(4095 - i2);
        k3 = ((ull)(__float_as_uint(sb[i3]) + 1u) << 32) | (unsigned)(4095 - i3);
    }
    for (int it = 0; it < 64; ++it) {
        ull lm = k0;
        if (k1 > lm) lm = k1;
        if (k2 > lm) lm = k2;
        if (k3 > lm) lm = k3;
        ull gm = lm;
        #pragma unroll
        for (int off = 32; off; off >>= 1) {
            ull o = __shfl_xor(gm, off, 64);
            if (o > gm) gm = o;
        }
        if (lane == 0) ind[b*NS + it] = 4095 - (int)(gm & 0xffffffffull);
        if      (k0 == gm) k0 = 0;
        else if (k1 == gm) k1 = 0;
        else if (k2 == gm) k2 = 0;
        else if (k3 == gm) k3 = 0;
    }
}

__global__ void assign_k(const float* __restrict__ dist, const int* __restrict__ ind,
                         int* __restrict__ idxcl) {
    int row = blockIdx.x*4 + (threadIdx.x >> 6);
    int lane = threadIdx.x & 63;
    int b = row >> 8, i = row & 255;
    int center = ind[b*NS + lane];
    float d = dist[((size_t)(b*NTOK + center))*NTOK + i];
    ull key = ((ull)__float_as_uint(d) << 32) | (unsigned)lane;
    #pragma unroll
    for (int off = 32; off; off >>= 1) {
        ull o = __shfl_xor(key, off, 64);
        if (o < key) key = o;
    }
    if (lane == 0) idxcl[row] = (int)(key & 0xffffffffull);
}

__global__ void center_set(const int* __restrict__ ind, int* __restrict__ idxcl) {
    int id = threadIdx.x;
    int b = id >> 6, s = id & 63;
    idxcl[b*NTOK + ind[id]] = s;
}

__global__ void allw_acc(const int* __restrict__ idxcl, const float* __restrict__ wexp,
                         float* __restrict__ allw) {
    int b = blockIdx.x, i = threadIdx.x;
    atomicAdd(&allw[b*NS + idxcl[b*NTOK + i]], wexp[b*NTOK + i]);
}

__global__ void normw_k(const int* __restrict__ idxcl, const float* __restrict__ wexp,
                        const float* __restrict__ allw, float* __restrict__ normw) {
    int b = blockIdx.x, i = threadIdx.x;
    normw[b*NTOK + i] = wexp[b*NTOK + i] / (allw[b*NS + idxcl[b*NTOK + i]] + EPS);
}

__global__ void merge_k(const float* __restrict__ xtok, const int* __restrict__ idxcl,
                        const float* __restrict__ normw, float* __restrict__ xout) {
    int row = blockIdx.x, t = threadIdx.x;
    int b = row >> 8;
    int cl = idxcl[row];
    float nw = normw[row];
    float* o = xout + ((size_t)(b*NS + cl))*NCO;
    const float* xr = xtok + (size_t)row*NCO;
    atomicAdd(&o[t],       xr[t]       * nw);
    atomicAdd(&o[t + 256], xr[t + 256] * nw);
}

__global__ void out_idx_aw(const int* __restrict__ idxagg, const float* __restrict__ aggw,
                           const int* __restrict__ idxcl, const float* __restrict__ normw,
                           float* __restrict__ dout, float* __restrict__ awbuf,
                           unsigned* __restrict__ maxw) {
    __shared__ float red[4];
    int bp = blockIdx.x*256 + threadIdx.x;
    int b = bp >> 14;
    int tok = idxagg[bp];
    int cl = idxcl[b*NTOK + tok];
    dout[(size_t)NB*NS*NCO + bp] = (float)cl;
    float aw = aggw[bp] * normw[b*NTOK + tok];
    awbuf[bp] = aw;
    float m = aw;
    #pragma unroll
    for (int off = 32; off; off >>= 1) m = fmaxf(m, __shfl_xor(m, off, 64));
    if ((threadIdx.x & 63) == 0) red[threadIdx.x >> 6] = m;
    __syncthreads();
    if (threadIdx.x == 0) {
        float mm = fmaxf(fmaxf(red[0], red[1]), fmaxf(red[2], red[3]));
        atomicMax(&maxw[b], __float_as_uint(mm));
    }
}

__global__ void aw_final(const float* __restrict__ awbuf, const float* __restrict__ maxw,
                         float* __restrict__ dout) {
    int bp = blockIdx.x*256 + threadIdx.x;
    int b = bp >> 14;
    dout[(size_t)NB*NS*NCO + (size_t)NB*NP + bp] = awbuf[bp] / maxw[b];
}

// ---------------- launch ----------------
extern "C" void kernel_launch(void* const* d_in, const int* in_sizes, int n_in,
                              void* d_out, int out_size, void* d_ws, size_t ws_size,
                              hipStream_t stream) {
    const float* x      = (const float*)d_in[0];
    const float* loc    = (const float*)d_in[1];
    const int*   idxagg = (const int*)  d_in[2];
    const float* aggw   = (const float*)d_in[3];
    const float* convw  = (const float*)d_in[7];
    const float* convb  = (const float*)d_in[8];
    const float* skipw  = (const float*)d_in[9];
    const float* lng    = (const float*)d_in[10];
    const float* lnb    = (const float*)d_in[11];
    const float* confw  = (const float*)d_in[12];
    const float* confb  = (const float*)d_in[13];

    float* ws = (float*)d_ws;
    float* dout = (float*)d_out;

    (void)hipMemsetAsync(ws, 0, ZERO_END*sizeof(float), stream);
    (void)hipMemsetAsync(dout, 0, (size_t)NB*NS*NCO*sizeof(float), stream);

    scatter_map<<<dim3(NB*NP), 256, 0, stream>>>(x, loc, idxagg, aggw,
                                                 ws + OFF_SUMS, ws + OFF_CNT, ws + OFF_AMAT);
    wtrans<<<dim3(KC*NCO/256), 256, 0, stream>>>(convw, (unsigned*)(ws + OFF_WT));
    pack4<<<dim3(CIN*NCO/1024), 256, 0, stream>>>((const float4*)skipw, (uint4*)(ws + OFF_SKWT));
    pack4<<<dim3(NB*NTOK*CIN/1024), 256, 0, stream>>>((const float4*)x, (uint4*)(ws + OFF_XPK));
    finalize_map<<<dim3((NB*HW64*CIN/4)/256), 256, 0, stream>>>((unsigned*)(ws + OFF_SUMS), ws + OFF_CNT);

    conv_gemm<<<dim3(64, 4), 256, 0, stream>>>((const unsigned*)(ws + OFF_SUMS),
                                               (const unsigned*)(ws + OFF_WT), convb,
                                               (unsigned*)(ws + OFF_Y));

    wsum_rows<<<dim3(NB*NTOK/4), 256, 0, stream>>>(ws + OFF_AMAT, ws + OFF_WSUM);
    // Amat packed into SUMS region (xmap dead after conv)
    pack4<<<dim3(NB*NTOK*OHW/1024), 256, 0, stream>>>((const float4*)(ws + OFF_AMAT),
                                                      (uint4*)(ws + OFF_AMATP));
    // ssum: C2[tok][cout] = Amat @ y  (M=256,N=512,K=1024 per batch)
    gemm_pk<0><<<dim3(4, 2, 8), 256, 0, stream>>>((const unsigned*)(ws + OFF_AMATP),
                                                  (const unsigned*)(ws + OFF_Y),
                                                  ws + OFF_C2, OHW, NCO,
                                                  (long)NTOK*OHW, (long)NCO*OHW, (long)NTOK*NCO,
                                                  nullptr, nullptr);
    // xskip = x @ skip_w^T (M=2048,N=512,K=256)
    gemm_pk<0><<<dim3(4, 16, 1), 256, 0, stream>>>((const unsigned*)(ws + OFF_XPK),
                                                   (const unsigned*)(ws + OFF_SKWT),
                                                   ws + OFF_XSKIP, CIN, NCO, 0, 0, 0,
                                                   nullptr, nullptr);

    ln_conf<<<dim3(NB*NTOK), 256, 0, stream>>>(ws + OFF_C2, ws + OFF_WSUM, ws + OFF_XSKIP,
                                               lng, lnb, confw, confb,
                                               ws + OFF_XTOK, (unsigned*)(ws + OFF_XTOKPK),
                                               ws + OFF_WEXP, ws + OFF_SQ);

    // dist: Gram + sqrt epilogue (M=N=256,K=512 per batch), A=B=xtok packed
    gemm_pk<1><<<dim3(2, 2, 8), 256, 0, stream>>>((const unsigned*)(ws + OFF_XTOKPK),
                                                  (const unsigned*)(ws + OFF_XTOKPK),
                                                  ws + OFF_DIST, NCO, NTOK,
                                                  (long)NTOK*NCO, (long)NTOK*NCO, (long)NTOK*NTOK,
                                                  ws + OFF_SQ, (unsigned*)(ws + OFF_DMAX));

    knn_dens<<<dim3(NB*NTOK/4), 256, 0, stream>>>(ws + OFF_DIST, ws + OFF_DENS);
    parent_score<<<dim3(NB*NTOK/4), 256, 0, stream>>>(ws + OFF_DIST, ws + OFF_DENS,
                                                      (const unsigned*)(ws + OFF_DMAX), ws + OFF_SCORE);
    topk64<<<dim3(NB), 64, 0, stream>>>(ws + OFF_SCORE, (int*)(ws + OFF_IND));
    assign_k<<<dim3(NB*NTOK/4), 256, 0, stream>>>(ws + OFF_DIST, (const int*)(ws + OFF_IND),
                                                  (int*)(ws + OFF_IDXCL));
    center_set<<<dim3(1), 512, 0, stream>>>((const int*)(ws + OFF_IND), (int*)(ws + OFF_IDXCL));
    allw_acc<<<dim3(NB), 256, 0, stream>>>((const int*)(ws + OFF_IDXCL), ws + OFF_WEXP, ws + OFF_ALLW);
    normw_k<<<dim3(NB), 256, 0, stream>>>((const int*)(ws + OFF_IDXCL), ws + OFF_WEXP,
                                          ws + OFF_ALLW, ws + OFF_NORMW);
    merge_k<<<dim3(NB*NTOK), 256, 0, stream>>>(ws + OFF_XTOK, (const int*)(ws + OFF_IDXCL),
                                               ws + OFF_NORMW, dout);
    out_idx_aw<<<dim3(NB*NP/256), 256, 0, stream>>>(idxagg, aggw, (const int*)(ws + OFF_IDXCL),
                                                    ws + OFF_NORMW, dout, ws + OFF_AWBUF,
                                                    (unsigned*)(ws + OFF_MAXW));
    aw_final<<<dim3(NB*NP/256), 256, 0, stream>>>(ws + OFF_AWBUF, (const float*)(ws + OFF_MAXW), dout);
}

// Round 5
// 368.973 us; speedup vs baseline: 5.9786x; 1.2098x over previous
//
#include <hip/hip_runtime.h>
#include <math.h>

typedef unsigned long long ull;
typedef __attribute__((ext_vector_type(8))) short short8v;   // 8 bf16 in 4 VGPRs
typedef __attribute__((ext_vector_type(4))) float float4v;

#define NB   8
#define NTOK 256
#define CIN  256
#define NP   16384
#define NCO  512
#define HW64 4096
#define OHW  1024
#define NS   64
#define EPS  1e-6f
#define KC   2304   // 9*256 conv K

// ---------------- workspace layout (float offsets) ----------------
constexpr size_t OFF_SUMS = 0;                                   // cntmat(int) -> xmap packed (in-place GEMM); after conv: AMATP alias
constexpr size_t OFF_CNT  = OFF_SUMS + (size_t)NB*HW64*CIN;
constexpr size_t OFF_AMAT = OFF_CNT  + (size_t)NB*HW64;          // fp32 tok x cell32 weights
constexpr size_t OFF_ALLW = OFF_AMAT + (size_t)NB*NTOK*OHW;
constexpr size_t OFF_DMAX = OFF_ALLW + (size_t)NB*NS;
constexpr size_t OFF_MAXW = OFF_DMAX + NB;
constexpr size_t ZERO_END = OFF_MAXW + NB;
constexpr size_t OFF_WT   = ZERO_END;                            // 512*2304 packed hi|lo [cout][k]
constexpr size_t OFF_SKWT = OFF_WT   + (size_t)KC*NCO;           // 512*256 packed [cout][cin]
constexpr size_t OFF_Y    = OFF_SKWT + (size_t)CIN*NCO;          // yT packed [b][cout][cell]; after ssum: XTOKPK alias
constexpr size_t OFF_C2   = OFF_Y    + (size_t)NB*OHW*NCO;       // ssum fp32
constexpr size_t OFF_WSUM = OFF_C2   + (size_t)NB*NTOK*NCO;
constexpr size_t OFF_XSKIP= OFF_WSUM + (size_t)NB*NTOK;
constexpr size_t OFF_XTOK = OFF_XSKIP+ (size_t)NB*NTOK*NCO;      // fp32
constexpr size_t OFF_XPK  = OFF_XTOK + (size_t)NB*NTOK*NCO;      // x packed [b][tok][cin]
constexpr size_t OFF_WEXP = OFF_XPK  + (size_t)NB*NTOK*NCO;
constexpr size_t OFF_SQ   = OFF_WEXP + (size_t)NB*NTOK;
constexpr size_t OFF_DIST = OFF_SQ   + (size_t)NB*NTOK;
constexpr size_t OFF_DENS = OFF_DIST + (size_t)NB*NTOK*NTOK;
constexpr size_t OFF_SCORE= OFF_DENS + (size_t)NB*NTOK;
constexpr size_t OFF_IND  = OFF_SCORE+ (size_t)NB*NTOK;
constexpr size_t OFF_IDXCL= OFF_IND  + (size_t)NB*NS;
constexpr size_t OFF_NORMW= OFF_IDXCL+ (size_t)NB*NTOK;
constexpr size_t OFF_AWBUF= OFF_NORMW+ (size_t)NB*NTOK;
constexpr size_t OFF_XTPK = OFF_AWBUF+ (size_t)NB*NP;            // x^T packed [b][cin][tok] (new, 512K)
// aliases (regions dead by the time these are written)
constexpr size_t OFF_AMATP = OFF_SUMS;   // written after conv consumed xmap
constexpr size_t OFF_XTOKPK= OFF_Y;      // written after ssum consumed yT

// pack fp32 -> (bf16_hi << 16) | bf16_lo, both RNE; hi+lo reconstructs x to ~2^-17 rel
__device__ __forceinline__ unsigned pack_hl(float x) {
    unsigned u = __float_as_uint(x);
    unsigned t = u + 0x7fffu + ((u >> 16) & 1u);
    unsigned hibits = t & 0xffff0000u;
    float lo = x - __uint_as_float(hibits);
    unsigned ul = __float_as_uint(lo);
    unsigned lt = ul + 0x7fffu + ((ul >> 16) & 1u);
    return hibits | (lt >> 16);
}
__device__ __forceinline__ unsigned hp2(unsigned w0, unsigned w1) {
    return __builtin_amdgcn_perm(w1, w0, 0x07060302u);
}
__device__ __forceinline__ unsigned lp2(unsigned w0, unsigned w1) {
    return __builtin_amdgcn_perm(w1, w0, 0x05040100u);
}

// ---------------- histogram (replaces 33.5M-atomic scatter) ----------------
// per point: cntmat[b][cell64][tok]++ (int), cnt[b][cell64]+=1, amat[b][tok][cell32]+=aggw
__global__ void hist(const float* __restrict__ loc, const int* __restrict__ idxagg,
                     const float* __restrict__ aggw,
                     int* __restrict__ cntmat, float* __restrict__ cnt,
                     float* __restrict__ amat) {
    int bp = blockIdx.x*256 + threadIdx.x;
    int b  = bp >> 14;
    float lx = loc[2*bp+0], ly = loc[2*bp+1];
    lx = fminf(fmaxf(lx, -1.f), 1.f);
    ly = fminf(fmaxf(ly, -1.f), 1.f);
    int px = (int)rintf((lx + 1.f)*32.f - 0.5f); px = min(max(px,0),63);
    int py = (int)rintf((ly + 1.f)*32.f - 0.5f); py = min(max(py,0),63);
    int cell = py*64 + px;
    int tok = idxagg[bp];
    atomicAdd(&cntmat[((size_t)(b*HW64 + cell))*NTOK + tok], 1);
    atomicAdd(&cnt[b*HW64 + cell], 1.0f);
    int qx = (int)rintf((lx + 1.f)*16.f - 0.5f); qx = min(max(qx,0),31);
    int qy = (int)rintf((ly + 1.f)*16.f - 0.5f); qy = min(max(qy,0),31);
    atomicAdd(&amat[((size_t)(b*NTOK + tok))*OHW + qy*32 + qx], aggw[bp]);
}

// int counts -> packed hi|lo bf16 in place (exact for ints < 2^16)
__global__ void cnt_pack(unsigned* __restrict__ m) {
    size_t i = (size_t)blockIdx.x*256 + threadIdx.x;   // uint4 index, 2097152 total
    int4 v = ((const int4*)m)[i];
    uint4 o;
    o.x = pack_hl((float)v.x); o.y = pack_hl((float)v.y);
    o.z = pack_hl((float)v.z); o.w = pack_hl((float)v.w);
    ((uint4*)m)[i] = o;
}

// x^T packed: xtpk[b][cin][tok]
__global__ void xt_pack(const float* __restrict__ x, unsigned* __restrict__ xtpk) {
    int id = blockIdx.x*256 + threadIdx.x;   // 8*256*256
    int tok = id & 255, cin = (id >> 8) & 255, b = id >> 16;
    xtpk[id] = pack_hl(x[((size_t)(b*NTOK + tok))*CIN + cin]);
}

__global__ void wtrans(const float* __restrict__ convw, unsigned* __restrict__ wt) {
    int id = blockIdx.x*256 + threadIdx.x;
    int cout = id / KC, k = id - cout*KC;
    int grp = k >> 8, cin = k & 255;
    wt[id] = pack_hl(convw[(size_t)cout*KC + cin*9 + grp]);
}

__global__ void pack4(const float4* __restrict__ src, uint4* __restrict__ dst) {
    size_t i = (size_t)blockIdx.x*256 + threadIdx.x;
    float4 v = src[i];
    uint4 o;
    o.x = pack_hl(v.x); o.y = pack_hl(v.y); o.z = pack_hl(v.z); o.w = pack_hl(v.w);
    dst[i] = o;
}

// ---------------- split-bf16 MFMA conv (128x128 tile, frag-major LDS) ----------------
__launch_bounds__(256)
__global__ void conv_gemm(const unsigned* __restrict__ xmap, const unsigned* __restrict__ wt,
                          const float* __restrict__ convb, unsigned* __restrict__ ytp) {
    __shared__ __align__(16) unsigned short Ahi[4096], Alo[4096], Bhi[4096], Blo[4096];
    int n0 = blockIdx.x * 128;
    int m0 = blockIdx.y * 128;
    int t = threadIdx.x;
    int lane = t & 63, wid = t >> 6;
    int wm = wid >> 1, wn = wid & 1;
    int l15 = lane & 15, l4 = lane >> 4;

    int rowL = t & 127, kg = t >> 7;
    int posG = n0 + rowL;
    int bb = posG >> 10, rem = posG & 1023;
    int oy = rem >> 5, ox = rem & 31;
    const unsigned* brow = wt + (size_t)(m0 + rowL)*KC + kg*8;

    int wb0 = (rowL>>4)*512 + kg*128 + (rowL&15)*8;
    int wb1 = wb0 + 256;

    float4v acc[4][4] = {};
    uint4 a00,a01,a10,a11, b00,b01,b10,b11;

    auto loadA = [&](int kc) {
        int grp = kc >> 3;
        int ky = grp/3, kx = grp - 3*ky;
        int iy = 2*oy - 1 + ky, ix = 2*ox - 1 + kx;
        if ((unsigned)iy < 64u && (unsigned)ix < 64u) {
            const unsigned* ap = xmap + ((((size_t)bb*64 + iy)*64 + ix)*256 + (kc&7)*32 + kg*8);
            a00 = *(const uint4*)ap;       a01 = *(const uint4*)(ap + 4);
            a10 = *(const uint4*)(ap + 16); a11 = *(const uint4*)(ap + 20);
        } else {
            a00 = make_uint4(0,0,0,0); a01 = a00; a10 = a00; a11 = a00;
        }
    };
    auto loadB = [&](int kc) {
        const unsigned* bp = brow + (size_t)kc*32;
        b00 = *(const uint4*)bp;        b01 = *(const uint4*)(bp + 4);
        b10 = *(const uint4*)(bp + 16); b11 = *(const uint4*)(bp + 20);
    };
    loadA(0); loadB(0);

    for (int kc = 0; kc < KC/32; ++kc) {
        __syncthreads();
        uint4 h, l;
        h.x=hp2(a00.x,a00.y); h.y=hp2(a00.z,a00.w); h.z=hp2(a01.x,a01.y); h.w=hp2(a01.z,a01.w);
        l.x=lp2(a00.x,a00.y); l.y=lp2(a00.z,a00.w); l.z=lp2(a01.x,a01.y); l.w=lp2(a01.z,a01.w);
        *(uint4*)&Ahi[wb0] = h; *(uint4*)&Alo[wb0] = l;
        h.x=hp2(a10.x,a10.y); h.y=hp2(a10.z,a10.w); h.z=hp2(a11.x,a11.y); h.w=hp2(a11.z,a11.w);
        l.x=lp2(a10.x,a10.y); l.y=lp2(a10.z,a10.w); l.z=lp2(a11.x,a11.y); l.w=lp2(a11.z,a11.w);
        *(uint4*)&Ahi[wb1] = h; *(uint4*)&Alo[wb1] = l;
        h.x=hp2(b00.x,b00.y); h.y=hp2(b00.z,b00.w); h.z=hp2(b01.x,b01.y); h.w=hp2(b01.z,b01.w);
        l.x=lp2(b00.x,b00.y); l.y=lp2(b00.z,b00.w); l.z=lp2(b01.x,b01.y); l.w=lp2(b01.z,b01.w);
        *(uint4*)&Bhi[wb0] = h; *(uint4*)&Blo[wb0] = l;
        h.x=hp2(b10.x,b10.y); h.y=hp2(b10.z,b10.w); h.z=hp2(b11.x,b11.y); h.w=hp2(b11.z,b11.w);
        l.x=lp2(b10.x,b10.y); l.y=lp2(b10.z,b10.w); l.z=lp2(b11.x,b11.y); l.w=lp2(b11.z,b11.w);
        *(uint4*)&Bhi[wb1] = h; *(uint4*)&Blo[wb1] = l;
        __syncthreads();
        if (kc + 1 < KC/32) { loadA(kc+1); loadB(kc+1); }

        short8v bh[4], bl[4];
        #pragma unroll
        for (int q = 0; q < 4; ++q) {
            int off = (wn*4 + q)*512 + l4*128 + l15*8;
            bh[q] = *(const short8v*)&Bhi[off];
            bl[q] = *(const short8v*)&Blo[off];
        }
        #pragma unroll
        for (int p = 0; p < 4; ++p) {
            int off = (wm*4 + p)*512 + l4*128 + l15*8;
            short8v ah = *(const short8v*)&Ahi[off];
            short8v al = *(const short8v*)&Alo[off];
            #pragma unroll
            for (int q = 0; q < 4; ++q) {
                acc[p][q] = __builtin_amdgcn_mfma_f32_16x16x32_bf16(ah, bh[q], acc[p][q], 0, 0, 0);
                acc[p][q] = __builtin_amdgcn_mfma_f32_16x16x32_bf16(ah, bl[q], acc[p][q], 0, 0, 0);
                acc[p][q] = __builtin_amdgcn_mfma_f32_16x16x32_bf16(al, bh[q], acc[p][q], 0, 0, 0);
            }
        }
    }

    int bbk = n0 >> 10;
    int pos0 = (n0 & 1023) + wm*64;
    #pragma unroll
    for (int p = 0; p < 4; ++p) {
        int posb = pos0 + p*16 + l4*4;
        #pragma unroll
        for (int q = 0; q < 4; ++q) {
            int col = m0 + wn*64 + q*16 + l15;
            float bv = convb[col];
            uint4 o;
            o.x = pack_hl(acc[p][q][0] + bv);
            o.y = pack_hl(acc[p][q][1] + bv);
            o.z = pack_hl(acc[p][q][2] + bv);
            o.w = pack_hl(acc[p][q][3] + bv);
            *(uint4*)&ytp[((size_t)(bbk*NCO + col))*OHW + posb] = o;
        }
    }
}

// ---------------- generic split-bf16 MFMA GEMM, 128x128 tile ----------------
// A_pk[b][M][K], B_pk[b][N][K]. MODE 0: C=fp32. MODE 1: dist epilogue.
// MODE 2: xmap epilogue — C_uint[m][n] = pack_hl(acc/(aux[m]+eps)), IN PLACE over A.
template<int MODE>
__launch_bounds__(256)
__global__ void gemm_pk(const unsigned* __restrict__ A, const unsigned* __restrict__ B,
                        float* __restrict__ C, int K, int N,
                        long sA, long sB, long sC,
                        const float* __restrict__ aux, unsigned* __restrict__ dmaxU) {
    __shared__ __align__(16) unsigned short Ahi[4096], Alo[4096], Bhi[4096], Blo[4096];
    int z = blockIdx.z;
    const unsigned* Ab = A + (size_t)z*sA;
    const unsigned* Bb = B + (size_t)z*sB;
    float* Cb = C + (size_t)z*sC;
    int n0 = blockIdx.x*128, m0 = blockIdx.y*128;
    int t = threadIdx.x;
    int lane = t & 63, wid = t >> 6;
    int wm = wid >> 1, wn = wid & 1;
    int l15 = lane & 15, l4 = lane >> 4;

    int rowL = t & 127, kg = t >> 7;
    const unsigned* arow = Ab + (size_t)(m0 + rowL)*K + kg*8;
    const unsigned* brw  = Bb + (size_t)(n0 + rowL)*K + kg*8;
    int wb0 = (rowL>>4)*512 + kg*128 + (rowL&15)*8;
    int wb1 = wb0 + 256;

    float4v acc[4][4] = {};
    uint4 a00,a01,a10,a11, b00,b01,b10,b11;
    auto loadA = [&](int kc) {
        const unsigned* p = arow + (size_t)kc*32;
        a00 = *(const uint4*)p;        a01 = *(const uint4*)(p + 4);
        a10 = *(const uint4*)(p + 16); a11 = *(const uint4*)(p + 20);
    };
    auto loadB = [&](int kc) {
        const unsigned* p = brw + (size_t)kc*32;
        b00 = *(const uint4*)p;        b01 = *(const uint4*)(p + 4);
        b10 = *(const uint4*)(p + 16); b11 = *(const uint4*)(p + 20);
    };
    loadA(0); loadB(0);
    int nkc = K >> 5;

    for (int kc = 0; kc < nkc; ++kc) {
        __syncthreads();
        uint4 h, l;
        h.x=hp2(a00.x,a00.y); h.y=hp2(a00.z,a00.w); h.z=hp2(a01.x,a01.y); h.w=hp2(a01.z,a01.w);
        l.x=lp2(a00.x,a00.y); l.y=lp2(a00.z,a00.w); l.z=lp2(a01.x,a01.y); l.w=lp2(a01.z,a01.w);
        *(uint4*)&Ahi[wb0] = h; *(uint4*)&Alo[wb0] = l;
        h.x=hp2(a10.x,a10.y); h.y=hp2(a10.z,a10.w); h.z=hp2(a11.x,a11.y); h.w=hp2(a11.z,a11.w);
        l.x=lp2(a10.x,a10.y); l.y=lp2(a10.z,a10.w); l.z=lp2(a11.x,a11.y); l.w=lp2(a11.z,a11.w);
        *(uint4*)&Ahi[wb1] = h; *(uint4*)&Alo[wb1] = l;
        h.x=hp2(b00.x,b00.y); h.y=hp2(b00.z,b00.w); h.z=hp2(b01.x,b01.y); h.w=hp2(b01.z,b01.w);
        l.x=lp2(b00.x,b00.y); l.y=lp2(b00.z,b00.w); l.z=lp2(b01.x,b01.y); l.w=lp2(b01.z,b01.w);
        *(uint4*)&Bhi[wb0] = h; *(uint4*)&Blo[wb0] = l;
        h.x=hp2(b10.x,b10.y); h.y=hp2(b10.z,b10.w); h.z=hp2(b11.x,b11.y); h.w=hp2(b11.z,b11.w);
        l.x=lp2(b10.x,b10.y); l.y=lp2(b10.z,b10.w); l.z=lp2(b11.x,b11.y); l.w=lp2(b11.z,b11.w);
        *(uint4*)&Bhi[wb1] = h; *(uint4*)&Blo[wb1] = l;
        __syncthreads();
        if (kc + 1 < nkc) { loadA(kc+1); loadB(kc+1); }

        short8v bh[4], bl[4];
        #pragma unroll
        for (int q = 0; q < 4; ++q) {
            int off = (wn*4 + q)*512 + l4*128 + l15*8;
            bh[q] = *(const short8v*)&Bhi[off];
            bl[q] = *(const short8v*)&Blo[off];
        }
        #pragma unroll
        for (int p = 0; p < 4; ++p) {
            int off = (wm*4 + p)*512 + l4*128 + l15*8;
            short8v ah = *(const short8v*)&Ahi[off];
            short8v al = *(const short8v*)&Alo[off];
            #pragma unroll
            for (int q = 0; q < 4; ++q) {
                acc[p][q] = __builtin_amdgcn_mfma_f32_16x16x32_bf16(ah, bh[q], acc[p][q], 0, 0, 0);
                acc[p][q] = __builtin_amdgcn_mfma_f32_16x16x32_bf16(ah, bl[q], acc[p][q], 0, 0, 0);
                acc[p][q] = __builtin_amdgcn_mfma_f32_16x16x32_bf16(al, bh[q], acc[p][q], 0, 0, 0);
            }
        }
    }

    if (MODE == 0) {
        #pragma unroll
        for (int p = 0; p < 4; ++p) {
            int mb = m0 + wm*64 + p*16 + l4*4;
            #pragma unroll
            for (int q = 0; q < 4; ++q) {
                int n = n0 + wn*64 + q*16 + l15;
                #pragma unroll
                for (int r = 0; r < 4; ++r)
                    Cb[(size_t)(mb + r)*N + n] = acc[p][q][r];
            }
        }
    } else if (MODE == 1) {
        const float inv = 1.0f / sqrtf(512.0f);
        const float* sqb = aux + (size_t)z*NTOK;
        float tmax = 0.f;
        #pragma unroll
        for (int p = 0; p < 4; ++p) {
            int mb = m0 + wm*64 + p*16 + l4*4;
            #pragma unroll
            for (int q = 0; q < 4; ++q) {
                int n = n0 + wn*64 + q*16 + l15;
                float sn = sqb[n];
                #pragma unroll
                for (int r = 0; r < 4; ++r) {
                    float d2 = sqb[mb + r] + sn - 2.0f*acc[p][q][r];
                    float d = sqrtf(fmaxf(d2, 0.0f)) * inv;
                    Cb[(size_t)(mb + r)*N + n] = d;
                    tmax = fmaxf(tmax, d);
                }
            }
        }
        __shared__ float redm[4];
        #pragma unroll
        for (int off = 32; off; off >>= 1) tmax = fmaxf(tmax, __shfl_xor(tmax, off, 64));
        if (lane == 0) redm[wid] = tmax;
        __syncthreads();
        if (t == 0) {
            float m = fmaxf(fmaxf(redm[0], redm[1]), fmaxf(redm[2], redm[3]));
            atomicMax(dmaxU + z, __float_as_uint(m));
        }
    } else {   // MODE 2: x_map = acc/(cnt+eps), packed, in place over A
        unsigned* Cu = (unsigned*)Cb;
        const float* cntb = aux + (size_t)z*HW64;
        #pragma unroll
        for (int p = 0; p < 4; ++p) {
            int mb = m0 + wm*64 + p*16 + l4*4;
            #pragma unroll
            for (int q = 0; q < 4; ++q) {
                int n = n0 + wn*64 + q*16 + l15;
                #pragma unroll
                for (int r = 0; r < 4; ++r) {
                    float v = acc[p][q][r] / (cntb[mb + r] + EPS);
                    Cu[(size_t)(mb + r)*N + n] = pack_hl(v);
                }
            }
        }
    }
}

// ---------------- remaining pipeline ----------------
__global__ void wsum_rows(const float* __restrict__ amat, float* __restrict__ wsum) {
    int row = blockIdx.x*4 + (threadIdx.x >> 6);
    int lane = threadIdx.x & 63;
    const float* ar = amat + (size_t)row*OHW;
    float s = 0.f;
    #pragma unroll
    for (int r = 0; r < 16; ++r) s += ar[lane + 64*r];
    #pragma unroll
    for (int off = 32; off; off >>= 1) s += __shfl_xor(s, off, 64);
    if (lane == 0) wsum[row] = s;
}

__device__ __forceinline__ float block_sum256(float v, float* red) {
    #pragma unroll
    for (int off = 32; off; off >>= 1) v += __shfl_xor(v, off, 64);
    __syncthreads();
    if ((threadIdx.x & 63) == 0) red[threadIdx.x >> 6] = v;
    __syncthreads();
    return red[0] + red[1] + red[2] + red[3];
}

__global__ void ln_conf(const float* __restrict__ C2, const float* __restrict__ wsum,
                        const float* __restrict__ xskip, const float* __restrict__ g,
                        const float* __restrict__ be, const float* __restrict__ confw,
                        const float* __restrict__ confb, float* __restrict__ xtok,
                        unsigned* __restrict__ xtokpk,
                        float* __restrict__ wexp, float* __restrict__ sqv) {
    __shared__ float red[4];
    int row = blockIdx.x, t = threadIdx.x;
    float ws = wsum[row] + EPS;
    size_t base = (size_t)row*NCO;
    float v0 = C2[base + t]       / ws + xskip[base + t];
    float v1 = C2[base + t + 256] / ws + xskip[base + t + 256];
    float mu  = block_sum256(v0 + v1, red) / 512.0f;
    float d0 = v0 - mu, d1 = v1 - mu;
    float var = block_sum256(d0*d0 + d1*d1, red) / 512.0f;
    float sv = sqrtf(var + 1e-5f);
    float x0 = d0/sv * g[t]       + be[t];
    float x1 = d1/sv * g[t + 256] + be[t + 256];
    xtok[base + t] = x0;
    xtok[base + t + 256] = x1;
    xtokpk[base + t] = pack_hl(x0);
    xtokpk[base + t + 256] = pack_hl(x1);
    float cs = block_sum256(x0*confw[t] + x1*confw[t + 256], red);
    float qs = block_sum256(x0*x0 + x1*x1, red);
    if (t == 0) {
        wexp[row] = expf(cs + confb[0]);
        sqv[row]  = qs;
    }
}

__global__ void knn_dens(const float* __restrict__ dist, float* __restrict__ dens) {
    int row = blockIdx.x*4 + (threadIdx.x >> 6);
    int lane = threadIdx.x & 63;
    const float* dr = dist + (size_t)row*NTOK;
    float v0 = dr[lane], v1 = dr[lane+64], v2 = dr[lane+128], v3 = dr[lane+192];
    float acc = 0.f;
    #pragma unroll
    for (int it = 0; it < 5; ++it) {
        float lm = fminf(fminf(v0, v1), fminf(v2, v3));
        float gm = lm;
        #pragma unroll
        for (int off = 32; off; off >>= 1) gm = fminf(gm, __shfl_xor(gm, off, 64));
        acc += gm*gm;
        ull ball = __ballot(lm == gm);
        int first = __ffsll(ball) - 1;
        if (lane == first) {
            if      (v0 == gm) v0 = 1e30f;
            else if (v1 == gm) v1 = 1e30f;
            else if (v2 == gm) v2 = 1e30f;
            else               v3 = 1e30f;
        }
    }
    if (lane == 0) dens[row] = expf(-(acc/5.0f));
}

__global__ void parent_score(const float* __restrict__ dist, const float* __restrict__ dens,
                             const unsigned* __restrict__ dmaxU, float* __restrict__ score) {
    int row = blockIdx.x*4 + (threadIdx.x >> 6);
    int lane = threadIdx.x & 63;
    int b = row >> 8;
    float di = dens[row];
    float dm = __uint_as_float(dmaxU[b]);
    const float* dr = dist + (size_t)row*NTOK;
    const float* db = dens + (size_t)b*NTOK;
    float pd = dm;
    #pragma unroll
    for (int r = 0; r < 4; ++r) {
        int j = lane + 64*r;
        pd = fminf(pd, (db[j] > di) ? dr[j] : dm);
    }
    #pragma unroll
    for (int off = 32; off; off >>= 1) pd = fminf(pd, __shfl_xor(pd, off, 64));
    if (lane == 0) score[row] = pd * di;
}

__global__ void topk64(const float* __restrict__ score, int* __restrict__ ind) {
    int b = blockIdx.x, lane = threadIdx.x;
    const float* sb = score + b*NTOK;
    ull k0, k1, k2, k3;
    {
        unsigned i0 = lane, i1 = lane+64, i2 = lane+128, i3 = lane+192;
        k0 = ((ull)(__float_as_uint(sb[i0]) + 1u) << 32) | (unsigned)(4095 - i0);
        k1 = ((ull)(__float_as_uint(sb[i1]) + 1u) << 32) | (unsigned)(4095 - i1);
        k2 = ((ull)(__float_as_uint(sb[i2]) + 1u) << 32) | (unsigned)(4095 - i2);
        k3 = ((ull)(__float_as_uint(sb[i3]) + 1u) << 32) | (unsigned)(4095 - i3);
    }
    for (int it = 0; it < 64; ++it) {
        ull lm = k0;
        if (k1 > lm) lm = k1;
        if (k2 > lm) lm = k2;
        if (k3 > lm) lm = k3;
        ull gm = lm;
        #pragma unroll
        for (int off = 32; off; off >>= 1) {
            ull o = __shfl_xor(gm, off, 64);
            if (o > gm) gm = o;
        }
        if (lane == 0) ind[b*NS + it] = 4095 - (int)(gm & 0xffffffffull);
        if      (k0 == gm) k0 = 0;
        else if (k1 == gm) k1 = 0;
        else if (k2 == gm) k2 = 0;
        else if (k3 == gm) k3 = 0;
    }
}

__global__ void assign_k(const float* __restrict__ dist, const int* __restrict__ ind,
                         int* __restrict__ idxcl) {
    int row = blockIdx.x*4 + (threadIdx.x >> 6);
    int lane = threadIdx.x & 63;
    int b = row >> 8, i = row & 255;
    int center = ind[b*NS + lane];
    float d = dist[((size_t)(b*NTOK + center))*NTOK + i];
    ull key = ((ull)__float_as_uint(d) << 32) | (unsigned)lane;
    #pragma unroll
    for (int off = 32; off; off >>= 1) {
        ull o = __shfl_xor(key, off, 64);
        if (o < key) key = o;
    }
    if (lane == 0) idxcl[row] = (int)(key & 0xffffffffull);
}

__global__ void center_set(const int* __restrict__ ind, int* __restrict__ idxcl) {
    int id = threadIdx.x;
    int b = id >> 6, s = id & 63;
    idxcl[b*NTOK + ind[id]] = s;
}

__global__ void allw_acc(const int* __restrict__ idxcl, const float* __restrict__ wexp,
                         float* __restrict__ allw) {
    int b = blockIdx.x, i = threadIdx.x;
    atomicAdd(&allw[b*NS + idxcl[b*NTOK + i]], wexp[b*NTOK + i]);
}

__global__ void normw_k(const int* __restrict__ idxcl, const float* __restrict__ wexp,
                        const float* __restrict__ allw, float* __restrict__ normw) {
    int b = blockIdx.x, i = threadIdx.x;
    normw[b*NTOK + i] = wexp[b*NTOK + i] / (allw[b*NS + idxcl[b*NTOK + i]] + EPS);
}

__global__ void merge_k(const float* __restrict__ xtok, const int* __restrict__ idxcl,
                        const float* __restrict__ normw, float* __restrict__ xout) {
    int row = blockIdx.x, t = threadIdx.x;
    int b = row >> 8;
    int cl = idxcl[row];
    float nw = normw[row];
    float* o = xout + ((size_t)(b*NS + cl))*NCO;
    const float* xr = xtok + (size_t)row*NCO;
    atomicAdd(&o[t],       xr[t]       * nw);
    atomicAdd(&o[t + 256], xr[t + 256] * nw);
}

__global__ void out_idx_aw(const int* __restrict__ idxagg, const float* __restrict__ aggw,
                           const int* __restrict__ idxcl, const float* __restrict__ normw,
                           float* __restrict__ dout, float* __restrict__ awbuf,
                           unsigned* __restrict__ maxw) {
    __shared__ float red[4];
    int bp = blockIdx.x*256 + threadIdx.x;
    int b = bp >> 14;
    int tok = idxagg[bp];
    int cl = idxcl[b*NTOK + tok];
    dout[(size_t)NB*NS*NCO + bp] = (float)cl;
    float aw = aggw[bp] * normw[b*NTOK + tok];
    awbuf[bp] = aw;
    float m = aw;
    #pragma unroll
    for (int off = 32; off; off >>= 1) m = fmaxf(m, __shfl_xor(m, off, 64));
    if ((threadIdx.x & 63) == 0) red[threadIdx.x >> 6] = m;
    __syncthreads();
    if (threadIdx.x == 0) {
        float mm = fmaxf(fmaxf(red[0], red[1]), fmaxf(red[2], red[3]));
        atomicMax(&maxw[b], __float_as_uint(mm));
    }
}

__global__ void aw_final(const float* __restrict__ awbuf, const float* __restrict__ maxw,
                         float* __restrict__ dout) {
    int bp = blockIdx.x*256 + threadIdx.x;
    int b = bp >> 14;
    dout[(size_t)NB*NS*NCO + (size_t)NB*NP + bp] = awbuf[bp] / maxw[b];
}

// ---------------- launch ----------------
extern "C" void kernel_launch(void* const* d_in, const int* in_sizes, int n_in,
                              void* d_out, int out_size, void* d_ws, size_t ws_size,
                              hipStream_t stream) {
    const float* x      = (const float*)d_in[0];
    const float* loc    = (const float*)d_in[1];
    const int*   idxagg = (const int*)  d_in[2];
    const float* aggw   = (const float*)d_in[3];
    const float* convw  = (const float*)d_in[7];
    const float* convb  = (const float*)d_in[8];
    const float* skipw  = (const float*)d_in[9];
    const float* lng    = (const float*)d_in[10];
    const float* lnb    = (const float*)d_in[11];
    const float* confw  = (const float*)d_in[12];
    const float* confb  = (const float*)d_in[13];

    float* ws = (float*)d_ws;
    float* dout = (float*)d_out;

    (void)hipMemsetAsync(ws, 0, ZERO_END*sizeof(float), stream);
    (void)hipMemsetAsync(dout, 0, (size_t)NB*NS*NCO*sizeof(float), stream);

    // histogram scatter (131K int atomics instead of 33.5M f32 atomics)
    hist<<<dim3(NB*NP/256), 256, 0, stream>>>(loc, idxagg, aggw,
                                              (int*)(ws + OFF_SUMS), ws + OFF_CNT, ws + OFF_AMAT);
    cnt_pack<<<dim3(NB*HW64*CIN/1024), 256, 0, stream>>>((unsigned*)(ws + OFF_SUMS));
    xt_pack<<<dim3(NB*CIN*NTOK/256), 256, 0, stream>>>(x, (unsigned*)(ws + OFF_XTPK));
    wtrans<<<dim3(KC*NCO/256), 256, 0, stream>>>(convw, (unsigned*)(ws + OFF_WT));
    pack4<<<dim3(CIN*NCO/1024), 256, 0, stream>>>((const float4*)skipw, (uint4*)(ws + OFF_SKWT));
    pack4<<<dim3(NB*NTOK*CIN/1024), 256, 0, stream>>>((const float4*)x, (uint4*)(ws + OFF_XPK));

    // x_map = (cntmat @ x) / (cnt+eps), packed, in place over cntmat (M=4096,N=256,K=256)
    gemm_pk<2><<<dim3(2, 32, 8), 256, 0, stream>>>((const unsigned*)(ws + OFF_SUMS),
                                                   (const unsigned*)(ws + OFF_XTPK),
                                                   ws + OFF_SUMS, NTOK, CIN,
                                                   (long)HW64*NTOK, (long)CIN*NTOK, (long)HW64*CIN,
                                                   ws + OFF_CNT, nullptr);

    conv_gemm<<<dim3(64, 4), 256, 0, stream>>>((const unsigned*)(ws + OFF_SUMS),
                                               (const unsigned*)(ws + OFF_WT), convb,
                                               (unsigned*)(ws + OFF_Y));

    wsum_rows<<<dim3(NB*NTOK/4), 256, 0, stream>>>(ws + OFF_AMAT, ws + OFF_WSUM);
    // Amat packed into SUMS region (xmap dead after conv)
    pack4<<<dim3(NB*NTOK*OHW/1024), 256, 0, stream>>>((const float4*)(ws + OFF_AMAT),
                                                      (uint4*)(ws + OFF_AMATP));
    // ssum: C2[tok][cout] = Amat @ y  (M=256,N=512,K=1024 per batch)
    gemm_pk<0><<<dim3(4, 2, 8), 256, 0, stream>>>((const unsigned*)(ws + OFF_AMATP),
                                                  (const unsigned*)(ws + OFF_Y),
                                                  ws + OFF_C2, OHW, NCO,
                                                  (long)NTOK*OHW, (long)NCO*OHW, (long)NTOK*NCO,
                                                  nullptr, nullptr);
    // xskip = x @ skip_w^T (M=2048,N=512,K=256)
    gemm_pk<0><<<dim3(4, 16, 1), 256, 0, stream>>>((const unsigned*)(ws + OFF_XPK),
                                                   (const unsigned*)(ws + OFF_SKWT),
                                                   ws + OFF_XSKIP, CIN, NCO, 0, 0, 0,
                                                   nullptr, nullptr);

    ln_conf<<<dim3(NB*NTOK), 256, 0, stream>>>(ws + OFF_C2, ws + OFF_WSUM, ws + OFF_XSKIP,
                                               lng, lnb, confw, confb,
                                               ws + OFF_XTOK, (unsigned*)(ws + OFF_XTOKPK),
                                               ws + OFF_WEXP, ws + OFF_SQ);

    // dist: Gram + sqrt epilogue (M=N=256,K=512 per batch)
    gemm_pk<1><<<dim3(2, 2, 8), 256, 0, stream>>>((const unsigned*)(ws + OFF_XTOKPK),
                                                  (const unsigned*)(ws + OFF_XTOKPK),
                                                  ws + OFF_DIST, NCO, NTOK,
                                                  (long)NTOK*NCO, (long)NTOK*NCO, (long)NTOK*NTOK,
                                                  ws + OFF_SQ, (unsigned*)(ws + OFF_DMAX));

    knn_dens<<<dim3(NB*NTOK/4), 256, 0, stream>>>(ws + OFF_DIST, ws + OFF_DENS);
    parent_score<<<dim3(NB*NTOK/4), 256, 0, stream>>>(ws + OFF_DIST, ws + OFF_DENS,
                                                      (const unsigned*)(ws + OFF_DMAX), ws + OFF_SCORE);
    topk64<<<dim3(NB), 64, 0, stream>>>(ws + OFF_SCORE, (int*)(ws + OFF_IND));
    assign_k<<<dim3(NB*NTOK/4), 256, 0, stream>>>(ws + OFF_DIST, (const int*)(ws + OFF_IND),
                                                  (int*)(ws + OFF_IDXCL));
    center_set<<<dim3(1), 512, 0, stream>>>((const int*)(ws + OFF_IND), (int*)(ws + OFF_IDXCL));
    allw_acc<<<dim3(NB), 256, 0, stream>>>((const int*)(ws + OFF_IDXCL), ws + OFF_WEXP, ws + OFF_ALLW);
    normw_k<<<dim3(NB), 256, 0, stream>>>((const int*)(ws + OFF_IDXCL), ws + OFF_WEXP,
                                          ws + OFF_ALLW, ws + OFF_NORMW);
    merge_k<<<dim3(NB*NTOK), 256, 0, stream>>>(ws + OFF_XTOK, (const int*)(ws + OFF_IDXCL),
                                               ws + OFF_NORMW, dout);
    out_idx_aw<<<dim3(NB*NP/256), 256, 0, stream>>>(idxagg, aggw, (const int*)(ws + OFF_IDXCL),
                                                    ws + OFF_NORMW, dout, ws + OFF_AWBUF,
                                                    (unsigned*)(ws + OFF_MAXW));
    aw_final<<<dim3(NB*NP/256), 256, 0, stream>>>(ws + OFF_AWBUF, (const float*)(ws + OFF_MAXW), dout);
}

// Round 6
// 321.083 us; speedup vs baseline: 6.8703x; 1.1492x over previous
//
#include <hip/hip_runtime.h>
#include <math.h>

typedef unsigned long long ull;
typedef __attribute__((ext_vector_type(8))) short short8v;   // 8 bf16 in 4 VGPRs
typedef __attribute__((ext_vector_type(4))) float float4v;

#define NB   8
#define NTOK 256
#define CIN  256
#define NP   16384
#define NCO  512
#define HW64 4096
#define OHW  1024
#define NS   64
#define EPS  1e-6f
#define KC   2304   // 9*256 conv K

// ---------------- workspace layout (float offsets) ----------------
constexpr size_t OFF_SUMS = 0;                                   // cntmat(int) -> xmap packed (in-place GEMM); after conv: AMATP alias
constexpr size_t OFF_CNT  = OFF_SUMS + (size_t)NB*HW64*CIN;
constexpr size_t OFF_AMAT = OFF_CNT  + (size_t)NB*HW64;          // fp32 tok x cell32 weights
constexpr size_t OFF_ALLW = OFF_AMAT + (size_t)NB*NTOK*OHW;
constexpr size_t OFF_DMAX = OFF_ALLW + (size_t)NB*NS;
constexpr size_t OFF_MAXW = OFF_DMAX + NB;
constexpr size_t ZERO_END = OFF_MAXW + NB;
constexpr size_t OFF_WT   = ZERO_END;                            // 512*2304 packed hi|lo [cout][k]
constexpr size_t OFF_SKWT = OFF_WT   + (size_t)KC*NCO;           // 512*256 packed [cout][cin]
constexpr size_t OFF_Y    = OFF_SKWT + (size_t)CIN*NCO;          // yT packed [b][cout][cell]; after ssum: XTOKPK alias
constexpr size_t OFF_C2   = OFF_Y    + (size_t)NB*OHW*NCO;       // ssum fp32
constexpr size_t OFF_WSUM = OFF_C2   + (size_t)NB*NTOK*NCO;
constexpr size_t OFF_XSKIP= OFF_WSUM + (size_t)NB*NTOK;
constexpr size_t OFF_XTOK = OFF_XSKIP+ (size_t)NB*NTOK*NCO;      // fp32
constexpr size_t OFF_XPK  = OFF_XTOK + (size_t)NB*NTOK*NCO;      // x packed [b][tok][cin]
constexpr size_t OFF_WEXP = OFF_XPK  + (size_t)NB*NTOK*NCO;
constexpr size_t OFF_SQ   = OFF_WEXP + (size_t)NB*NTOK;
constexpr size_t OFF_DIST = OFF_SQ   + (size_t)NB*NTOK;
constexpr size_t OFF_DENS = OFF_DIST + (size_t)NB*NTOK*NTOK;
constexpr size_t OFF_SCORE= OFF_DENS + (size_t)NB*NTOK;
constexpr size_t OFF_IND  = OFF_SCORE+ (size_t)NB*NTOK;
constexpr size_t OFF_IDXCL= OFF_IND  + (size_t)NB*NS;
constexpr size_t OFF_NORMW= OFF_IDXCL+ (size_t)NB*NTOK;
constexpr size_t OFF_AWBUF= OFF_NORMW+ (size_t)NB*NTOK;
constexpr size_t OFF_XTPK = OFF_AWBUF+ (size_t)NB*NP;            // x^T packed [b][cin][tok]
// aliases (regions dead by the time these are written)
constexpr size_t OFF_AMATP = OFF_SUMS;
constexpr size_t OFF_XTOKPK= OFF_Y;

// pack fp32 -> (bf16_hi << 16) | bf16_lo, both RNE
__device__ __forceinline__ unsigned pack_hl(float x) {
    unsigned u = __float_as_uint(x);
    unsigned t = u + 0x7fffu + ((u >> 16) & 1u);
    unsigned hibits = t & 0xffff0000u;
    float lo = x - __uint_as_float(hibits);
    unsigned ul = __float_as_uint(lo);
    unsigned lt = ul + 0x7fffu + ((ul >> 16) & 1u);
    return hibits | (lt >> 16);
}
__device__ __forceinline__ unsigned hp2(unsigned w0, unsigned w1) {
    return __builtin_amdgcn_perm(w1, w0, 0x07060302u);
}
__device__ __forceinline__ unsigned lp2(unsigned w0, unsigned w1) {
    return __builtin_amdgcn_perm(w1, w0, 0x05040100u);
}

// ---------------- histogram ----------------
__global__ void hist(const float* __restrict__ loc, const int* __restrict__ idxagg,
                     const float* __restrict__ aggw,
                     int* __restrict__ cntmat, float* __restrict__ cnt,
                     float* __restrict__ amat) {
    int bp = blockIdx.x*256 + threadIdx.x;
    int b  = bp >> 14;
    float lx = loc[2*bp+0], ly = loc[2*bp+1];
    lx = fminf(fmaxf(lx, -1.f), 1.f);
    ly = fminf(fmaxf(ly, -1.f), 1.f);
    int px = (int)rintf((lx + 1.f)*32.f - 0.5f); px = min(max(px,0),63);
    int py = (int)rintf((ly + 1.f)*32.f - 0.5f); py = min(max(py,0),63);
    int cell = py*64 + px;
    int tok = idxagg[bp];
    atomicAdd(&cntmat[((size_t)(b*HW64 + cell))*NTOK + tok], 1);
    atomicAdd(&cnt[b*HW64 + cell], 1.0f);
    int qx = (int)rintf((lx + 1.f)*16.f - 0.5f); qx = min(max(qx,0),31);
    int qy = (int)rintf((ly + 1.f)*16.f - 0.5f); qy = min(max(qy,0),31);
    atomicAdd(&amat[((size_t)(b*NTOK + tok))*OHW + qy*32 + qx], aggw[bp]);
}

__global__ void cnt_pack(unsigned* __restrict__ m) {
    size_t i = (size_t)blockIdx.x*256 + threadIdx.x;
    int4 v = ((const int4*)m)[i];
    uint4 o;
    o.x = pack_hl((float)v.x); o.y = pack_hl((float)v.y);
    o.z = pack_hl((float)v.z); o.w = pack_hl((float)v.w);
    ((uint4*)m)[i] = o;
}

__global__ void xt_pack(const float* __restrict__ x, unsigned* __restrict__ xtpk) {
    int id = blockIdx.x*256 + threadIdx.x;
    int tok = id & 255, cin = (id >> 8) & 255, b = id >> 16;
    xtpk[id] = pack_hl(x[((size_t)(b*NTOK + tok))*CIN + cin]);
}

__global__ void wtrans(const float* __restrict__ convw, unsigned* __restrict__ wt) {
    int id = blockIdx.x*256 + threadIdx.x;
    int cout = id / KC, k = id - cout*KC;
    int grp = k >> 8, cin = k & 255;
    wt[id] = pack_hl(convw[(size_t)cout*KC + cin*9 + grp]);
}

__global__ void pack4(const float4* __restrict__ src, uint4* __restrict__ dst) {
    size_t i = (size_t)blockIdx.x*256 + threadIdx.x;
    float4 v = src[i];
    uint4 o;
    o.x = pack_hl(v.x); o.y = pack_hl(v.y); o.z = pack_hl(v.z); o.w = pack_hl(v.w);
    dst[i] = o;
}

// ---------------- split-bf16 MFMA conv: 128(pos) x 64(cout) tile, grid 64x8=512 blocks ----------------
__launch_bounds__(256)
__global__ void conv_gemm(const unsigned* __restrict__ xmap, const unsigned* __restrict__ wt,
                          const float* __restrict__ convb, unsigned* __restrict__ ytp) {
    __shared__ __align__(16) unsigned short Ahi[4096], Alo[4096];   // 128 pos x 32 k
    __shared__ __align__(16) unsigned short Bhi[2048], Blo[2048];   // 64 cout x 32 k
    int n0 = blockIdx.x * 128;          // pos tile (8192/128 = 64)
    int m0 = blockIdx.y * 64;           // cout tile (512/64 = 8)
    int t = threadIdx.x;
    int lane = t & 63, wid = t >> 6;
    int wm = wid >> 1, wn = wid & 1;    // wave: 64 pos x 32 cout
    int l15 = lane & 15, l4 = lane >> 4;

    // A staging: rowL=t&127 (pos), kg=t>>7 (2 slots of 8 k)
    int rowL = t & 127, kg = t >> 7;
    int posG = n0 + rowL;
    int bb = posG >> 10, rem = posG & 1023;
    int oy = rem >> 5, ox = rem & 31;
    // B staging: rowB=t&63 (cout), kgB=t>>6 (one slot of 8 k)
    int rowB = t & 63, kgB = t >> 6;
    const unsigned* brow = wt + (size_t)(m0 + rowB)*KC + kgB*8;

    int wbA0 = (rowL>>4)*512 + kg*128 + (rowL&15)*8;
    int wbA1 = wbA0 + 256;
    int wbB  = (rowB>>4)*512 + kgB*128 + (rowB&15)*8;

    float4v acc[4][2] = {};
    uint4 a00,a01,a10,a11, b0,b1;

    auto loadA = [&](int kc) {
        int grp = kc >> 3;
        int ky = grp/3, kx = grp - 3*ky;
        int iy = 2*oy - 1 + ky, ix = 2*ox - 1 + kx;
        if ((unsigned)iy < 64u && (unsigned)ix < 64u) {
            const unsigned* ap = xmap + ((((size_t)bb*64 + iy)*64 + ix)*256 + (kc&7)*32 + kg*8);
            a00 = *(const uint4*)ap;       a01 = *(const uint4*)(ap + 4);
            a10 = *(const uint4*)(ap + 16); a11 = *(const uint4*)(ap + 20);
        } else {
            a00 = make_uint4(0,0,0,0); a01 = a00; a10 = a00; a11 = a00;
        }
    };
    auto loadB = [&](int kc) {
        const unsigned* bp = brow + (size_t)kc*32;
        b0 = *(const uint4*)bp; b1 = *(const uint4*)(bp + 4);
    };
    loadA(0); loadB(0);

    for (int kc = 0; kc < KC/32; ++kc) {
        __syncthreads();
        uint4 h, l;
        h.x=hp2(a00.x,a00.y); h.y=hp2(a00.z,a00.w); h.z=hp2(a01.x,a01.y); h.w=hp2(a01.z,a01.w);
        l.x=lp2(a00.x,a00.y); l.y=lp2(a00.z,a00.w); l.z=lp2(a01.x,a01.y); l.w=lp2(a01.z,a01.w);
        *(uint4*)&Ahi[wbA0] = h; *(uint4*)&Alo[wbA0] = l;
        h.x=hp2(a10.x,a10.y); h.y=hp2(a10.z,a10.w); h.z=hp2(a11.x,a11.y); h.w=hp2(a11.z,a11.w);
        l.x=lp2(a10.x,a10.y); l.y=lp2(a10.z,a10.w); l.z=lp2(a11.x,a11.y); l.w=lp2(a11.z,a11.w);
        *(uint4*)&Ahi[wbA1] = h; *(uint4*)&Alo[wbA1] = l;
        h.x=hp2(b0.x,b0.y); h.y=hp2(b0.z,b0.w); h.z=hp2(b1.x,b1.y); h.w=hp2(b1.z,b1.w);
        l.x=lp2(b0.x,b0.y); l.y=lp2(b0.z,b0.w); l.z=lp2(b1.x,b1.y); l.w=lp2(b1.z,b1.w);
        *(uint4*)&Bhi[wbB] = h; *(uint4*)&Blo[wbB] = l;
        __syncthreads();
        if (kc + 1 < KC/32) { loadA(kc+1); loadB(kc+1); }

        short8v bh[2], bl[2];
        #pragma unroll
        for (int q = 0; q < 2; ++q) {
            int off = (wn*2 + q)*512 + l4*128 + l15*8;
            bh[q] = *(const short8v*)&Bhi[off];
            bl[q] = *(const short8v*)&Blo[off];
        }
        #pragma unroll
        for (int p = 0; p < 4; ++p) {
            int off = (wm*4 + p)*512 + l4*128 + l15*8;
            short8v ah = *(const short8v*)&Ahi[off];
            short8v al = *(const short8v*)&Alo[off];
            #pragma unroll
            for (int q = 0; q < 2; ++q) {
                acc[p][q] = __builtin_amdgcn_mfma_f32_16x16x32_bf16(ah, bh[q], acc[p][q], 0, 0, 0);
                acc[p][q] = __builtin_amdgcn_mfma_f32_16x16x32_bf16(ah, bl[q], acc[p][q], 0, 0, 0);
                acc[p][q] = __builtin_amdgcn_mfma_f32_16x16x32_bf16(al, bh[q], acc[p][q], 0, 0, 0);
            }
        }
    }

    int bbk = n0 >> 10;
    int pos0 = (n0 & 1023) + wm*64;
    #pragma unroll
    for (int p = 0; p < 4; ++p) {
        int posb = pos0 + p*16 + l4*4;
        #pragma unroll
        for (int q = 0; q < 2; ++q) {
            int col = m0 + wn*32 + q*16 + l15;
            float bv = convb[col];
            uint4 o;
            o.x = pack_hl(acc[p][q][0] + bv);
            o.y = pack_hl(acc[p][q][1] + bv);
            o.z = pack_hl(acc[p][q][2] + bv);
            o.w = pack_hl(acc[p][q][3] + bv);
            *(uint4*)&ytp[((size_t)(bbk*NCO + col))*OHW + posb] = o;
        }
    }
}

// ---------------- generic split-bf16 MFMA GEMM, TM x TN tile (64 or 128 each) ----------------
// A_pk[b][M][K], B_pk[b][N][K]. MODE 0: C=fp32. MODE 1: dist epilogue. MODE 2: xmap epilogue.
template<int MODE, int TM, int TN>
__launch_bounds__(256)
__global__ void gemm_pk(const unsigned* __restrict__ A, const unsigned* __restrict__ B,
                        float* __restrict__ C, int K, int N,
                        long sA, long sB, long sC,
                        const float* __restrict__ aux, unsigned* __restrict__ dmaxU) {
    constexpr int NA = TM/64, NBs = TN/64;          // staging slots per thread
    constexpr int WSM = TM/64;                       // waves along M (1 or 2)
    constexpr int WSN = 4/WSM;
    constexpr int TWM = TM/WSM, TWN = TN/WSN;        // per-wave tile
    constexpr int P = TWM/16, Q = TWN/16;
    __shared__ __align__(16) unsigned short Ahi[TM*32], Alo[TM*32];
    __shared__ __align__(16) unsigned short Bhi[TN*32], Blo[TN*32];
    int z = blockIdx.z;
    const unsigned* Ab = A + (size_t)z*sA;
    const unsigned* Bb = B + (size_t)z*sB;
    float* Cb = C + (size_t)z*sC;
    int n0 = blockIdx.x*TN, m0 = blockIdx.y*TM;
    int t = threadIdx.x;
    int lane = t & 63, wid = t >> 6;
    int wm = (WSM==2) ? (wid >> 1) : 0;
    int wn = (WSM==2) ? (wid & 1)  : wid;
    int l15 = lane & 15, l4 = lane >> 4;

    int rowA = t & (TM-1), kgA = t / TM;
    int rowB = t & (TN-1), kgB = t / TN;
    const unsigned* arow = Ab + (size_t)(m0 + rowA)*K + kgA*8;
    const unsigned* brw  = Bb + (size_t)(n0 + rowB)*K + kgB*8;
    int wbA = (rowA>>4)*512 + kgA*128 + (rowA&15)*8;
    int wbB = (rowB>>4)*512 + kgB*128 + (rowB&15)*8;

    float4v acc[P][Q] = {};
    uint4 ra[NA][2], rb[NBs][2];
    auto loadA = [&](int kc) {
        #pragma unroll
        for (int s = 0; s < NA; ++s) {
            const unsigned* p = arow + (size_t)kc*32 + s*16;
            ra[s][0] = *(const uint4*)p; ra[s][1] = *(const uint4*)(p + 4);
        }
    };
    auto loadB = [&](int kc) {
        #pragma unroll
        for (int s = 0; s < NBs; ++s) {
            const unsigned* p = brw + (size_t)kc*32 + s*16;
            rb[s][0] = *(const uint4*)p; rb[s][1] = *(const uint4*)(p + 4);
        }
    };
    loadA(0); loadB(0);
    int nkc = K >> 5;

    for (int kc = 0; kc < nkc; ++kc) {
        __syncthreads();
        uint4 h, l;
        #pragma unroll
        for (int s = 0; s < NA; ++s) {
            uint4 u0 = ra[s][0], u1 = ra[s][1];
            h.x=hp2(u0.x,u0.y); h.y=hp2(u0.z,u0.w); h.z=hp2(u1.x,u1.y); h.w=hp2(u1.z,u1.w);
            l.x=lp2(u0.x,u0.y); l.y=lp2(u0.z,u0.w); l.z=lp2(u1.x,u1.y); l.w=lp2(u1.z,u1.w);
            *(uint4*)&Ahi[wbA + s*256] = h; *(uint4*)&Alo[wbA + s*256] = l;
        }
        #pragma unroll
        for (int s = 0; s < NBs; ++s) {
            uint4 u0 = rb[s][0], u1 = rb[s][1];
            h.x=hp2(u0.x,u0.y); h.y=hp2(u0.z,u0.w); h.z=hp2(u1.x,u1.y); h.w=hp2(u1.z,u1.w);
            l.x=lp2(u0.x,u0.y); l.y=lp2(u0.z,u0.w); l.z=lp2(u1.x,u1.y); l.w=lp2(u1.z,u1.w);
            *(uint4*)&Bhi[wbB + s*256] = h; *(uint4*)&Blo[wbB + s*256] = l;
        }
        __syncthreads();
        if (kc + 1 < nkc) { loadA(kc+1); loadB(kc+1); }

        short8v bh[Q], bl[Q];
        #pragma unroll
        for (int q = 0; q < Q; ++q) {
            int off = (wn*Q + q)*512 + l4*128 + l15*8;
            bh[q] = *(const short8v*)&Bhi[off];
            bl[q] = *(const short8v*)&Blo[off];
        }
        #pragma unroll
        for (int p = 0; p < P; ++p) {
            int off = (wm*P + p)*512 + l4*128 + l15*8;
            short8v ah = *(const short8v*)&Ahi[off];
            short8v al = *(const short8v*)&Alo[off];
            #pragma unroll
            for (int q = 0; q < Q; ++q) {
                acc[p][q] = __builtin_amdgcn_mfma_f32_16x16x32_bf16(ah, bh[q], acc[p][q], 0, 0, 0);
                acc[p][q] = __builtin_amdgcn_mfma_f32_16x16x32_bf16(ah, bl[q], acc[p][q], 0, 0, 0);
                acc[p][q] = __builtin_amdgcn_mfma_f32_16x16x32_bf16(al, bh[q], acc[p][q], 0, 0, 0);
            }
        }
    }

    if (MODE == 0) {
        #pragma unroll
        for (int p = 0; p < P; ++p) {
            int mb = m0 + wm*TWM + p*16 + l4*4;
            #pragma unroll
            for (int q = 0; q < Q; ++q) {
                int n = n0 + wn*TWN + q*16 + l15;
                #pragma unroll
                for (int r = 0; r < 4; ++r)
                    Cb[(size_t)(mb + r)*N + n] = acc[p][q][r];
            }
        }
    } else if (MODE == 1) {
        const float inv = 1.0f / sqrtf(512.0f);
        const float* sqb = aux + (size_t)z*NTOK;
        float tmax = 0.f;
        #pragma unroll
        for (int p = 0; p < P; ++p) {
            int mb = m0 + wm*TWM + p*16 + l4*4;
            #pragma unroll
            for (int q = 0; q < Q; ++q) {
                int n = n0 + wn*TWN + q*16 + l15;
                float sn = sqb[n];
                #pragma unroll
                for (int r = 0; r < 4; ++r) {
                    float d2 = sqb[mb + r] + sn - 2.0f*acc[p][q][r];
                    float d = sqrtf(fmaxf(d2, 0.0f)) * inv;
                    Cb[(size_t)(mb + r)*N + n] = d;
                    tmax = fmaxf(tmax, d);
                }
            }
        }
        __shared__ float redm[4];
        #pragma unroll
        for (int off = 32; off; off >>= 1) tmax = fmaxf(tmax, __shfl_xor(tmax, off, 64));
        if (lane == 0) redm[wid] = tmax;
        __syncthreads();
        if (t == 0) {
            float m = fmaxf(fmaxf(redm[0], redm[1]), fmaxf(redm[2], redm[3]));
            atomicMax(dmaxU + z, __float_as_uint(m));
        }
    } else {   // MODE 2: x_map = acc/(cnt+eps), packed, in place over A
        unsigned* Cu = (unsigned*)Cb;
        const float* cntb = aux + (size_t)z*HW64;
        #pragma unroll
        for (int p = 0; p < P; ++p) {
            int mb = m0 + wm*TWM + p*16 + l4*4;
            #pragma unroll
            for (int q = 0; q < Q; ++q) {
                int n = n0 + wn*TWN + q*16 + l15;
                #pragma unroll
                for (int r = 0; r < 4; ++r) {
                    float v = acc[p][q][r] / (cntb[mb + r] + EPS);
                    Cu[(size_t)(mb + r)*N + n] = pack_hl(v);
                }
            }
        }
    }
}

// ---------------- remaining pipeline ----------------
__global__ void wsum_rows(const float* __restrict__ amat, float* __restrict__ wsum) {
    int row = blockIdx.x*4 + (threadIdx.x >> 6);
    int lane = threadIdx.x & 63;
    const float* ar = amat + (size_t)row*OHW;
    float s = 0.f;
    #pragma unroll
    for (int r = 0; r < 16; ++r) s += ar[lane + 64*r];
    #pragma unroll
    for (int off = 32; off; off >>= 1) s += __shfl_xor(s, off, 64);
    if (lane == 0) wsum[row] = s;
}

__device__ __forceinline__ float block_sum256(float v, float* red) {
    #pragma unroll
    for (int off = 32; off; off >>= 1) v += __shfl_xor(v, off, 64);
    __syncthreads();
    if ((threadIdx.x & 63) == 0) red[threadIdx.x >> 6] = v;
    __syncthreads();
    return red[0] + red[1] + red[2] + red[3];
}

__global__ void ln_conf(const float* __restrict__ C2, const float* __restrict__ wsum,
                        const float* __restrict__ xskip, const float* __restrict__ g,
                        const float* __restrict__ be, const float* __restrict__ confw,
                        const float* __restrict__ confb, float* __restrict__ xtok,
                        unsigned* __restrict__ xtokpk,
                        float* __restrict__ wexp, float* __restrict__ sqv) {
    __shared__ float red[4];
    int row = blockIdx.x, t = threadIdx.x;
    float ws = wsum[row] + EPS;
    size_t base = (size_t)row*NCO;
    float v0 = C2[base + t]       / ws + xskip[base + t];
    float v1 = C2[base + t + 256] / ws + xskip[base + t + 256];
    float mu  = block_sum256(v0 + v1, red) / 512.0f;
    float d0 = v0 - mu, d1 = v1 - mu;
    float var = block_sum256(d0*d0 + d1*d1, red) / 512.0f;
    float sv = sqrtf(var + 1e-5f);
    float x0 = d0/sv * g[t]       + be[t];
    float x1 = d1/sv * g[t + 256] + be[t + 256];
    xtok[base + t] = x0;
    xtok[base + t + 256] = x1;
    xtokpk[base + t] = pack_hl(x0);
    xtokpk[base + t + 256] = pack_hl(x1);
    float cs = block_sum256(x0*confw[t] + x1*confw[t + 256], red);
    float qs = block_sum256(x0*x0 + x1*x1, red);
    if (t == 0) {
        wexp[row] = expf(cs + confb[0]);
        sqv[row]  = qs;
    }
}

__global__ void knn_dens(const float* __restrict__ dist, float* __restrict__ dens) {
    int row = blockIdx.x*4 + (threadIdx.x >> 6);
    int lane = threadIdx.x & 63;
    const float* dr = dist + (size_t)row*NTOK;
    float v0 = dr[lane], v1 = dr[lane+64], v2 = dr[lane+128], v3 = dr[lane+192];
    float acc = 0.f;
    #pragma unroll
    for (int it = 0; it < 5; ++it) {
        float lm = fminf(fminf(v0, v1), fminf(v2, v3));
        float gm = lm;
        #pragma unroll
        for (int off = 32; off; off >>= 1) gm = fminf(gm, __shfl_xor(gm, off, 64));
        acc += gm*gm;
        ull ball = __ballot(lm == gm);
        int first = __ffsll(ball) - 1;
        if (lane == first) {
            if      (v0 == gm) v0 = 1e30f;
            else if (v1 == gm) v1 = 1e30f;
            else if (v2 == gm) v2 = 1e30f;
            else               v3 = 1e30f;
        }
    }
    if (lane == 0) dens[row] = expf(-(acc/5.0f));
}

__global__ void parent_score(const float* __restrict__ dist, const float* __restrict__ dens,
                             const unsigned* __restrict__ dmaxU, float* __restrict__ score) {
    int row = blockIdx.x*4 + (threadIdx.x >> 6);
    int lane = threadIdx.x & 63;
    int b = row >> 8;
    float di = dens[row];
    float dm = __uint_as_float(dmaxU[b]);
    const float* dr = dist + (size_t)row*NTOK;
    const float* db = dens + (size_t)b*NTOK;
    float pd = dm;
    #pragma unroll
    for (int r = 0; r < 4; ++r) {
        int j = lane + 64*r;
        pd = fminf(pd, (db[j] > di) ? dr[j] : dm);
    }
    #pragma unroll
    for (int off = 32; off; off >>= 1) pd = fminf(pd, __shfl_xor(pd, off, 64));
    if (lane == 0) score[row] = pd * di;
}

__global__ void topk64(const float* __restrict__ score, int* __restrict__ ind) {
    int b = blockIdx.x, lane = threadIdx.x;
    const float* sb = score + b*NTOK;
    ull k0, k1, k2, k3;
    {
        unsigned i0 = lane, i1 = lane+64, i2 = lane+128, i3 = lane+192;
        k0 = ((ull)(__float_as_uint(sb[i0]) + 1u) << 32) | (unsigned)(4095 - i0);
        k1 = ((ull)(__float_as_uint(sb[i1]) + 1u) << 32) | (unsigned)(4095 - i1);
        k2 = ((ull)(__float_as_uint(sb[i2]) + 1u) << 32) | (unsigned)(4095 - i2);
        k3 = ((ull)(__float_as_uint(sb[i3]) + 1u) << 32) | (unsigned)(4095 - i3);
    }
    for (int it = 0; it < 64; ++it) {
        ull lm = k0;
        if (k1 > lm) lm = k1;
        if (k2 > lm) lm = k2;
        if (k3 > lm) lm = k3;
        ull gm = lm;
        #pragma unroll
        for (int off = 32; off; off >>= 1) {
            ull o = __shfl_xor(gm, off, 64);
            if (o > gm) gm = o;
        }
        if (lane == 0) ind[b*NS + it] = 4095 - (int)(gm & 0xffffffffull);
        if      (k0 == gm) k0 = 0;
        else if (k1 == gm) k1 = 0;
        else if (k2 == gm) k2 = 0;
        else if (k3 == gm) k3 = 0;
    }
}

__global__ void assign_k(const float* __restrict__ dist, const int* __restrict__ ind,
                         int* __restrict__ idxcl) {
    int row = blockIdx.x*4 + (threadIdx.x >> 6);
    int lane = threadIdx.x & 63;
    int b = row >> 8, i = row & 255;
    int center = ind[b*NS + lane];
    float d = dist[((size_t)(b*NTOK + center))*NTOK + i];
    ull key = ((ull)__float_as_uint(d) << 32) | (unsigned)lane;
    #pragma unroll
    for (int off = 32; off; off >>= 1) {
        ull o = __shfl_xor(key, off, 64);
        if (o < key) key = o;
    }
    if (lane == 0) idxcl[row] = (int)(key & 0xffffffffull);
}

__global__ void center_set(const int* __restrict__ ind, int* __restrict__ idxcl) {
    int id = threadIdx.x;
    int b = id >> 6, s = id & 63;
    idxcl[b*NTOK + ind[id]] = s;
}

__global__ void allw_acc(const int* __restrict__ idxcl, const float* __restrict__ wexp,
                         float* __restrict__ allw) {
    int b = blockIdx.x, i = threadIdx.x;
    atomicAdd(&allw[b*NS + idxcl[b*NTOK + i]], wexp[b*NTOK + i]);
}

__global__ void normw_k(const int* __restrict__ idxcl, const float* __restrict__ wexp,
                        const float* __restrict__ allw, float* __restrict__ normw) {
    int b = blockIdx.x, i = threadIdx.x;
    normw[b*NTOK + i] = wexp[b*NTOK + i] / (allw[b*NS + idxcl[b*NTOK + i]] + EPS);
}

__global__ void merge_k(const float* __restrict__ xtok, const int* __restrict__ idxcl,
                        const float* __restrict__ normw, float* __restrict__ xout) {
    int row = blockIdx.x, t = threadIdx.x;
    int b = row >> 8;
    int cl = idxcl[row];
    float nw = normw[row];
    float* o = xout + ((size_t)(b*NS + cl))*NCO;
    const float* xr = xtok + (size_t)row*NCO;
    atomicAdd(&o[t],       xr[t]       * nw);
    atomicAdd(&o[t + 256], xr[t + 256] * nw);
}

__global__ void out_idx_aw(const int* __restrict__ idxagg, const float* __restrict__ aggw,
                           const int* __restrict__ idxcl, const float* __restrict__ normw,
                           float* __restrict__ dout, float* __restrict__ awbuf,
                           unsigned* __restrict__ maxw) {
    __shared__ float red[4];
    int bp = blockIdx.x*256 + threadIdx.x;
    int b = bp >> 14;
    int tok = idxagg[bp];
    int cl = idxcl[b*NTOK + tok];
    dout[(size_t)NB*NS*NCO + bp] = (float)cl;
    float aw = aggw[bp] * normw[b*NTOK + tok];
    awbuf[bp] = aw;
    float m = aw;
    #pragma unroll
    for (int off = 32; off; off >>= 1) m = fmaxf(m, __shfl_xor(m, off, 64));
    if ((threadIdx.x & 63) == 0) red[threadIdx.x >> 6] = m;
    __syncthreads();
    if (threadIdx.x == 0) {
        float mm = fmaxf(fmaxf(red[0], red[1]), fmaxf(red[2], red[3]));
        atomicMax(&maxw[b], __float_as_uint(mm));
    }
}

__global__ void aw_final(const float* __restrict__ awbuf, const float* __restrict__ maxw,
                         float* __restrict__ dout) {
    int bp = blockIdx.x*256 + threadIdx.x;
    int b = bp >> 14;
    dout[(size_t)NB*NS*NCO + (size_t)NB*NP + bp] = awbuf[bp] / maxw[b];
}

// ---------------- launch ----------------
extern "C" void kernel_launch(void* const* d_in, const int* in_sizes, int n_in,
                              void* d_out, int out_size, void* d_ws, size_t ws_size,
                              hipStream_t stream) {
    const float* x      = (const float*)d_in[0];
    const float* loc    = (const float*)d_in[1];
    const int*   idxagg = (const int*)  d_in[2];
    const float* aggw   = (const float*)d_in[3];
    const float* convw  = (const float*)d_in[7];
    const float* convb  = (const float*)d_in[8];
    const float* skipw  = (const float*)d_in[9];
    const float* lng    = (const float*)d_in[10];
    const float* lnb    = (const float*)d_in[11];
    const float* confw  = (const float*)d_in[12];
    const float* confb  = (const float*)d_in[13];

    float* ws = (float*)d_ws;
    float* dout = (float*)d_out;

    (void)hipMemsetAsync(ws, 0, ZERO_END*sizeof(float), stream);
    (void)hipMemsetAsync(dout, 0, (size_t)NB*NS*NCO*sizeof(float), stream);

    hist<<<dim3(NB*NP/256), 256, 0, stream>>>(loc, idxagg, aggw,
                                              (int*)(ws + OFF_SUMS), ws + OFF_CNT, ws + OFF_AMAT);
    cnt_pack<<<dim3(NB*HW64*CIN/1024), 256, 0, stream>>>((unsigned*)(ws + OFF_SUMS));
    xt_pack<<<dim3(NB*CIN*NTOK/256), 256, 0, stream>>>(x, (unsigned*)(ws + OFF_XTPK));
    wtrans<<<dim3(KC*NCO/256), 256, 0, stream>>>(convw, (unsigned*)(ws + OFF_WT));
    pack4<<<dim3(CIN*NCO/1024), 256, 0, stream>>>((const float4*)skipw, (uint4*)(ws + OFF_SKWT));
    pack4<<<dim3(NB*NTOK*CIN/1024), 256, 0, stream>>>((const float4*)x, (uint4*)(ws + OFF_XPK));

    // x_map = (cntmat @ x) / (cnt+eps), packed, in place (M=4096,N=256,K=256)
    gemm_pk<2,128,128><<<dim3(2, 32, 8), 256, 0, stream>>>((const unsigned*)(ws + OFF_SUMS),
                                                   (const unsigned*)(ws + OFF_XTPK),
                                                   ws + OFF_SUMS, NTOK, CIN,
                                                   (long)HW64*NTOK, (long)CIN*NTOK, (long)HW64*CIN,
                                                   ws + OFF_CNT, nullptr);

    // conv: 128(pos) x 64(cout) tiles -> 512 blocks = 2/CU
    conv_gemm<<<dim3(64, 8), 256, 0, stream>>>((const unsigned*)(ws + OFF_SUMS),
                                               (const unsigned*)(ws + OFF_WT), convb,
                                               (unsigned*)(ws + OFF_Y));

    wsum_rows<<<dim3(NB*NTOK/4), 256, 0, stream>>>(ws + OFF_AMAT, ws + OFF_WSUM);
    pack4<<<dim3(NB*NTOK*OHW/1024), 256, 0, stream>>>((const float4*)(ws + OFF_AMAT),
                                                      (uint4*)(ws + OFF_AMATP));
    // ssum: C2[tok][cout] = Amat @ y (M=256,N=512,K=1024) -> 64x64 tiles, 256 blocks
    gemm_pk<0,64,64><<<dim3(8, 4, 8), 256, 0, stream>>>((const unsigned*)(ws + OFF_AMATP),
                                                  (const unsigned*)(ws + OFF_Y),
                                                  ws + OFF_C2, OHW, NCO,
                                                  (long)NTOK*OHW, (long)NCO*OHW, (long)NTOK*NCO,
                                                  nullptr, nullptr);
    // xskip = x @ skip_w^T (M=2048,N=512,K=256) -> 64x64 tiles, 256 blocks
    gemm_pk<0,64,64><<<dim3(8, 32, 1), 256, 0, stream>>>((const unsigned*)(ws + OFF_XPK),
                                                   (const unsigned*)(ws + OFF_SKWT),
                                                   ws + OFF_XSKIP, CIN, NCO, 0, 0, 0,
                                                   nullptr, nullptr);

    ln_conf<<<dim3(NB*NTOK), 256, 0, stream>>>(ws + OFF_C2, ws + OFF_WSUM, ws + OFF_XSKIP,
                                               lng, lnb, confw, confb,
                                               ws + OFF_XTOK, (unsigned*)(ws + OFF_XTOKPK),
                                               ws + OFF_WEXP, ws + OFF_SQ);

    // dist: Gram + sqrt epilogue (M=N=256,K=512) -> 64x64 tiles, 128 blocks
    gemm_pk<1,64,64><<<dim3(4, 4, 8), 256, 0, stream>>>((const unsigned*)(ws + OFF_XTOKPK),
                                                  (const unsigned*)(ws + OFF_XTOKPK),
                                                  ws + OFF_DIST, NCO, NTOK,
                                                  (long)NTOK*NCO, (long)NTOK*NCO, (long)NTOK*NTOK,
                                                  ws + OFF_SQ, (unsigned*)(ws + OFF_DMAX));

    knn_dens<<<dim3(NB*NTOK/4), 256, 0, stream>>>(ws + OFF_DIST, ws + OFF_DENS);
    parent_score<<<dim3(NB*NTOK/4), 256, 0, stream>>>(ws + OFF_DIST, ws + OFF_DENS,
                                                      (const unsigned*)(ws + OFF_DMAX), ws + OFF_SCORE);
    topk64<<<dim3(NB), 64, 0, stream>>>(ws + OFF_SCORE, (int*)(ws + OFF_IND));
    assign_k<<<dim3(NB*NTOK/4), 256, 0, stream>>>(ws + OFF_DIST, (const int*)(ws + OFF_IND),
                                                  (int*)(ws + OFF_IDXCL));
    center_set<<<dim3(1), 512, 0, stream>>>((const int*)(ws + OFF_IND), (int*)(ws + OFF_IDXCL));
    allw_acc<<<dim3(NB), 256, 0, stream>>>((const int*)(ws + OFF_IDXCL), ws + OFF_WEXP, ws + OFF_ALLW);
    normw_k<<<dim3(NB), 256, 0, stream>>>((const int*)(ws + OFF_IDXCL), ws + OFF_WEXP,
                                          ws + OFF_ALLW, ws + OFF_NORMW);
    merge_k<<<dim3(NB*NTOK), 256, 0, stream>>>(ws + OFF_XTOK, (const int*)(ws + OFF_IDXCL),
                                               ws + OFF_NORMW, dout);
    out_idx_aw<<<dim3(NB*NP/256), 256, 0, stream>>>(idxagg, aggw, (const int*)(ws + OFF_IDXCL),
                                                    ws + OFF_NORMW, dout, ws + OFF_AWBUF,
                                                    (unsigned*)(ws + OFF_MAXW));
    aw_final<<<dim3(NB*NP/256), 256, 0, stream>>>(ws + OFF_AWBUF, (const float*)(ws + OFF_MAXW), dout);
}

// Round 7
// 304.268 us; speedup vs baseline: 7.2500x; 1.0553x over previous
//
#include <hip/hip_runtime.h>
#include <math.h>

typedef unsigned long long ull;
typedef __attribute__((ext_vector_type(8))) short short8v;   // 8 bf16 in 4 VGPRs
typedef __attribute__((ext_vector_type(4))) float float4v;

#define NB   8
#define NTOK 256
#define CIN  256
#define NP   16384
#define NCO  512
#define HW64 4096
#define OHW  1024
#define NS   64
#define EPS  1e-6f
#define KC   2304   // 9*256 conv K
#define NKC  72     // KC/32

// ---------------- workspace layout (float offsets) ----------------
constexpr size_t OFF_SUMS = 0;                                   // cntmat(int) -> xmap packed; after conv: AMATP alias
constexpr size_t OFF_CNT  = OFF_SUMS + (size_t)NB*HW64*CIN;
constexpr size_t OFF_AMAT = OFF_CNT  + (size_t)NB*HW64;
constexpr size_t OFF_ALLW = OFF_AMAT + (size_t)NB*NTOK*OHW;
constexpr size_t OFF_DMAX = OFF_ALLW + (size_t)NB*NS;
constexpr size_t OFF_MAXW = OFF_DMAX + NB;
constexpr size_t ZERO_END = OFF_MAXW + NB;
constexpr size_t OFF_WT   = ZERO_END;                            // 4.7MB: frag-major weights
constexpr size_t OFF_SKWT = OFF_WT   + (size_t)KC*NCO;
constexpr size_t OFF_Y    = OFF_SKWT + (size_t)CIN*NCO;          // yT packed; after ssum: XTOKPK alias
constexpr size_t OFF_C2   = OFF_Y    + (size_t)NB*OHW*NCO;
constexpr size_t OFF_WSUM = OFF_C2   + (size_t)NB*NTOK*NCO;
constexpr size_t OFF_XSKIP= OFF_WSUM + (size_t)NB*NTOK;
constexpr size_t OFF_XTOK = OFF_XSKIP+ (size_t)NB*NTOK*NCO;
constexpr size_t OFF_XPK  = OFF_XTOK + (size_t)NB*NTOK*NCO;
constexpr size_t OFF_WEXP = OFF_XPK  + (size_t)NB*NTOK*NCO;
constexpr size_t OFF_SQ   = OFF_WEXP + (size_t)NB*NTOK;
constexpr size_t OFF_DIST = OFF_SQ   + (size_t)NB*NTOK;
constexpr size_t OFF_DENS = OFF_DIST + (size_t)NB*NTOK*NTOK;
constexpr size_t OFF_SCORE= OFF_DENS + (size_t)NB*NTOK;
constexpr size_t OFF_IND  = OFF_SCORE+ (size_t)NB*NTOK;
constexpr size_t OFF_IDXCL= OFF_IND  + (size_t)NB*NS;
constexpr size_t OFF_NORMW= OFF_IDXCL+ (size_t)NB*NTOK;
constexpr size_t OFF_AWBUF= OFF_NORMW+ (size_t)NB*NTOK;
constexpr size_t OFF_XTPK = OFF_AWBUF+ (size_t)NB*NP;
constexpr size_t OFF_AMATP = OFF_SUMS;
constexpr size_t OFF_XTOKPK= OFF_Y;

__device__ __forceinline__ unsigned pack_hl(float x) {
    unsigned u = __float_as_uint(x);
    unsigned t = u + 0x7fffu + ((u >> 16) & 1u);
    unsigned hibits = t & 0xffff0000u;
    float lo = x - __uint_as_float(hibits);
    unsigned ul = __float_as_uint(lo);
    unsigned lt = ul + 0x7fffu + ((ul >> 16) & 1u);
    return hibits | (lt >> 16);
}
__device__ __forceinline__ unsigned hp2(unsigned w0, unsigned w1) {
    return __builtin_amdgcn_perm(w1, w0, 0x07060302u);
}
__device__ __forceinline__ unsigned lp2(unsigned w0, unsigned w1) {
    return __builtin_amdgcn_perm(w1, w0, 0x05040100u);
}

// ---------------- histogram ----------------
__global__ void hist(const float* __restrict__ loc, const int* __restrict__ idxagg,
                     const float* __restrict__ aggw,
                     int* __restrict__ cntmat, float* __restrict__ cnt,
                     float* __restrict__ amat) {
    int bp = blockIdx.x*256 + threadIdx.x;
    int b  = bp >> 14;
    float lx = loc[2*bp+0], ly = loc[2*bp+1];
    lx = fminf(fmaxf(lx, -1.f), 1.f);
    ly = fminf(fmaxf(ly, -1.f), 1.f);
    int px = (int)rintf((lx + 1.f)*32.f - 0.5f); px = min(max(px,0),63);
    int py = (int)rintf((ly + 1.f)*32.f - 0.5f); py = min(max(py,0),63);
    int cell = py*64 + px;
    int tok = idxagg[bp];
    atomicAdd(&cntmat[((size_t)(b*HW64 + cell))*NTOK + tok], 1);
    atomicAdd(&cnt[b*HW64 + cell], 1.0f);
    int qx = (int)rintf((lx + 1.f)*16.f - 0.5f); qx = min(max(qx,0),31);
    int qy = (int)rintf((ly + 1.f)*16.f - 0.5f); qy = min(max(qy,0),31);
    atomicAdd(&amat[((size_t)(b*NTOK + tok))*OHW + qy*32 + qx], aggw[bp]);
}

__global__ void cnt_pack(unsigned* __restrict__ m) {
    size_t i = (size_t)blockIdx.x*256 + threadIdx.x;
    int4 v = ((const int4*)m)[i];
    uint4 o;
    o.x = pack_hl((float)v.x); o.y = pack_hl((float)v.y);
    o.z = pack_hl((float)v.z); o.w = pack_hl((float)v.w);
    ((uint4*)m)[i] = o;
}

__global__ void xt_pack(const float* __restrict__ x, unsigned* __restrict__ xtpk) {
    int id = blockIdx.x*256 + threadIdx.x;
    int tok = id & 255, cin = (id >> 8) & 255, b = id >> 16;
    xtpk[id] = pack_hl(x[((size_t)(b*NTOK + tok))*CIN + cin]);
}

// weights in MFMA-fragment order: wtf[(((mt*72+kc)*4+f)*2+h)*64+lane] (uint4 = 8 bf16)
// lane: cout = mt*64 + f*16 + (lane&15), k = kc*32 + (lane>>4)*8 + j
__global__ void wtrans(const float* __restrict__ convw, uint4* __restrict__ wtf) {
    int tid = blockIdx.x*256 + threadIdx.x;   // 294912
    int lane = tid & 63;
    int r1 = tid >> 6;
    int h = r1 & 1;
    int r2 = r1 >> 1;
    int f = r2 & 3;
    int r3 = r2 >> 2;
    int kc = r3 % NKC, mt = r3 / NKC;
    int cout = mt*64 + f*16 + (lane & 15);
    int kb = kc*32 + (lane >> 4)*8;
    unsigned s[8];
    #pragma unroll
    for (int j = 0; j < 8; ++j) {
        int k = kb + j;
        int grp = k >> 8, cin = k & 255;
        unsigned w = pack_hl(convw[(size_t)cout*KC + cin*9 + grp]);
        s[j] = h ? (w & 0xffffu) : (w >> 16);
    }
    uint4 o;
    o.x = s[0] | (s[1]<<16); o.y = s[2] | (s[3]<<16);
    o.z = s[4] | (s[5]<<16); o.w = s[6] | (s[7]<<16);
    wtf[tid] = o;
}

__global__ void pack4(const float4* __restrict__ src, uint4* __restrict__ dst) {
    size_t i = (size_t)blockIdx.x*256 + threadIdx.x;
    float4 v = src[i];
    uint4 o;
    o.x = pack_hl(v.x); o.y = pack_hl(v.y); o.z = pack_hl(v.z); o.w = pack_hl(v.w);
    dst[i] = o;
}

// ---------------- conv: 128(pos)x64(cout), A dbuf-LDS (1 barrier/kc), B direct-from-L2 frags ----------------
__launch_bounds__(256)
__global__ void conv_gemm(const unsigned* __restrict__ xmap, const uint4* __restrict__ wtf,
                          const float* __restrict__ convb, unsigned* __restrict__ ytp) {
    __shared__ __align__(16) unsigned short Ahi[2][4096], Alo[2][4096];  // dbuf, 128 pos x 32 k
    int n0 = blockIdx.x * 128;          // pos tile (64)
    int mt = blockIdx.y;                // cout tile (8)
    int m0 = mt * 64;
    int t = threadIdx.x;
    int lane = t & 63, wid = t >> 6;
    int wm = wid >> 1, wn = wid & 1;    // wave: 64 pos x 32 cout
    int l15 = lane & 15, l4 = lane >> 4;

    int rowL = t & 127, kg = t >> 7;
    int posG = n0 + rowL;
    int bb = posG >> 10, rem = posG & 1023;
    int oy = rem >> 5, ox = rem & 31;

    int wbA0 = (rowL>>4)*512 + kg*128 + (rowL&15)*8;
    int wbA1 = wbA0 + 256;

    float4v acc[4][2] = {};
    uint4 a00,a01,a10,a11;

    auto loadA = [&](int kc) {
        int grp = kc >> 3;
        int ky = grp/3, kx = grp - 3*ky;
        int iy = 2*oy - 1 + ky, ix = 2*ox - 1 + kx;
        if ((unsigned)iy < 64u && (unsigned)ix < 64u) {
            const unsigned* ap = xmap + ((((size_t)bb*64 + iy)*64 + ix)*256 + (kc&7)*32 + kg*8);
            a00 = *(const uint4*)ap;       a01 = *(const uint4*)(ap + 4);
            a10 = *(const uint4*)(ap + 16); a11 = *(const uint4*)(ap + 20);
        } else {
            a00 = make_uint4(0,0,0,0); a01 = a00; a10 = a00; a11 = a00;
        }
    };
    auto repackA = [&](int buf) {
        uint4 h, l;
        h.x=hp2(a00.x,a00.y); h.y=hp2(a00.z,a00.w); h.z=hp2(a01.x,a01.y); h.w=hp2(a01.z,a01.w);
        l.x=lp2(a00.x,a00.y); l.y=lp2(a00.z,a00.w); l.z=lp2(a01.x,a01.y); l.w=lp2(a01.z,a01.w);
        *(uint4*)&Ahi[buf][wbA0] = h; *(uint4*)&Alo[buf][wbA0] = l;
        h.x=hp2(a10.x,a10.y); h.y=hp2(a10.z,a10.w); h.z=hp2(a11.x,a11.y); h.w=hp2(a11.z,a11.w);
        l.x=lp2(a10.x,a10.y); l.y=lp2(a10.z,a10.w); l.z=lp2(a11.x,a11.y); l.w=lp2(a11.z,a11.w);
        *(uint4*)&Ahi[buf][wbA1] = h; *(uint4*)&Alo[buf][wbA1] = l;
    };
    // B fragment base: per (kc,q,h): stride kc=512, f=128, h=64 (uint4 units)
    const uint4* wbase = wtf + ((size_t)(((mt*NKC)*4 + wn*2)*2))*64 + lane;

    short8v bhc[2], blc[2], bhn[2], bln[2];
    #pragma unroll
    for (int q = 0; q < 2; ++q) {
        bhc[q] = *(const short8v*)(wbase + q*128);
        blc[q] = *(const short8v*)(wbase + q*128 + 64);
    }
    loadA(0);
    repackA(0);
    __syncthreads();
    int cur = 0;

    for (int kc = 0; kc < NKC; ++kc) {
        bool notlast = (kc + 1 < NKC);
        if (notlast) {
            loadA(kc+1);                       // global, in flight under MFMA
            const uint4* wb = wbase + (size_t)(kc+1)*512;
            #pragma unroll
            for (int q = 0; q < 2; ++q) {
                bhn[q] = *(const short8v*)(wb + q*128);
                bln[q] = *(const short8v*)(wb + q*128 + 64);
            }
        }
        #pragma unroll
        for (int p = 0; p < 4; ++p) {
            int off = (wm*4 + p)*512 + l4*128 + l15*8;
            short8v ah = *(const short8v*)&Ahi[cur][off];
            short8v al = *(const short8v*)&Alo[cur][off];
            #pragma unroll
            for (int q = 0; q < 2; ++q) {
                acc[p][q] = __builtin_amdgcn_mfma_f32_16x16x32_bf16(ah, bhc[q], acc[p][q], 0, 0, 0);
                acc[p][q] = __builtin_amdgcn_mfma_f32_16x16x32_bf16(ah, blc[q], acc[p][q], 0, 0, 0);
                acc[p][q] = __builtin_amdgcn_mfma_f32_16x16x32_bf16(al, bhc[q], acc[p][q], 0, 0, 0);
            }
        }
        if (notlast) {
            repackA(cur ^ 1);
            #pragma unroll
            for (int q = 0; q < 2; ++q) { bhc[q] = bhn[q]; blc[q] = bln[q]; }
        }
        __syncthreads();
        cur ^= 1;
    }

    int bbk = n0 >> 10;
    int pos0 = (n0 & 1023) + wm*64;
    #pragma unroll
    for (int p = 0; p < 4; ++p) {
        int posb = pos0 + p*16 + l4*4;
        #pragma unroll
        for (int q = 0; q < 2; ++q) {
            int col = m0 + wn*32 + q*16 + l15;
            float bv = convb[col];
            uint4 o;
            o.x = pack_hl(acc[p][q][0] + bv);
            o.y = pack_hl(acc[p][q][1] + bv);
            o.z = pack_hl(acc[p][q][2] + bv);
            o.w = pack_hl(acc[p][q][3] + bv);
            *(uint4*)&ytp[((size_t)(bbk*NCO + col))*OHW + posb] = o;
        }
    }
}

// ---------------- generic split-bf16 MFMA GEMM, TM x TN tile ----------------
template<int MODE, int TM, int TN>
__launch_bounds__(256)
__global__ void gemm_pk(const unsigned* __restrict__ A, const unsigned* __restrict__ B,
                        float* __restrict__ C, int K, int N,
                        long sA, long sB, long sC,
                        const float* __restrict__ aux, unsigned* __restrict__ dmaxU) {
    constexpr int NA = TM/64, NBs = TN/64;
    constexpr int WSM = TM/64;
    constexpr int WSN = 4/WSM;
    constexpr int TWM = TM/WSM, TWN = TN/WSN;
    constexpr int P = TWM/16, Q = TWN/16;
    __shared__ __align__(16) unsigned short Ahi[TM*32], Alo[TM*32];
    __shared__ __align__(16) unsigned short Bhi[TN*32], Blo[TN*32];
    int z = blockIdx.z;
    const unsigned* Ab = A + (size_t)z*sA;
    const unsigned* Bb = B + (size_t)z*sB;
    float* Cb = C + (size_t)z*sC;
    int n0 = blockIdx.x*TN, m0 = blockIdx.y*TM;
    int t = threadIdx.x;
    int lane = t & 63, wid = t >> 6;
    int wm = (WSM==2) ? (wid >> 1) : 0;
    int wn = (WSM==2) ? (wid & 1)  : wid;
    int l15 = lane & 15, l4 = lane >> 4;

    int rowA = t & (TM-1), kgA = t / TM;
    int rowB = t & (TN-1), kgB = t / TN;
    const unsigned* arow = Ab + (size_t)(m0 + rowA)*K + kgA*8;
    const unsigned* brw  = Bb + (size_t)(n0 + rowB)*K + kgB*8;
    int wbA = (rowA>>4)*512 + kgA*128 + (rowA&15)*8;
    int wbB = (rowB>>4)*512 + kgB*128 + (rowB&15)*8;

    float4v acc[P][Q] = {};
    uint4 ra[NA][2], rb[NBs][2];
    auto loadA = [&](int kc) {
        #pragma unroll
        for (int s = 0; s < NA; ++s) {
            const unsigned* p = arow + (size_t)kc*32 + s*16;
            ra[s][0] = *(const uint4*)p; ra[s][1] = *(const uint4*)(p + 4);
        }
    };
    auto loadB = [&](int kc) {
        #pragma unroll
        for (int s = 0; s < NBs; ++s) {
            const unsigned* p = brw + (size_t)kc*32 + s*16;
            rb[s][0] = *(const uint4*)p; rb[s][1] = *(const uint4*)(p + 4);
        }
    };
    loadA(0); loadB(0);
    int nkc = K >> 5;

    for (int kc = 0; kc < nkc; ++kc) {
        __syncthreads();
        uint4 h, l;
        #pragma unroll
        for (int s = 0; s < NA; ++s) {
            uint4 u0 = ra[s][0], u1 = ra[s][1];
            h.x=hp2(u0.x,u0.y); h.y=hp2(u0.z,u0.w); h.z=hp2(u1.x,u1.y); h.w=hp2(u1.z,u1.w);
            l.x=lp2(u0.x,u0.y); l.y=lp2(u0.z,u0.w); l.z=lp2(u1.x,u1.y); l.w=lp2(u1.z,u1.w);
            *(uint4*)&Ahi[wbA + s*256] = h; *(uint4*)&Alo[wbA + s*256] = l;
        }
        #pragma unroll
        for (int s = 0; s < NBs; ++s) {
            uint4 u0 = rb[s][0], u1 = rb[s][1];
            h.x=hp2(u0.x,u0.y); h.y=hp2(u0.z,u0.w); h.z=hp2(u1.x,u1.y); h.w=hp2(u1.z,u1.w);
            l.x=lp2(u0.x,u0.y); l.y=lp2(u0.z,u0.w); l.z=lp2(u1.x,u1.y); l.w=lp2(u1.z,u1.w);
            *(uint4*)&Bhi[wbB + s*256] = h; *(uint4*)&Blo[wbB + s*256] = l;
        }
        __syncthreads();
        if (kc + 1 < nkc) { loadA(kc+1); loadB(kc+1); }

        short8v bh[Q], bl[Q];
        #pragma unroll
        for (int q = 0; q < Q; ++q) {
            int off = (wn*Q + q)*512 + l4*128 + l15*8;
            bh[q] = *(const short8v*)&Bhi[off];
            bl[q] = *(const short8v*)&Blo[off];
        }
        #pragma unroll
        for (int p = 0; p < P; ++p) {
            int off = (wm*P + p)*512 + l4*128 + l15*8;
            short8v ah = *(const short8v*)&Ahi[off];
            short8v al = *(const short8v*)&Alo[off];
            #pragma unroll
            for (int q = 0; q < Q; ++q) {
                acc[p][q] = __builtin_amdgcn_mfma_f32_16x16x32_bf16(ah, bh[q], acc[p][q], 0, 0, 0);
                acc[p][q] = __builtin_amdgcn_mfma_f32_16x16x32_bf16(ah, bl[q], acc[p][q], 0, 0, 0);
                acc[p][q] = __builtin_amdgcn_mfma_f32_16x16x32_bf16(al, bh[q], acc[p][q], 0, 0, 0);
            }
        }
    }

    if (MODE == 0) {
        #pragma unroll
        for (int p = 0; p < P; ++p) {
            int mb = m0 + wm*TWM + p*16 + l4*4;
            #pragma unroll
            for (int q = 0; q < Q; ++q) {
                int n = n0 + wn*TWN + q*16 + l15;
                #pragma unroll
                for (int r = 0; r < 4; ++r)
                    Cb[(size_t)(mb + r)*N + n] = acc[p][q][r];
            }
        }
    } else if (MODE == 1) {
        const float inv = 1.0f / sqrtf(512.0f);
        const float* sqb = aux + (size_t)z*NTOK;
        float tmax = 0.f;
        #pragma unroll
        for (int p = 0; p < P; ++p) {
            int mb = m0 + wm*TWM + p*16 + l4*4;
            #pragma unroll
            for (int q = 0; q < Q; ++q) {
                int n = n0 + wn*TWN + q*16 + l15;
                float sn = sqb[n];
                #pragma unroll
                for (int r = 0; r < 4; ++r) {
                    float d2 = sqb[mb + r] + sn - 2.0f*acc[p][q][r];
                    float d = sqrtf(fmaxf(d2, 0.0f)) * inv;
                    Cb[(size_t)(mb + r)*N + n] = d;
                    tmax = fmaxf(tmax, d);
                }
            }
        }
        __shared__ float redm[4];
        #pragma unroll
        for (int off = 32; off; off >>= 1) tmax = fmaxf(tmax, __shfl_xor(tmax, off, 64));
        if (lane == 0) redm[wid] = tmax;
        __syncthreads();
        if (t == 0) {
            float m = fmaxf(fmaxf(redm[0], redm[1]), fmaxf(redm[2], redm[3]));
            atomicMax(dmaxU + z, __float_as_uint(m));
        }
    } else {
        unsigned* Cu = (unsigned*)Cb;
        const float* cntb = aux + (size_t)z*HW64;
        #pragma unroll
        for (int p = 0; p < P; ++p) {
            int mb = m0 + wm*TWM + p*16 + l4*4;
            #pragma unroll
            for (int q = 0; q < Q; ++q) {
                int n = n0 + wn*TWN + q*16 + l15;
                #pragma unroll
                for (int r = 0; r < 4; ++r) {
                    float v = acc[p][q][r] / (cntb[mb + r] + EPS);
                    Cu[(size_t)(mb + r)*N + n] = pack_hl(v);
                }
            }
        }
    }
}

// ---------------- remaining pipeline ----------------
__global__ void wsum_rows(const float* __restrict__ amat, float* __restrict__ wsum) {
    int row = blockIdx.x*4 + (threadIdx.x >> 6);
    int lane = threadIdx.x & 63;
    const float* ar = amat + (size_t)row*OHW;
    float s = 0.f;
    #pragma unroll
    for (int r = 0; r < 16; ++r) s += ar[lane + 64*r];
    #pragma unroll
    for (int off = 32; off; off >>= 1) s += __shfl_xor(s, off, 64);
    if (lane == 0) wsum[row] = s;
}

__device__ __forceinline__ float block_sum256(float v, float* red) {
    #pragma unroll
    for (int off = 32; off; off >>= 1) v += __shfl_xor(v, off, 64);
    __syncthreads();
    if ((threadIdx.x & 63) == 0) red[threadIdx.x >> 6] = v;
    __syncthreads();
    return red[0] + red[1] + red[2] + red[3];
}

__global__ void ln_conf(const float* __restrict__ C2, const float* __restrict__ wsum,
                        const float* __restrict__ xskip, const float* __restrict__ g,
                        const float* __restrict__ be, const float* __restrict__ confw,
                        const float* __restrict__ confb, float* __restrict__ xtok,
                        unsigned* __restrict__ xtokpk,
                        float* __restrict__ wexp, float* __restrict__ sqv) {
    __shared__ float red[4];
    int row = blockIdx.x, t = threadIdx.x;
    float ws = wsum[row] + EPS;
    size_t base = (size_t)row*NCO;
    float v0 = C2[base + t]       / ws + xskip[base + t];
    float v1 = C2[base + t + 256] / ws + xskip[base + t + 256];
    float mu  = block_sum256(v0 + v1, red) / 512.0f;
    float d0 = v0 - mu, d1 = v1 - mu;
    float var = block_sum256(d0*d0 + d1*d1, red) / 512.0f;
    float sv = sqrtf(var + 1e-5f);
    float x0 = d0/sv * g[t]       + be[t];
    float x1 = d1/sv * g[t + 256] + be[t + 256];
    xtok[base + t] = x0;
    xtok[base + t + 256] = x1;
    xtokpk[base + t] = pack_hl(x0);
    xtokpk[base + t + 256] = pack_hl(x1);
    float cs = block_sum256(x0*confw[t] + x1*confw[t + 256], red);
    float qs = block_sum256(x0*x0 + x1*x1, red);
    if (t == 0) {
        wexp[row] = expf(cs + confb[0]);
        sqv[row]  = qs;
    }
}

__global__ void knn_dens(const float* __restrict__ dist, float* __restrict__ dens) {
    int row = blockIdx.x*4 + (threadIdx.x >> 6);
    int lane = threadIdx.x & 63;
    const float* dr = dist + (size_t)row*NTOK;
    float v0 = dr[lane], v1 = dr[lane+64], v2 = dr[lane+128], v3 = dr[lane+192];
    float acc = 0.f;
    #pragma unroll
    for (int it = 0; it < 5; ++it) {
        float lm = fminf(fminf(v0, v1), fminf(v2, v3));
        float gm = lm;
        #pragma unroll
        for (int off = 32; off; off >>= 1) gm = fminf(gm, __shfl_xor(gm, off, 64));
        acc += gm*gm;
        ull ball = __ballot(lm == gm);
        int first = __ffsll(ball) - 1;
        if (lane == first) {
            if      (v0 == gm) v0 = 1e30f;
            else if (v1 == gm) v1 = 1e30f;
            else if (v2 == gm) v2 = 1e30f;
            else               v3 = 1e30f;
        }
    }
    if (lane == 0) dens[row] = expf(-(acc/5.0f));
}

__global__ void parent_score(const float* __restrict__ dist, const float* __restrict__ dens,
                             const unsigned* __restrict__ dmaxU, float* __restrict__ score) {
    int row = blockIdx.x*4 + (threadIdx.x >> 6);
    int lane = threadIdx.x & 63;
    int b = row >> 8;
    float di = dens[row];
    float dm = __uint_as_float(dmaxU[b]);
    const float* dr = dist + (size_t)row*NTOK;
    const float* db = dens + (size_t)b*NTOK;
    float pd = dm;
    #pragma unroll
    for (int r = 0; r < 4; ++r) {
        int j = lane + 64*r;
        pd = fminf(pd, (db[j] > di) ? dr[j] : dm);
    }
    #pragma unroll
    for (int off = 32; off; off >>= 1) pd = fminf(pd, __shfl_xor(pd, off, 64));
    if (lane == 0) score[row] = pd * di;
}

__global__ void topk64(const float* __restrict__ score, int* __restrict__ ind) {
    int b = blockIdx.x, lane = threadIdx.x;
    const float* sb = score + b*NTOK;
    ull k0, k1, k2, k3;
    {
        unsigned i0 = lane, i1 = lane+64, i2 = lane+128, i3 = lane+192;
        k0 = ((ull)(__float_as_uint(sb[i0]) + 1u) << 32) | (unsigned)(4095 - i0);
        k1 = ((ull)(__float_as_uint(sb[i1]) + 1u) << 32) | (unsigned)(4095 - i1);
        k2 = ((ull)(__float_as_uint(sb[i2]) + 1u) << 32) | (unsigned)(4095 - i2);
        k3 = ((ull)(__float_as_uint(sb[i3]) + 1u) << 32) | (unsigned)(4095 - i3);
    }
    for (int it = 0; it < 64; ++it) {
        ull lm = k0;
        if (k1 > lm) lm = k1;
        if (k2 > lm) lm = k2;
        if (k3 > lm) lm = k3;
        ull gm = lm;
        #pragma unroll
        for (int off = 32; off; off >>= 1) {
            ull o = __shfl_xor(gm, off, 64);
            if (o > gm) gm = o;
        }
        if (lane == 0) ind[b*NS + it] = 4095 - (int)(gm & 0xffffffffull);
        if      (k0 == gm) k0 = 0;
        else if (k1 == gm) k1 = 0;
        else if (k2 == gm) k2 = 0;
        else if (k3 == gm) k3 = 0;
    }
}

__global__ void assign_k(const float* __restrict__ dist, const int* __restrict__ ind,
                         int* __restrict__ idxcl) {
    int row = blockIdx.x*4 + (threadIdx.x >> 6);
    int lane = threadIdx.x & 63;
    int b = row >> 8, i = row & 255;
    int center = ind[b*NS + lane];
    float d = dist[((size_t)(b*NTOK + center))*NTOK + i];
    ull key = ((ull)__float_as_uint(d) << 32) | (unsigned)lane;
    #pragma unroll
    for (int off = 32; off; off >>= 1) {
        ull o = __shfl_xor(key, off, 64);
        if (o < key) key = o;
    }
    if (lane == 0) idxcl[row] = (int)(key & 0xffffffffull);
}

__global__ void center_set(const int* __restrict__ ind, int* __restrict__ idxcl) {
    int id = threadIdx.x;
    int b = id >> 6, s = id & 63;
    idxcl[b*NTOK + ind[id]] = s;
}

__global__ void allw_acc(const int* __restrict__ idxcl, const float* __restrict__ wexp,
                         float* __restrict__ allw) {
    int b = blockIdx.x, i = threadIdx.x;
    atomicAdd(&allw[b*NS + idxcl[b*NTOK + i]], wexp[b*NTOK + i]);
}

__global__ void normw_k(const int* __restrict__ idxcl, const float* __restrict__ wexp,
                        const float* __restrict__ allw, float* __restrict__ normw) {
    int b = blockIdx.x, i = threadIdx.x;
    normw[b*NTOK + i] = wexp[b*NTOK + i] / (allw[b*NS + idxcl[b*NTOK + i]] + EPS);
}

__global__ void merge_k(const float* __restrict__ xtok, const int* __restrict__ idxcl,
                        const float* __restrict__ normw, float* __restrict__ xout) {
    int row = blockIdx.x, t = threadIdx.x;
    int b = row >> 8;
    int cl = idxcl[row];
    float nw = normw[row];
    float* o = xout + ((size_t)(b*NS + cl))*NCO;
    const float* xr = xtok + (size_t)row*NCO;
    atomicAdd(&o[t],       xr[t]       * nw);
    atomicAdd(&o[t + 256], xr[t + 256] * nw);
}

__global__ void out_idx_aw(const int* __restrict__ idxagg, const float* __restrict__ aggw,
                           const int* __restrict__ idxcl, const float* __restrict__ normw,
                           float* __restrict__ dout, float* __restrict__ awbuf,
                           unsigned* __restrict__ maxw) {
    __shared__ float red[4];
    int bp = blockIdx.x*256 + threadIdx.x;
    int b = bp >> 14;
    int tok = idxagg[bp];
    int cl = idxcl[b*NTOK + tok];
    dout[(size_t)NB*NS*NCO + bp] = (float)cl;
    float aw = aggw[bp] * normw[b*NTOK + tok];
    awbuf[bp] = aw;
    float m = aw;
    #pragma unroll
    for (int off = 32; off; off >>= 1) m = fmaxf(m, __shfl_xor(m, off, 64));
    if ((threadIdx.x & 63) == 0) red[threadIdx.x >> 6] = m;
    __syncthreads();
    if (threadIdx.x == 0) {
        float mm = fmaxf(fmaxf(red[0], red[1]), fmaxf(red[2], red[3]));
        atomicMax(&maxw[b], __float_as_uint(mm));
    }
}

__global__ void aw_final(const float* __restrict__ awbuf, const float* __restrict__ maxw,
                         float* __restrict__ dout) {
    int bp = blockIdx.x*256 + threadIdx.x;
    int b = bp >> 14;
    dout[(size_t)NB*NS*NCO + (size_t)NB*NP + bp] = awbuf[bp] / maxw[b];
}

// ---------------- launch ----------------
extern "C" void kernel_launch(void* const* d_in, const int* in_sizes, int n_in,
                              void* d_out, int out_size, void* d_ws, size_t ws_size,
                              hipStream_t stream) {
    const float* x      = (const float*)d_in[0];
    const float* loc    = (const float*)d_in[1];
    const int*   idxagg = (const int*)  d_in[2];
    const float* aggw   = (const float*)d_in[3];
    const float* convw  = (const float*)d_in[7];
    const float* convb  = (const float*)d_in[8];
    const float* skipw  = (const float*)d_in[9];
    const float* lng    = (const float*)d_in[10];
    const float* lnb    = (const float*)d_in[11];
    const float* confw  = (const float*)d_in[12];
    const float* confb  = (const float*)d_in[13];

    float* ws = (float*)d_ws;
    float* dout = (float*)d_out;

    (void)hipMemsetAsync(ws, 0, ZERO_END*sizeof(float), stream);
    (void)hipMemsetAsync(dout, 0, (size_t)NB*NS*NCO*sizeof(float), stream);

    hist<<<dim3(NB*NP/256), 256, 0, stream>>>(loc, idxagg, aggw,
                                              (int*)(ws + OFF_SUMS), ws + OFF_CNT, ws + OFF_AMAT);
    cnt_pack<<<dim3(NB*HW64*CIN/1024), 256, 0, stream>>>((unsigned*)(ws + OFF_SUMS));
    xt_pack<<<dim3(NB*CIN*NTOK/256), 256, 0, stream>>>(x, (unsigned*)(ws + OFF_XTPK));
    wtrans<<<dim3(1152), 256, 0, stream>>>(convw, (uint4*)(ws + OFF_WT));
    pack4<<<dim3(CIN*NCO/1024), 256, 0, stream>>>((const float4*)skipw, (uint4*)(ws + OFF_SKWT));
    pack4<<<dim3(NB*NTOK*CIN/1024), 256, 0, stream>>>((const float4*)x, (uint4*)(ws + OFF_XPK));

    // x_map = (cntmat @ x) / (cnt+eps), packed, in place (M=4096,N=256,K=256)
    gemm_pk<2,128,128><<<dim3(2, 32, 8), 256, 0, stream>>>((const unsigned*)(ws + OFF_SUMS),
                                                   (const unsigned*)(ws + OFF_XTPK),
                                                   ws + OFF_SUMS, NTOK, CIN,
                                                   (long)HW64*NTOK, (long)CIN*NTOK, (long)HW64*CIN,
                                                   ws + OFF_CNT, nullptr);

    conv_gemm<<<dim3(64, 8), 256, 0, stream>>>((const unsigned*)(ws + OFF_SUMS),
                                               (const uint4*)(ws + OFF_WT), convb,
                                               (unsigned*)(ws + OFF_Y));

    wsum_rows<<<dim3(NB*NTOK/4), 256, 0, stream>>>(ws + OFF_AMAT, ws + OFF_WSUM);
    pack4<<<dim3(NB*NTOK*OHW/1024), 256, 0, stream>>>((const float4*)(ws + OFF_AMAT),
                                                      (uint4*)(ws + OFF_AMATP));
    gemm_pk<0,64,64><<<dim3(8, 4, 8), 256, 0, stream>>>((const unsigned*)(ws + OFF_AMATP),
                                                  (const unsigned*)(ws + OFF_Y),
                                                  ws + OFF_C2, OHW, NCO,
                                                  (long)NTOK*OHW, (long)NCO*OHW, (long)NTOK*NCO,
                                                  nullptr, nullptr);
    gemm_pk<0,64,64><<<dim3(8, 32, 1), 256, 0, stream>>>((const unsigned*)(ws + OFF_XPK),
                                                   (const unsigned*)(ws + OFF_SKWT),
                                                   ws + OFF_XSKIP, CIN, NCO, 0, 0, 0,
                                                   nullptr, nullptr);

    ln_conf<<<dim3(NB*NTOK), 256, 0, stream>>>(ws + OFF_C2, ws + OFF_WSUM, ws + OFF_XSKIP,
                                               lng, lnb, confw, confb,
                                               ws + OFF_XTOK, (unsigned*)(ws + OFF_XTOKPK),
                                               ws + OFF_WEXP, ws + OFF_SQ);

    gemm_pk<1,64,64><<<dim3(4, 4, 8), 256, 0, stream>>>((const unsigned*)(ws + OFF_XTOKPK),
                                                  (const unsigned*)(ws + OFF_XTOKPK),
                                                  ws + OFF_DIST, NCO, NTOK,
                                                  (long)NTOK*NCO, (long)NTOK*NCO, (long)NTOK*NTOK,
                                                  ws + OFF_SQ, (unsigned*)(ws + OFF_DMAX));

    knn_dens<<<dim3(NB*NTOK/4), 256, 0, stream>>>(ws + OFF_DIST, ws + OFF_DENS);
    parent_score<<<dim3(NB*NTOK/4), 256, 0, stream>>>(ws + OFF_DIST, ws + OFF_DENS,
                                                      (const unsigned*)(ws + OFF_DMAX), ws + OFF_SCORE);
    topk64<<<dim3(NB), 64, 0, stream>>>(ws + OFF_SCORE, (int*)(ws + OFF_IND));
    assign_k<<<dim3(NB*NTOK/4), 256, 0, stream>>>(ws + OFF_DIST, (const int*)(ws + OFF_IND),
                                                  (int*)(ws + OFF_IDXCL));
    center_set<<<dim3(1), 512, 0, stream>>>((const int*)(ws + OFF_IND), (int*)(ws + OFF_IDXCL));
    allw_acc<<<dim3(NB), 256, 0, stream>>>((const int*)(ws + OFF_IDXCL), ws + OFF_WEXP, ws + OFF_ALLW);
    normw_k<<<dim3(NB), 256, 0, stream>>>((const int*)(ws + OFF_IDXCL), ws + OFF_WEXP,
                                          ws + OFF_ALLW, ws + OFF_NORMW);
    merge_k<<<dim3(NB*NTOK), 256, 0, stream>>>(ws + OFF_XTOK, (const int*)(ws + OFF_IDXCL),
                                               ws + OFF_NORMW, dout);
    out_idx_aw<<<dim3(NB*NP/256), 256, 0, stream>>>(idxagg, aggw, (const int*)(ws + OFF_IDXCL),
                                                    ws + OFF_NORMW, dout, ws + OFF_AWBUF,
                                                    (unsigned*)(ws + OFF_MAXW));
    aw_final<<<dim3(NB*NP/256), 256, 0, stream>>>(ws + OFF_AWBUF, (const float*)(ws + OFF_MAXW), dout);
}